// Round 1
// baseline (1909.025 us; speedup 1.0000x reference)
//
#include <hip/hip_runtime.h>
#include <hip/hip_bf16.h>

#define NN 30000
#define EE 300000
#define BB 64
#define HH 4
#define CC 64
#define HC 256

// ---------- helpers: order-preserving float<->uint for atomicMax ----------
__device__ __forceinline__ unsigned fmap(float f) {
    unsigned u = __float_as_uint(f);
    return (u & 0x80000000u) ? ~u : (u | 0x80000000u);
}
__device__ __forceinline__ float funmap(unsigned u) {
    return (u & 0x80000000u) ? __uint_as_float(u & 0x7FFFFFFFu)
                             : __uint_as_float(~u);
}

// ---------- generic OUT[N,W] = H[N,K] @ Wt[K,W] + bias, W == blockDim.x ----
// 8 rows per block; H row values are block-uniform -> scalar loads.
__global__ void gemm_rows8(const float* __restrict__ H, const float* __restrict__ Wt,
                           const float* __restrict__ bias, float* __restrict__ OUT,
                           int K) {
    const int Wd = blockDim.x;
    const int c  = threadIdx.x;
    const int row0 = blockIdx.x * 8;
    float acc[8];
#pragma unroll
    for (int r = 0; r < 8; r++) acc[r] = bias[c];
#pragma unroll 4
    for (int k = 0; k < K; k++) {
        float wv = Wt[k * Wd + c];
#pragma unroll
        for (int r = 0; r < 8; r++)
            acc[r] = fmaf(H[(row0 + r) * K + k], wv, acc[r]);
    }
#pragma unroll
    for (int r = 0; r < 8; r++) OUT[(row0 + r) * Wd + c] = acc[r];
}

// ---------- per-edge logits + segment max --------------------------------
// block = 256 = 4 waves; wave w = head w; lane l = channel l of that head.
// Each lane keeps We[k][64*w+l], k=0..50 in registers.
__global__ void edge_logit_max(const float* __restrict__ xl, const float* __restrict__ xr,
                               const float* __restrict__ ea, const float* __restrict__ We,
                               const float* __restrict__ att, const int* __restrict__ ei,
                               float* __restrict__ logit, unsigned* __restrict__ mmax) {
    const int lane = threadIdx.x & 63;
    const int wv   = threadIdx.x >> 6;   // head
    const int col  = wv * 64 + lane;     // channel in [0,256)
    float wreg[51];
#pragma unroll
    for (int k = 0; k < 51; k++) wreg[k] = We[k * HC + col];
    const float av = att[col];

    for (int e = blockIdx.x; e < EE; e += gridDim.x) {
        const int src = ei[e];
        const int dst = ei[EE + e];
        const float* ear = ea + e * 51;
        float acc = 0.f;
#pragma unroll
        for (int k = 0; k < 51; k++) acc = fmaf(ear[k], wreg[k], acc);
        float v = xl[src * HC + col] + xr[dst * HC + col] + acc;
        v = v > 0.f ? v : 0.2f * v;         // leaky_relu(0.2)
        float p = v * av;
#pragma unroll
        for (int off = 32; off; off >>= 1) p += __shfl_xor(p, off);
        if (lane == 0) {
            logit[e * 4 + wv] = p;
            atomicMax(&mmax[dst * 4 + wv], fmap(p));
        }
    }
}

// ---------- exp(logit - max) and denominator sum -------------------------
__global__ void edge_softmax_den(const int* __restrict__ ei, float* __restrict__ lw,
                                 const unsigned* __restrict__ mmax,
                                 float* __restrict__ den) {
    int i = blockIdx.x * blockDim.x + threadIdx.x;
    if (i >= EE * 4) return;
    int e = i >> 2, h = i & 3;
    int dst = ei[EE + e];
    float m = funmap(mmax[dst * 4 + h]);
    float w = __expf(lw[i] - m);
    lw[i] = w;                              // in-place: logit -> weight
    atomicAdd(&den[dst * 4 + h], w);
}

// ---------- out[n] = bias ------------------------------------------------
__global__ void init_bias(float* __restrict__ out, const float* __restrict__ bias) {
    out[blockIdx.x * HC + threadIdx.x] = bias[threadIdx.x];
}

// ---------- aggregate: out[dst] += xl[src] * alpha -----------------------
__global__ void edge_aggregate(const float* __restrict__ xl, const float* __restrict__ lw,
                               const float* __restrict__ den, const int* __restrict__ ei,
                               float* __restrict__ out) {
    const int lane = threadIdx.x & 63;
    const int wv   = threadIdx.x >> 6;
    const int col  = wv * 64 + lane;
    for (int e = blockIdx.x; e < EE; e += gridDim.x) {
        const int src = ei[e];
        const int dst = ei[EE + e];
        float alpha = lw[e * 4 + wv] / (den[dst * 4 + wv] + 1e-16f);
        atomicAdd(&out[dst * HC + col], xl[src * HC + col] * alpha);
    }
}

// ---------- pooling: segment max over sorted batch -----------------------
__global__ void pool_max(const float* __restrict__ a, const int* __restrict__ batch,
                         unsigned* __restrict__ am) {
    const int c = threadIdx.x;
    const int n0 = blockIdx.x * 64;
    int curb = batch[n0];
    float m = -3.4e38f;
    const int nend = min(n0 + 64, NN);
    for (int n = n0; n < nend; n++) {
        int b = batch[n];
        float v = a[n * HC + c];
        if (b != curb) { atomicMax(&am[curb * HC + c], fmap(m)); curb = b; m = v; }
        else           { m = fmaxf(m, v); }
    }
    atomicMax(&am[curb * HC + c], fmap(m));
}

__global__ void pool_expsum(float* __restrict__ a, const int* __restrict__ batch,
                            const unsigned* __restrict__ am, float* __restrict__ ad) {
    const int c = threadIdx.x;
    const int n0 = blockIdx.x * 64;
    int curb = batch[n0];
    float s = 0.f;
    float mcur = funmap(am[curb * HC + c]);
    const int nend = min(n0 + 64, NN);
    for (int n = n0; n < nend; n++) {
        int b = batch[n];
        if (b != curb) {
            atomicAdd(&ad[curb * HC + c], s);
            curb = b; s = 0.f; mcur = funmap(am[b * HC + c]);
        }
        float w = __expf(a[n * HC + c] - mcur);
        a[n * HC + c] = w;                 // in-place: a -> aw
        s += w;
    }
    atomicAdd(&ad[curb * HC + c], s);
}

__global__ void pool_weighted(const float* __restrict__ h2, const float* __restrict__ aw,
                              const int* __restrict__ batch, const float* __restrict__ ad,
                              float* __restrict__ g) {
    const int c = threadIdx.x;
    const int n0 = blockIdx.x * 64;
    int curb = batch[n0];
    float s = 0.f;
    float dcur = ad[curb * HC + c] + 1e-16f;
    const int nend = min(n0 + 64, NN);
    for (int n = n0; n < nend; n++) {
        int b = batch[n];
        if (b != curb) {
            atomicAdd(&g[curb * HC + c], s);
            curb = b; s = 0.f; dcur = ad[b * HC + c] + 1e-16f;
        }
        s += h2[n * HC + c] * aw[n * HC + c] / dcur;
    }
    atomicAdd(&g[curb * HC + c], s);
}

// ---------- head MLP -----------------------------------------------------
__global__ void mlp_lin1(const float* __restrict__ g, const float* __restrict__ Wo1,
                         const float* __restrict__ bo1, float* __restrict__ y) {
    const int c = threadIdx.x;
    const int r = blockIdx.x;     // 64 rows
    float acc = bo1[c];
#pragma unroll 4
    for (int k = 0; k < HC; k++) acc = fmaf(g[r * HC + k], Wo1[k * HC + c], acc);
    y[r * HC + c] = acc;
}

__global__ void bn_relu(float* __restrict__ y, const float* __restrict__ gamma,
                        const float* __restrict__ beta) {
    const int c = threadIdx.x;    // one block of 256
    float s = 0.f, sq = 0.f;
    for (int r = 0; r < BB; r++) { float v = y[r * HC + c]; s += v; sq += v * v; }
    float mu  = s * (1.f / BB);
    float var = sq * (1.f / BB) - mu * mu;
    float inv = rsqrtf(var + 1e-5f) * gamma[c];
    float bt  = beta[c];
    for (int r = 0; r < BB; r++) {
        float v = (y[r * HC + c] - mu) * inv + bt;
        y[r * HC + c] = v > 0.f ? v : 0.f;
    }
}

__global__ void mlp_lin2(const float* __restrict__ y, const float* __restrict__ Wo2,
                         const float* __restrict__ bo2, float* __restrict__ out) {
    const int j = blockIdx.x * 256 + threadIdx.x;
    const int r = blockIdx.y;
    if (j >= 2001) return;
    float acc = bo2[j];
#pragma unroll 4
    for (int k = 0; k < HC; k++) acc = fmaf(y[r * HC + k], Wo2[k * 2001 + j], acc);
    out[r * 2001 + j] = acc > 0.f ? acc : 0.01f * acc;   // final leaky_relu(0.01)
}

extern "C" void kernel_launch(void* const* d_in, const int* in_sizes, int n_in,
                              void* d_out, int out_size, void* d_ws, size_t ws_size,
                              hipStream_t stream) {
    const float* x     = (const float*)d_in[0];
    const int*   ei    = (const int*)d_in[1];
    const float* ea    = (const float*)d_in[2];
    const int*   batch = (const int*)d_in[3];
    const float* W0 = (const float*)d_in[4];  const float* b0 = (const float*)d_in[5];
    const float* Wl1 = (const float*)d_in[6]; const float* bl1 = (const float*)d_in[7];
    const float* Wr1 = (const float*)d_in[8]; const float* br1 = (const float*)d_in[9];
    const float* We1 = (const float*)d_in[10]; const float* att1 = (const float*)d_in[11];
    const float* bias1 = (const float*)d_in[12];
    const float* Wl2 = (const float*)d_in[13]; const float* bl2 = (const float*)d_in[14];
    const float* Wr2 = (const float*)d_in[15]; const float* br2 = (const float*)d_in[16];
    const float* We2 = (const float*)d_in[17]; const float* att2 = (const float*)d_in[18];
    const float* bias2 = (const float*)d_in[19];
    const float* Wp = (const float*)d_in[20]; const float* bp = (const float*)d_in[21];
    const float* Wo1 = (const float*)d_in[22]; const float* bo1 = (const float*)d_in[23];
    const float* gamma = (const float*)d_in[24]; const float* beta = (const float*)d_in[25];
    const float* Wo2 = (const float*)d_in[26]; const float* bo2 = (const float*)d_in[27];
    float* out = (float*)d_out;

    // ---- workspace layout (floats) ----
    float* ws = (float*)d_ws;
    float* h0   = ws;                    // N*128
    float* xl   = h0 + NN * 128;         // N*256
    float* xr   = xl + NN * HC;          // N*256
    float* h1   = xr + NN * HC;          // N*256
    float* h2   = h1 + NN * HC;          // N*256
    float* abuf = h2 + NN * HC;          // N*256 (a, then aw in place)
    float* lw   = abuf + NN * HC;        // E*4 (logit, then w in place)
    unsigned* mmax = (unsigned*)(lw + EE * 4);   // N*4
    float* den  = (float*)(mmax + NN * 4);       // N*4
    unsigned* am = (unsigned*)(den + NN * 4);    // B*256
    float* ad   = (float*)(am + BB * HC);        // B*256
    float* g    = ad + BB * HC;                  // B*256
    float* ybuf = g + BB * HC;                   // 64*256

    const int edgeGrid = 4096;
    const int poolGrid = (NN + 63) / 64;

    // h0 = x @ W0 + b0
    gemm_rows8<<<NN / 8, 128, 0, stream>>>(x, W0, b0, h0, 13);

    // ---- GAT layer 1 ----
    gemm_rows8<<<NN / 8, HC, 0, stream>>>(h0, Wl1, bl1, xl, 128);
    gemm_rows8<<<NN / 8, HC, 0, stream>>>(h0, Wr1, br1, xr, 128);
    hipMemsetAsync(mmax, 0, NN * 4 * sizeof(unsigned), stream);
    hipMemsetAsync(den, 0, NN * 4 * sizeof(float), stream);
    edge_logit_max<<<edgeGrid, 256, 0, stream>>>(xl, xr, ea, We1, att1, ei, lw, mmax);
    edge_softmax_den<<<(EE * 4 + 255) / 256, 256, 0, stream>>>(ei, lw, mmax, den);
    init_bias<<<NN, HC, 0, stream>>>(h1, bias1);
    edge_aggregate<<<edgeGrid, 256, 0, stream>>>(xl, lw, den, ei, h1);

    // ---- GAT layer 2 ----
    gemm_rows8<<<NN / 8, HC, 0, stream>>>(h1, Wl2, bl2, xl, HC);
    gemm_rows8<<<NN / 8, HC, 0, stream>>>(h1, Wr2, br2, xr, HC);
    hipMemsetAsync(mmax, 0, NN * 4 * sizeof(unsigned), stream);
    hipMemsetAsync(den, 0, NN * 4 * sizeof(float), stream);
    edge_logit_max<<<edgeGrid, 256, 0, stream>>>(xl, xr, ea, We2, att2, ei, lw, mmax);
    edge_softmax_den<<<(EE * 4 + 255) / 256, 256, 0, stream>>>(ei, lw, mmax, den);
    init_bias<<<NN, HC, 0, stream>>>(h2, bias2);
    edge_aggregate<<<edgeGrid, 256, 0, stream>>>(xl, lw, den, ei, h2);

    // ---- attention pooling ----
    gemm_rows8<<<NN / 8, HC, 0, stream>>>(h2, Wp, bp, abuf, HC);
    hipMemsetAsync(am, 0, BB * HC * sizeof(unsigned), stream);
    hipMemsetAsync(ad, 0, BB * HC * sizeof(float), stream);
    hipMemsetAsync(g, 0, BB * HC * sizeof(float), stream);
    pool_max<<<poolGrid, HC, 0, stream>>>(abuf, batch, am);
    pool_expsum<<<poolGrid, HC, 0, stream>>>(abuf, batch, am, ad);
    pool_weighted<<<poolGrid, HC, 0, stream>>>(h2, abuf, batch, ad, g);

    // ---- head MLP ----
    mlp_lin1<<<BB, HC, 0, stream>>>(g, Wo1, bo1, ybuf);
    bn_relu<<<1, HC, 0, stream>>>(ybuf, gamma, beta);
    mlp_lin2<<<dim3(8, BB), 256, 0, stream>>>(ybuf, Wo2, bo2, out);
}

// Round 3
// 973.186 us; speedup vs baseline: 1.9616x; 1.9616x over previous
//
#include <hip/hip_runtime.h>
#include <hip/hip_bf16.h>

#define NN 30000
#define EE 300000
#define BB 64
#define HH 4
#define CC 64
#define HC 256

typedef __attribute__((ext_vector_type(8))) short short8;
typedef __attribute__((ext_vector_type(4))) float floatx4;

#define GLD16(gp, lp) __builtin_amdgcn_global_load_lds( \
    (const __attribute__((address_space(1))) void*)(gp), \
    (__attribute__((address_space(3))) void*)(lp), 16, 0, 0)

// ===================== bf16 MFMA GEMM ====================================
// OUT[M,Nc] = A[M,K](bf16,row-major) @ Bt[Nc,K](bf16, pre-transposed) + bias
// Tile: 64 rows x (CT*64) cols, block=256 (4 waves), BK=32.
// LDS XOR-swizzle: staging thread t fetches global k-chunk (t&3)^((t>>3)&3)
// into slot t&3, so frag reads (b128) spread across banks.
template<int CT>
__global__ __launch_bounds__(256) void mfma_gemm(
    const ushort* __restrict__ A, const ushort* __restrict__ Bt,
    const float* __restrict__ bias, float* __restrict__ outF,
    __hip_bfloat16* __restrict__ outB, int M, int Nc, int K) {
    __shared__ __align__(16) ushort lA[64 * 32];
    __shared__ __align__(16) ushort lB[CT * 64 * 32];
    const int tid = threadIdx.x, lane = tid & 63, wv = tid >> 6;
    const int row0 = blockIdx.x * 64, col0 = blockIdx.y * (CT * 64);

    floatx4 acc[4][CT];
#pragma unroll
    for (int r = 0; r < 4; r++)
#pragma unroll
        for (int c = 0; c < CT; c++) acc[r][c] = (floatx4){0.f, 0.f, 0.f, 0.f};

    const int arow = tid >> 2;                       // 0..63
    const int sl   = (tid & 3) ^ ((tid >> 3) & 3);   // swizzled k-chunk
    const ushort* ga = A + (size_t)(row0 + arow) * K + sl * 8;

    const int m16 = lane & 15, q = lane >> 4;

    for (int k0 = 0; k0 < K; k0 += 32) {
        __syncthreads();
        GLD16(ga + k0, &lA[tid * 8]);
#pragma unroll
        for (int j = 0; j < CT; j++) {
            const ushort* gb = Bt + (size_t)(col0 + j * 64 + arow) * K + k0 + sl * 8;
            GLD16(gb, &lB[j * 2048 + tid * 8]);
        }
        __syncthreads();
        short8 aF[4], bF[CT];
#pragma unroll
        for (int r = 0; r < 4; r++) {
            int rr = r * 16 + m16;
            aF[r] = *(const short8*)&lA[rr * 32 + ((q ^ ((rr >> 1) & 3)) << 3)];
        }
#pragma unroll
        for (int c = 0; c < CT; c++) {
            int nr = (wv * CT + c) * 16 + m16;
            bF[c] = *(const short8*)&lB[nr * 32 + ((q ^ ((nr >> 1) & 3)) << 3)];
        }
#pragma unroll
        for (int r = 0; r < 4; r++)
#pragma unroll
            for (int c = 0; c < CT; c++)
                acc[r][c] = __builtin_amdgcn_mfma_f32_16x16x32_bf16(aF[r], bF[c], acc[r][c], 0, 0, 0);
    }

#pragma unroll
    for (int c = 0; c < CT; c++) {
        int col = col0 + (wv * CT + c) * 16 + m16;
        float bv = bias ? bias[col] : 0.f;
#pragma unroll
        for (int r = 0; r < 4; r++)
#pragma unroll
            for (int j = 0; j < 4; j++) {
                int row = row0 + r * 16 + q * 4 + j;
                if (row < M) {
                    float v = acc[r][c][j] + bv;
                    if (outB) outB[(size_t)row * Nc + col] = __float2bfloat16(v);
                    else      outF[(size_t)row * Nc + col] = v;
                }
            }
    }
}

// ===================== packing / conversion ==============================
__global__ void pack_x(const float* __restrict__ x, __hip_bfloat16* __restrict__ d) {
    int i = blockIdx.x * 256 + threadIdx.x;
    if (i >= NN * 32) return;
    int n = i >> 5, k = i & 31;
    d[i] = __float2bfloat16(k < 13 ? x[n * 13 + k] : 0.f);
}
__global__ void pack_ea(const float* __restrict__ ea, __hip_bfloat16* __restrict__ d) {
    int i = blockIdx.x * 256 + threadIdx.x;
    if (i >= EE * 64) return;
    int e = i >> 6, k = i & 63;
    d[i] = __float2bfloat16(k < 51 ? ea[e * 51 + k] : 0.f);
}
// dst[(rowoff+n)*Kpad + k] = W[k*Nc + n] (zero-padded to Kpad)
__global__ void pack_wt(const float* __restrict__ W, __hip_bfloat16* __restrict__ dst,
                        int K, int Nc, int Kpad, int rowoff) {
    int i = blockIdx.x * 256 + threadIdx.x;
    if (i >= Nc * Kpad) return;
    int n = i / Kpad, k = i - n * Kpad;
    float v = (k < K) ? W[k * Nc + n] : 0.f;
    dst[(size_t)(rowoff + n) * Kpad + k] = __float2bfloat16(v);
}
__global__ void cat2(const float* __restrict__ a, const float* __restrict__ b,
                     float* __restrict__ o) {
    int i = blockIdx.x * 256 + threadIdx.x;
    if (i < 512) o[i] = i < 256 ? a[i] : b[i - 256];
}

// ===================== CSR build =========================================
__global__ void hist_deg(const int* __restrict__ ei, int* __restrict__ deg) {
    int e = blockIdx.x * 256 + threadIdx.x;
    if (e < EE) atomicAdd(&deg[ei[EE + e]], 1);
}
__global__ void scan1(const int* __restrict__ deg, int* __restrict__ partial,
                      int* __restrict__ bsum) {
    __shared__ int sh[256];
    int t = threadIdx.x, i = blockIdx.x * 256 + t;
    int v = (i < NN) ? deg[i] : 0;
    sh[t] = v; __syncthreads();
    for (int off = 1; off < 256; off <<= 1) {
        int x = (t >= off) ? sh[t - off] : 0;
        __syncthreads();
        sh[t] += x;
        __syncthreads();
    }
    if (i < NN) partial[i] = sh[t] - v;
    if (t == 255) bsum[blockIdx.x] = sh[255];
}
__global__ void scan2(int* __restrict__ bsum, int nb) {
    __shared__ int sh[256];
    int t = threadIdx.x;
    int v = (t < nb) ? bsum[t] : 0;
    sh[t] = v; __syncthreads();
    for (int off = 1; off < 256; off <<= 1) {
        int x = (t >= off) ? sh[t - off] : 0;
        __syncthreads();
        sh[t] += x;
        __syncthreads();
    }
    if (t < nb) bsum[t] = sh[t] - v;
}
__global__ void scan3(const int* __restrict__ partial, const int* __restrict__ bsum,
                      int* __restrict__ start) {
    int i = blockIdx.x * 256 + threadIdx.x;
    if (i < NN) start[i] = partial[i] + bsum[i >> 8];
    else if (i == NN) start[NN] = EE;
}
__global__ void scatter_e(const int* __restrict__ ei, int* __restrict__ cursor,
                          const int* __restrict__ start, int* __restrict__ eidx) {
    int e = blockIdx.x * 256 + threadIdx.x;
    if (e >= EE) return;
    int d = ei[EE + e];
    int p = atomicAdd(&cursor[d], 1);
    eidx[start[d] + p] = e;
}

// ===================== edge logits (chunked over edges) ==================
// wave = one edge (all 4 heads); lane l covers channels h*64+l.
// eeb is chunk-local: row (e - e0).
__global__ __launch_bounds__(256) void edge_logit(
    const __hip_bfloat16* __restrict__ xlr, const __hip_bfloat16* __restrict__ eeb,
    const float* __restrict__ att, const int* __restrict__ ei,
    float* __restrict__ logit, int e0, int ecount) {
    const int lane = threadIdx.x & 63, wv = threadIdx.x >> 6;
    float attv[4];
#pragma unroll
    for (int h = 0; h < 4; h++) attv[h] = att[h * 64 + lane];
    for (int r = blockIdx.x * 4 + wv; r < ecount; r += gridDim.x * 4) {
        int e = e0 + r;
        int src = ei[e], dst = ei[EE + e];
        const __hip_bfloat16* xl = xlr + (size_t)src * 512;
        const __hip_bfloat16* xr = xlr + (size_t)dst * 512 + 256;
        const __hip_bfloat16* ep = eeb + (size_t)r * 256;
        float v[4];
#pragma unroll
        for (int h = 0; h < 4; h++) {
            float s = __bfloat162float(xl[h * 64 + lane]) +
                      __bfloat162float(xr[h * 64 + lane]) +
                      __bfloat162float(ep[h * 64 + lane]);
            s = s > 0.f ? s : 0.2f * s;
            v[h] = s * attv[h];
        }
#pragma unroll
        for (int off = 32; off; off >>= 1)
#pragma unroll
            for (int h = 0; h < 4; h++) v[h] += __shfl_xor(v[h], off);
        if (lane < 4) {
            float rr = lane == 0 ? v[0] : lane == 1 ? v[1] : lane == 2 ? v[2] : v[3];
            logit[e * 4 + lane] = rr;
        }
    }
}

// ===================== fused segment softmax + aggregate =================
// wave = one dst node. Fuses segment max, denom, alpha-weighted sum, bias.
__global__ __launch_bounds__(256) void aggregate_csr(
    const __hip_bfloat16* __restrict__ xlr, const float* __restrict__ logit,
    const int* __restrict__ ei, const int* __restrict__ eidx,
    const int* __restrict__ start, const float* __restrict__ bias,
    __hip_bfloat16* __restrict__ outb) {
    const int lane = threadIdx.x & 63, wv = threadIdx.x >> 6;
    const int dst = blockIdx.x * 4 + wv;
    if (dst >= NN) return;
    const int s0 = start[dst];
    const int deg = start[dst + 1] - s0;

    float m[4] = {-3.4e38f, -3.4e38f, -3.4e38f, -3.4e38f};
    float lg[4] = {0.f, 0.f, 0.f, 0.f};
    int mysrc = 0;
    if (lane < deg) {
        int e = eidx[s0 + lane];
        mysrc = ei[e];
        float4 l4 = ((const float4*)logit)[e];
        lg[0] = l4.x; lg[1] = l4.y; lg[2] = l4.z; lg[3] = l4.w;
        m[0] = l4.x; m[1] = l4.y; m[2] = l4.z; m[3] = l4.w;
    }
    for (int i = 64 + lane; i < deg; i += 64) {            // rare: deg>64
        int e = eidx[s0 + i];
        float4 l4 = ((const float4*)logit)[e];
        m[0] = fmaxf(m[0], l4.x); m[1] = fmaxf(m[1], l4.y);
        m[2] = fmaxf(m[2], l4.z); m[3] = fmaxf(m[3], l4.w);
    }
#pragma unroll
    for (int off = 32; off; off >>= 1)
#pragma unroll
        for (int h = 0; h < 4; h++) m[h] = fmaxf(m[h], __shfl_xor(m[h], off));

    float w[4], d[4];
#pragma unroll
    for (int h = 0; h < 4; h++) {
        w[h] = (lane < deg) ? __expf(lg[h] - m[h]) : 0.f;
        d[h] = w[h];
    }
    for (int i = 64 + lane; i < deg; i += 64) {            // rare
        int e = eidx[s0 + i];
        float4 l4 = ((const float4*)logit)[e];
        d[0] += __expf(l4.x - m[0]); d[1] += __expf(l4.y - m[1]);
        d[2] += __expf(l4.z - m[2]); d[3] += __expf(l4.w - m[3]);
    }
#pragma unroll
    for (int off = 32; off; off >>= 1)
#pragma unroll
        for (int h = 0; h < 4; h++) d[h] += __shfl_xor(d[h], off);
#pragma unroll
    for (int h = 0; h < 4; h++) d[h] = 1.f / (d[h] + 1e-16f);

    float acc[4];
#pragma unroll
    for (int h = 0; h < 4; h++) acc[h] = bias[h * 64 + lane];

    const int dcap = deg < 64 ? deg : 64;
    for (int i = 0; i < dcap; i++) {
        int src = __shfl(mysrc, i);
        float a0 = __shfl(w[0], i) * d[0];
        float a1 = __shfl(w[1], i) * d[1];
        float a2 = __shfl(w[2], i) * d[2];
        float a3 = __shfl(w[3], i) * d[3];
        const __hip_bfloat16* xp = xlr + (size_t)src * 512;
        acc[0] += __bfloat162float(xp[lane]) * a0;
        acc[1] += __bfloat162float(xp[64 + lane]) * a1;
        acc[2] += __bfloat162float(xp[128 + lane]) * a2;
        acc[3] += __bfloat162float(xp[192 + lane]) * a3;
    }
    for (int i = 64; i < deg; i++) {                       // rare
        int e = eidx[s0 + i];
        int src = ei[e];
        float4 l4 = ((const float4*)logit)[e];
        float a0 = __expf(l4.x - m[0]) * d[0];
        float a1 = __expf(l4.y - m[1]) * d[1];
        float a2 = __expf(l4.z - m[2]) * d[2];
        float a3 = __expf(l4.w - m[3]) * d[3];
        const __hip_bfloat16* xp = xlr + (size_t)src * 512;
        acc[0] += __bfloat162float(xp[lane]) * a0;
        acc[1] += __bfloat162float(xp[64 + lane]) * a1;
        acc[2] += __bfloat162float(xp[128 + lane]) * a2;
        acc[3] += __bfloat162float(xp[192 + lane]) * a3;
    }
#pragma unroll
    for (int h = 0; h < 4; h++)
        outb[(size_t)dst * 256 + h * 64 + lane] = __float2bfloat16(acc[h]);
}

// ===================== pooling ===========================================
__device__ __forceinline__ unsigned fmap(float f) {
    unsigned u = __float_as_uint(f);
    return (u & 0x80000000u) ? ~u : (u | 0x80000000u);
}
__device__ __forceinline__ float funmap(unsigned u) {
    return (u & 0x80000000u) ? __uint_as_float(u & 0x7FFFFFFFu)
                             : __uint_as_float(~u);
}

__global__ void pool_max(const float* __restrict__ a, const int* __restrict__ batch,
                         unsigned* __restrict__ am) {
    const int c = threadIdx.x;
    const int n0 = blockIdx.x * 64;
    int curb = batch[n0];
    float m = -3.4e38f;
    const int nend = min(n0 + 64, NN);
    for (int n = n0; n < nend; n++) {
        int b = batch[n];
        float v = a[(size_t)n * HC + c];
        if (b != curb) { atomicMax(&am[curb * HC + c], fmap(m)); curb = b; m = v; }
        else           { m = fmaxf(m, v); }
    }
    atomicMax(&am[curb * HC + c], fmap(m));
}
__global__ void pool_expsum(float* __restrict__ a, const int* __restrict__ batch,
                            const unsigned* __restrict__ am, float* __restrict__ ad) {
    const int c = threadIdx.x;
    const int n0 = blockIdx.x * 64;
    int curb = batch[n0];
    float s = 0.f;
    float mcur = funmap(am[curb * HC + c]);
    const int nend = min(n0 + 64, NN);
    for (int n = n0; n < nend; n++) {
        int b = batch[n];
        if (b != curb) {
            atomicAdd(&ad[curb * HC + c], s);
            curb = b; s = 0.f; mcur = funmap(am[b * HC + c]);
        }
        float w = __expf(a[(size_t)n * HC + c] - mcur);
        a[(size_t)n * HC + c] = w;
        s += w;
    }
    atomicAdd(&ad[curb * HC + c], s);
}
__global__ void pool_weighted(const __hip_bfloat16* __restrict__ h2,
                              const float* __restrict__ aw,
                              const int* __restrict__ batch,
                              const float* __restrict__ ad, float* __restrict__ g) {
    const int c = threadIdx.x;
    const int n0 = blockIdx.x * 64;
    int curb = batch[n0];
    float s = 0.f;
    float dcur = ad[curb * HC + c] + 1e-16f;
    const int nend = min(n0 + 64, NN);
    for (int n = n0; n < nend; n++) {
        int b = batch[n];
        if (b != curb) {
            atomicAdd(&g[curb * HC + c], s);
            curb = b; s = 0.f; dcur = ad[b * HC + c] + 1e-16f;
        }
        s += __bfloat162float(h2[(size_t)n * HC + c]) * aw[(size_t)n * HC + c] / dcur;
    }
    atomicAdd(&g[curb * HC + c], s);
}

// ===================== head MLP ==========================================
__global__ void mlp_lin1(const float* __restrict__ g, const float* __restrict__ Wo1,
                         const float* __restrict__ bo1, float* __restrict__ y) {
    const int c = threadIdx.x;
    const int r = blockIdx.x;
    float acc = bo1[c];
#pragma unroll 4
    for (int k = 0; k < HC; k++) acc = fmaf(g[r * HC + k], Wo1[k * HC + c], acc);
    y[r * HC + c] = acc;
}
__global__ void bn_relu(float* __restrict__ y, const float* __restrict__ gamma,
                        const float* __restrict__ beta) {
    const int c = threadIdx.x;
    float s = 0.f, sq = 0.f;
    for (int r = 0; r < BB; r++) { float v = y[r * HC + c]; s += v; sq += v * v; }
    float mu  = s * (1.f / BB);
    float var = sq * (1.f / BB) - mu * mu;
    float inv = rsqrtf(var + 1e-5f) * gamma[c];
    float bt  = beta[c];
    for (int r = 0; r < BB; r++) {
        float v = (y[r * HC + c] - mu) * inv + bt;
        y[r * HC + c] = v > 0.f ? v : 0.f;
    }
}
__global__ void mlp_lin2(const float* __restrict__ y, const float* __restrict__ Wo2,
                         const float* __restrict__ bo2, float* __restrict__ out) {
    const int j = blockIdx.x * 256 + threadIdx.x;
    const int r = blockIdx.y;
    if (j >= 2001) return;
    float acc = bo2[j];
#pragma unroll 4
    for (int k = 0; k < HC; k++) acc = fmaf(y[r * HC + k], Wo2[k * 2001 + j], acc);
    out[r * 2001 + j] = acc > 0.f ? acc : 0.01f * acc;
}

// ===================== launcher ==========================================
extern "C" void kernel_launch(void* const* d_in, const int* in_sizes, int n_in,
                              void* d_out, int out_size, void* d_ws, size_t ws_size,
                              hipStream_t stream) {
    const float* x     = (const float*)d_in[0];
    const int*   ei    = (const int*)d_in[1];
    const float* ea    = (const float*)d_in[2];
    const int*   batch = (const int*)d_in[3];
    const float* W0 = (const float*)d_in[4];  const float* b0 = (const float*)d_in[5];
    const float* Wl1 = (const float*)d_in[6]; const float* bl1 = (const float*)d_in[7];
    const float* Wr1 = (const float*)d_in[8]; const float* br1 = (const float*)d_in[9];
    const float* We1 = (const float*)d_in[10]; const float* att1 = (const float*)d_in[11];
    const float* bias1 = (const float*)d_in[12];
    const float* Wl2 = (const float*)d_in[13]; const float* bl2 = (const float*)d_in[14];
    const float* Wr2 = (const float*)d_in[15]; const float* br2 = (const float*)d_in[16];
    const float* We2 = (const float*)d_in[17]; const float* att2 = (const float*)d_in[18];
    const float* bias2 = (const float*)d_in[19];
    const float* Wp = (const float*)d_in[20]; const float* bp = (const float*)d_in[21];
    const float* Wo1 = (const float*)d_in[22]; const float* bo1 = (const float*)d_in[23];
    const float* gamma = (const float*)d_in[24]; const float* beta = (const float*)d_in[25];
    const float* Wo2 = (const float*)d_in[26]; const float* bo2 = (const float*)d_in[27];
    float* out = (float*)d_out;

    // ---- workspace carve-up (256B aligned), total ~155 MB ----
    char* p = (char*)d_ws;
    auto alloc = [&](size_t bytes) { char* r = p; p += (bytes + 255) & ~(size_t)255; return r; };
    const int MP = 30016;      // padded node rows (469*64)
    const int EP = 300032;     // padded edge rows (4*75008)
    const int ECH = 75008;     // edge chunk (1172*64)
    __hip_bfloat16* xpad  = (__hip_bfloat16*)alloc((size_t)MP * 32 * 2);
    __hip_bfloat16* eapad = (__hip_bfloat16*)alloc((size_t)EP * 64 * 2);
    __hip_bfloat16* W0t   = (__hip_bfloat16*)alloc(128 * 32 * 2);
    __hip_bfloat16* W1t   = (__hip_bfloat16*)alloc(512 * 128 * 2);
    __hip_bfloat16* We1t  = (__hip_bfloat16*)alloc(256 * 64 * 2);
    __hip_bfloat16* W2t   = (__hip_bfloat16*)alloc(512 * 256 * 2);
    __hip_bfloat16* We2t  = (__hip_bfloat16*)alloc(256 * 64 * 2);
    __hip_bfloat16* Wpt   = (__hip_bfloat16*)alloc(256 * 256 * 2);
    float* bcat1 = (float*)alloc(512 * 4);
    float* bcat2 = (float*)alloc(512 * 4);
    __hip_bfloat16* h0b  = (__hip_bfloat16*)alloc((size_t)MP * 128 * 2);
    __hip_bfloat16* xlrb = (__hip_bfloat16*)alloc((size_t)MP * 512 * 2);
    __hip_bfloat16* h1b  = (__hip_bfloat16*)alloc((size_t)MP * 256 * 2);
    __hip_bfloat16* h2b  = (__hip_bfloat16*)alloc((size_t)MP * 256 * 2);
    // chunk ee buffer (bf16, ECH*256) aliases pooling's fp32 abuf (MP*256):
    // ee chunks are consumed before pooling starts.
    char* bigreg = alloc((size_t)ECH * 256 * 2);   // 38.4 MB >= MP*256*4=30.7MB? NO -> take max
    // NOTE: abuf needs MP*256*4 = 30.74MB; chunk buf is ECH*256*2 = 38.4MB -> chunk is bigger.
    __hip_bfloat16* eeb = (__hip_bfloat16*)bigreg;
    float* abuf = (float*)bigreg;
    float* logit = (float*)alloc((size_t)EE * 4 * 4);
    int* deg    = (int*)alloc(NN * 4);
    int* cursor = (int*)alloc(NN * 4);
    int* partial= (int*)alloc(NN * 4);
    int* bsum   = (int*)alloc(256 * 4);
    int* start  = (int*)alloc((NN + 4) * 4);
    int* eidx   = (int*)alloc((size_t)EE * 4);
    unsigned* am = (unsigned*)alloc(BB * HC * 4);
    float* ad   = (float*)alloc(BB * HC * 4);
    float* g    = (float*)alloc(BB * HC * 4);
    float* ybuf = (float*)alloc(BB * HC * 4);

    const int NB = (NN + 255) / 256;   // 118 scan blocks

    // ---- input packing ----
    pack_x<<<(NN * 32 + 255) / 256, 256, 0, stream>>>(x, xpad);
    pack_ea<<<(EE * 64 + 255) / 256, 256, 0, stream>>>(ea, eapad);
    pack_wt<<<(128 * 32 + 255) / 256, 256, 0, stream>>>(W0, W0t, 13, 128, 32, 0);
    pack_wt<<<(256 * 128 + 255) / 256, 256, 0, stream>>>(Wl1, W1t, 128, 256, 128, 0);
    pack_wt<<<(256 * 128 + 255) / 256, 256, 0, stream>>>(Wr1, W1t, 128, 256, 128, 256);
    pack_wt<<<(256 * 64 + 255) / 256, 256, 0, stream>>>(We1, We1t, 51, 256, 64, 0);
    pack_wt<<<(256 * 256 + 255) / 256, 256, 0, stream>>>(Wl2, W2t, 256, 256, 256, 0);
    pack_wt<<<(256 * 256 + 255) / 256, 256, 0, stream>>>(Wr2, W2t, 256, 256, 256, 256);
    pack_wt<<<(256 * 64 + 255) / 256, 256, 0, stream>>>(We2, We2t, 51, 256, 64, 0);
    pack_wt<<<(256 * 256 + 255) / 256, 256, 0, stream>>>(Wp, Wpt, 256, 256, 256, 0);
    cat2<<<2, 256, 0, stream>>>(bl1, br1, bcat1);
    cat2<<<2, 256, 0, stream>>>(bl2, br2, bcat2);

    // ---- CSR build ----
    hipMemsetAsync(deg, 0, NN * 4, stream);
    hipMemsetAsync(cursor, 0, NN * 4, stream);
    hist_deg<<<(EE + 255) / 256, 256, 0, stream>>>(ei, deg);
    scan1<<<NB, 256, 0, stream>>>(deg, partial, bsum);
    scan2<<<1, 256, 0, stream>>>(bsum, NB);
    scan3<<<NB + 1, 256, 0, stream>>>(partial, bsum, start);
    scatter_e<<<(EE + 255) / 256, 256, 0, stream>>>(ei, cursor, start, eidx);

    // ---- init transform ----
    mfma_gemm<2><<<dim3(469, 1), 256, 0, stream>>>(
        (const ushort*)xpad, (const ushort*)W0t, b0, nullptr, h0b, NN, 128, 32);

    // ---- GAT layer 1 ----
    mfma_gemm<4><<<dim3(469, 2), 256, 0, stream>>>(
        (const ushort*)h0b, (const ushort*)W1t, bcat1, nullptr, xlrb, NN, 512, 128);
    for (int c = 0; c < 4; c++) {
        int e0 = c * ECH;
        int ecount = (EE - e0) < ECH ? (EE - e0) : ECH;
        mfma_gemm<4><<<dim3(ECH / 64, 1), 256, 0, stream>>>(
            (const ushort*)(eapad + (size_t)e0 * 64), (const ushort*)We1t,
            nullptr, nullptr, eeb, ecount, 256, 64);
        edge_logit<<<1024, 256, 0, stream>>>(xlrb, eeb, att1, ei, logit, e0, ecount);
    }
    aggregate_csr<<<(NN + 3) / 4, 256, 0, stream>>>(xlrb, logit, ei, eidx, start, bias1, h1b);

    // ---- GAT layer 2 ----
    mfma_gemm<4><<<dim3(469, 2), 256, 0, stream>>>(
        (const ushort*)h1b, (const ushort*)W2t, bcat2, nullptr, xlrb, NN, 512, 256);
    for (int c = 0; c < 4; c++) {
        int e0 = c * ECH;
        int ecount = (EE - e0) < ECH ? (EE - e0) : ECH;
        mfma_gemm<4><<<dim3(ECH / 64, 1), 256, 0, stream>>>(
            (const ushort*)(eapad + (size_t)e0 * 64), (const ushort*)We2t,
            nullptr, nullptr, eeb, ecount, 256, 64);
        edge_logit<<<1024, 256, 0, stream>>>(xlrb, eeb, att2, ei, logit, e0, ecount);
    }
    aggregate_csr<<<(NN + 3) / 4, 256, 0, stream>>>(xlrb, logit, ei, eidx, start, bias2, h2b);

    // ---- attention pooling ----
    mfma_gemm<4><<<dim3(469, 1), 256, 0, stream>>>(
        (const ushort*)h2b, (const ushort*)Wpt, bp, abuf, nullptr, NN, 256, 256);
    hipMemsetAsync(am, 0, BB * HC * 4, stream);
    hipMemsetAsync(ad, 0, BB * HC * 4, stream);
    hipMemsetAsync(g, 0, BB * HC * 4, stream);
    const int poolGrid = (NN + 63) / 64;
    pool_max<<<poolGrid, HC, 0, stream>>>(abuf, batch, am);
    pool_expsum<<<poolGrid, HC, 0, stream>>>(abuf, batch, am, ad);
    pool_weighted<<<poolGrid, HC, 0, stream>>>(h2b, abuf, batch, ad, g);

    // ---- head MLP ----
    mlp_lin1<<<BB, HC, 0, stream>>>(g, Wo1, bo1, ybuf);
    bn_relu<<<1, HC, 0, stream>>>(ybuf, gamma, beta);
    mlp_lin2<<<dim3(8, BB), 256, 0, stream>>>(ybuf, Wo2, bo2, out);
}

// Round 4
// 878.387 us; speedup vs baseline: 2.1733x; 1.1079x over previous
//
#include <hip/hip_runtime.h>
#include <hip/hip_bf16.h>

#define NN 30000
#define EE 300000
#define BB 64
#define HH 4
#define CC 64
#define HC 256

typedef __attribute__((ext_vector_type(8))) short short8;
typedef __attribute__((ext_vector_type(4))) float floatx4;

__device__ __forceinline__ float b2f(short x) {
    return __uint_as_float(((unsigned)(unsigned short)x) << 16);
}
__device__ __forceinline__ unsigned short f2b(float f) {
    __hip_bfloat16 h = __float2bfloat16(f);
    return *(unsigned short*)&h;
}

#define GLD16(gp, lp) __builtin_amdgcn_global_load_lds( \
    (const __attribute__((address_space(1))) void*)(gp), \
    (__attribute__((address_space(3))) void*)(lp), 16, 0, 0)

// ===================== bf16 MFMA GEMM (dense transforms) =================
// OUT[M,Nc] = A[M,K](bf16,row-major) @ Bt[Nc,K](bf16 pre-transposed) + bias
template<int CT>
__global__ __launch_bounds__(256) void mfma_gemm(
    const ushort* __restrict__ A, const ushort* __restrict__ Bt,
    const float* __restrict__ bias, float* __restrict__ outF,
    __hip_bfloat16* __restrict__ outB, int M, int Nc, int K) {
    __shared__ __align__(16) ushort lA[64 * 32];
    __shared__ __align__(16) ushort lB[CT * 64 * 32];
    const int tid = threadIdx.x, lane = tid & 63, wv = tid >> 6;
    const int row0 = blockIdx.x * 64, col0 = blockIdx.y * (CT * 64);

    floatx4 acc[4][CT];
#pragma unroll
    for (int r = 0; r < 4; r++)
#pragma unroll
        for (int c = 0; c < CT; c++) acc[r][c] = (floatx4){0.f, 0.f, 0.f, 0.f};

    const int arow = tid >> 2;
    const int sl   = (tid & 3) ^ ((tid >> 3) & 3);
    const ushort* ga = A + (size_t)(row0 + arow) * K + sl * 8;
    const int m16 = lane & 15, q = lane >> 4;

    for (int k0 = 0; k0 < K; k0 += 32) {
        __syncthreads();
        GLD16(ga + k0, &lA[tid * 8]);
#pragma unroll
        for (int j = 0; j < CT; j++) {
            const ushort* gb = Bt + (size_t)(col0 + j * 64 + arow) * K + k0 + sl * 8;
            GLD16(gb, &lB[j * 2048 + tid * 8]);
        }
        __syncthreads();
        short8 aF[4], bF[CT];
#pragma unroll
        for (int r = 0; r < 4; r++) {
            int rr = r * 16 + m16;
            aF[r] = *(const short8*)&lA[rr * 32 + ((q ^ ((rr >> 1) & 3)) << 3)];
        }
#pragma unroll
        for (int c = 0; c < CT; c++) {
            int nr = (wv * CT + c) * 16 + m16;
            bF[c] = *(const short8*)&lB[nr * 32 + ((q ^ ((nr >> 1) & 3)) << 3)];
        }
#pragma unroll
        for (int r = 0; r < 4; r++)
#pragma unroll
            for (int c = 0; c < CT; c++)
                acc[r][c] = __builtin_amdgcn_mfma_f32_16x16x32_bf16(aF[r], bF[c], acc[r][c], 0, 0, 0);
    }

#pragma unroll
    for (int c = 0; c < CT; c++) {
        int col = col0 + (wv * CT + c) * 16 + m16;
        float bv = bias ? bias[col] : 0.f;
#pragma unroll
        for (int r = 0; r < 4; r++)
#pragma unroll
            for (int j = 0; j < 4; j++) {
                int row = row0 + r * 16 + q * 4 + j;
                if (row < M) {
                    float v = acc[r][c][j] + bv;
                    if (outB) outB[(size_t)row * Nc + col] = __float2bfloat16(v);
                    else      outF[(size_t)row * Nc + col] = v;
                }
            }
    }
}

// ===================== fused ea@We GEMM + edge logit =====================
// One block = 64 edges. MFMA the [64,64]x[64,256] ee tile into LDS (never
// global), then logit[e,h] = sum_c att[h,c]*leaky(xl[src,hc]+xr[dst,hc]+ee).
__global__ __launch_bounds__(256) void edge_fused(
    const float* __restrict__ ea, const ushort* __restrict__ Bt,
    const float* __restrict__ att, const int* __restrict__ ei,
    const ushort* __restrict__ xlr, float* __restrict__ logit) {
    __shared__ __align__(16) char smem[40960];
    ushort* lA  = (ushort*)smem;            // 64 x 64  (8 KB)
    ushort* lB  = (ushort*)(smem + 8192);   // 256 x 64 (32 KB)
    ushort* eeS = (ushort*)smem;            // 64 x 256 (32 KB) alias
    __shared__ float satt[256];
    const int tid = threadIdx.x, lane = tid & 63, wv = tid >> 6;
    const int e0 = blockIdx.x * 64;
    satt[tid] = att[tid];

    // ---- stage A: ea fp32 -> bf16, XOR-swizzled [row][64] ----
    {
        const int row = tid >> 2, cg = tid & 3;
        const int e = e0 + row;
        float tmp[16];
#pragma unroll
        for (int m = 0; m < 16; m++) {
            int k = cg * 16 + m;
            tmp[m] = (e < EE && k < 51) ? ea[(size_t)e * 51 + k] : 0.f;
        }
#pragma unroll
        for (int cc = 0; cc < 2; cc++) {
            short8 v8;
#pragma unroll
            for (int j = 0; j < 8; j++) v8[j] = (short)f2b(tmp[cc * 8 + j]);
            int c = cg * 2 + cc;
            *(short8*)&lA[row * 64 + ((c ^ (row & 7)) << 3)] = v8;
        }
    }
    // ---- stage B: Bt [256][64] bf16 ----
    {
        const int n = tid;
#pragma unroll
        for (int c = 0; c < 8; c++) {
            short8 bv = *(const short8*)&Bt[(size_t)n * 64 + c * 8];
            *(short8*)&lB[n * 64 + ((c ^ (n & 7)) << 3)] = bv;
        }
    }
    __syncthreads();

    // ---- MFMA: 64x256 = A[64,64] x B[64,256] ----
    const int m16 = lane & 15, q = lane >> 4;
    floatx4 acc[4][4];
#pragma unroll
    for (int r = 0; r < 4; r++)
#pragma unroll
        for (int c = 0; c < 4; c++) acc[r][c] = (floatx4){0.f, 0.f, 0.f, 0.f};
#pragma unroll
    for (int k0 = 0; k0 < 2; k0++) {
        short8 aF[4], bF[4];
#pragma unroll
        for (int r = 0; r < 4; r++) {
            int rr = r * 16 + m16;
            aF[r] = *(const short8*)&lA[rr * 64 + (((k0 * 4 + q) ^ (rr & 7)) << 3)];
        }
#pragma unroll
        for (int c = 0; c < 4; c++) {
            int nr = (wv * 4 + c) * 16 + m16;
            bF[c] = *(const short8*)&lB[nr * 64 + (((k0 * 4 + q) ^ (nr & 7)) << 3)];
        }
#pragma unroll
        for (int r = 0; r < 4; r++)
#pragma unroll
            for (int c = 0; c < 4; c++)
                acc[r][c] = __builtin_amdgcn_mfma_f32_16x16x32_bf16(aF[r], bF[c], acc[r][c], 0, 0, 0);
    }
    __syncthreads();   // all waves done reading lA/lB before aliasing as eeS

    // ---- park ee tile in LDS (swizzled [row][256]) ----
#pragma unroll
    for (int r = 0; r < 4; r++)
#pragma unroll
        for (int cc = 0; cc < 4; cc++)
#pragma unroll
            for (int j = 0; j < 4; j++) {
                int row = r * 16 + q * 4 + j;
                int col = (wv * 4 + cc) * 16 + m16;
                eeS[row * 256 + (((col >> 3) ^ (row & 31)) << 3) + (col & 7)] =
                    f2b(acc[r][cc][j]);
            }
    __syncthreads();

    // ---- logit: thread = (edge el, head h) ----
    const int el = tid >> 2, h = tid & 3;
    const int e = e0 + el;
    if (e < EE) {
        int src = ei[e], dstn = ei[EE + e];
        const ushort* xlp = xlr + (size_t)src * 512 + h * 64;
        const ushort* xrp = xlr + (size_t)dstn * 512 + 256 + h * 64;
        float s = 0.f;
#pragma unroll
        for (int c = 0; c < 8; c++) {
            short8 xlv = *(const short8*)(xlp + c * 8);
            short8 xrv = *(const short8*)(xrp + c * 8);
            short8 eev = *(const short8*)&eeS[el * 256 + (((h * 8 + c) ^ (el & 31)) << 3)];
#pragma unroll
            for (int j = 0; j < 8; j++) {
                float v = b2f(xlv[j]) + b2f(xrv[j]) + b2f(eev[j]);
                v = v > 0.f ? v : 0.2f * v;
                s += v * satt[h * 64 + c * 8 + j];
            }
        }
        logit[(size_t)e * 4 + h] = s;
    }
}

// ===================== packing ===========================================
__global__ void pack_x(const float* __restrict__ x, __hip_bfloat16* __restrict__ d) {
    int i = blockIdx.x * 256 + threadIdx.x;
    if (i >= NN * 32) return;
    int n = i >> 5, k = i & 31;
    d[i] = __float2bfloat16(k < 13 ? x[n * 13 + k] : 0.f);
}
struct PackJob { const float* W; __hip_bfloat16* dst; int K, Nc, Kpad, rowoff; };
struct PackJobs { PackJob j[8]; };
__global__ void pack_all(PackJobs jobs) {
    PackJob jb = jobs.j[blockIdx.y];
    int tot = jb.Nc * jb.Kpad;
    for (int i = blockIdx.x * 256 + threadIdx.x; i < tot; i += gridDim.x * 256) {
        int n = i / jb.Kpad, k = i - n * jb.Kpad;
        float v = (k < jb.K) ? jb.W[k * jb.Nc + n] : 0.f;
        jb.dst[(size_t)(jb.rowoff + n) * jb.Kpad + k] = __float2bfloat16(v);
    }
}
__global__ void cat2(const float* __restrict__ a, const float* __restrict__ b,
                     float* __restrict__ o) {
    int i = blockIdx.x * 256 + threadIdx.x;
    if (i < 512) o[i] = i < 256 ? a[i] : b[i - 256];
}

// ===================== CSR build =========================================
__global__ void hist_deg(const int* __restrict__ ei, int* __restrict__ deg) {
    int e = blockIdx.x * 256 + threadIdx.x;
    if (e < EE) atomicAdd(&deg[ei[EE + e]], 1);
}
__global__ void scan1(const int* __restrict__ deg, int* __restrict__ partial,
                      int* __restrict__ bsum) {
    __shared__ int sh[256];
    int t = threadIdx.x, i = blockIdx.x * 256 + t;
    int v = (i < NN) ? deg[i] : 0;
    sh[t] = v; __syncthreads();
    for (int off = 1; off < 256; off <<= 1) {
        int x = (t >= off) ? sh[t - off] : 0;
        __syncthreads();
        sh[t] += x;
        __syncthreads();
    }
    if (i < NN) partial[i] = sh[t] - v;
    if (t == 255) bsum[blockIdx.x] = sh[255];
}
__global__ void scan2(int* __restrict__ bsum, int nb) {
    __shared__ int sh[256];
    int t = threadIdx.x;
    int v = (t < nb) ? bsum[t] : 0;
    sh[t] = v; __syncthreads();
    for (int off = 1; off < 256; off <<= 1) {
        int x = (t >= off) ? sh[t - off] : 0;
        __syncthreads();
        sh[t] += x;
        __syncthreads();
    }
    if (t < nb) bsum[t] = sh[t] - v;
}
__global__ void scan3(const int* __restrict__ partial, const int* __restrict__ bsum,
                      int* __restrict__ start) {
    int i = blockIdx.x * 256 + threadIdx.x;
    if (i < NN) start[i] = partial[i] + bsum[i >> 8];
    else if (i == NN) start[NN] = EE;
}
__global__ void scatter_e(const int* __restrict__ ei, int* __restrict__ cursor,
                          const int* __restrict__ start, int* __restrict__ eidx) {
    int e = blockIdx.x * 256 + threadIdx.x;
    if (e >= EE) return;
    int d = ei[EE + e];
    int p = atomicAdd(&cursor[d], 1);
    eidx[start[d] + p] = e;
}

// ===================== fused segment softmax + aggregate =================
// wave = one dst node; lane owns channels 4l..4l+3 (single head l>>4).
__global__ __launch_bounds__(256) void aggregate_csr(
    const ushort* __restrict__ xlr, const float* __restrict__ logit,
    const int* __restrict__ ei, const int* __restrict__ eidx,
    const int* __restrict__ start, const float* __restrict__ bias,
    ushort* __restrict__ outb) {
    const int lane = threadIdx.x & 63, wv = threadIdx.x >> 6;
    const int dst = blockIdx.x * 4 + wv;
    if (dst >= NN) return;
    const int s0 = start[dst];
    const int deg = start[dst + 1] - s0;
    const int h = lane >> 4;

    float m[4] = {-3.4e38f, -3.4e38f, -3.4e38f, -3.4e38f};
    float lg[4] = {0.f, 0.f, 0.f, 0.f};
    int mysrc = 0;
    if (lane < deg) {
        int e = eidx[s0 + lane];
        mysrc = ei[e];
        float4 l4 = ((const float4*)logit)[e];
        lg[0] = l4.x; lg[1] = l4.y; lg[2] = l4.z; lg[3] = l4.w;
        m[0] = l4.x; m[1] = l4.y; m[2] = l4.z; m[3] = l4.w;
    }
    for (int i = 64 + lane; i < deg; i += 64) {
        int e = eidx[s0 + i];
        float4 l4 = ((const float4*)logit)[e];
        m[0] = fmaxf(m[0], l4.x); m[1] = fmaxf(m[1], l4.y);
        m[2] = fmaxf(m[2], l4.z); m[3] = fmaxf(m[3], l4.w);
    }
#pragma unroll
    for (int off = 32; off; off >>= 1)
#pragma unroll
        for (int k = 0; k < 4; k++) m[k] = fmaxf(m[k], __shfl_xor(m[k], off));

    float w[4], d[4];
#pragma unroll
    for (int k = 0; k < 4; k++) {
        w[k] = (lane < deg) ? __expf(lg[k] - m[k]) : 0.f;
        d[k] = w[k];
    }
    for (int i = 64 + lane; i < deg; i += 64) {
        int e = eidx[s0 + i];
        float4 l4 = ((const float4*)logit)[e];
        d[0] += __expf(l4.x - m[0]); d[1] += __expf(l4.y - m[1]);
        d[2] += __expf(l4.z - m[2]); d[3] += __expf(l4.w - m[3]);
    }
#pragma unroll
    for (int off = 32; off; off >>= 1)
#pragma unroll
        for (int k = 0; k < 4; k++) d[k] += __shfl_xor(d[k], off);
    const float dh = 1.f / (((h == 0) ? d[0] : (h == 1) ? d[1] : (h == 2) ? d[2] : d[3]) + 1e-16f);
    const float mh = (h == 0) ? m[0] : (h == 1) ? m[1] : (h == 2) ? m[2] : m[3];

    float4 b4 = ((const float4*)bias)[lane];
    float a0 = b4.x, a1 = b4.y, a2 = b4.z, a3 = b4.w;

    const int dcap = deg < 64 ? deg : 64;
    for (int i = 0; i < dcap; i++) {
        int srcv = __shfl(mysrc, i);
        float s0v = __shfl(w[0], i), s1v = __shfl(w[1], i);
        float s2v = __shfl(w[2], i), s3v = __shfl(w[3], i);
        float aw = ((h == 0) ? s0v : (h == 1) ? s1v : (h == 2) ? s2v : s3v) * dh;
        ushort4 xv = *(const ushort4*)(xlr + (size_t)srcv * 512 + lane * 4);
        a0 += b2f(xv.x) * aw; a1 += b2f(xv.y) * aw;
        a2 += b2f(xv.z) * aw; a3 += b2f(xv.w) * aw;
    }
    for (int i = 64; i < deg; i++) {
        int e = eidx[s0 + i];
        int srcv = ei[e];
        float4 l4 = ((const float4*)logit)[e];
        float lh = (h == 0) ? l4.x : (h == 1) ? l4.y : (h == 2) ? l4.z : l4.w;
        float aw = __expf(lh - mh) * dh;
        ushort4 xv = *(const ushort4*)(xlr + (size_t)srcv * 512 + lane * 4);
        a0 += b2f(xv.x) * aw; a1 += b2f(xv.y) * aw;
        a2 += b2f(xv.z) * aw; a3 += b2f(xv.w) * aw;
    }
    ushort4 ov;
    ov.x = f2b(a0); ov.y = f2b(a1); ov.z = f2b(a2); ov.w = f2b(a3);
    *(ushort4*)(outb + (size_t)dst * 256 + lane * 4) = ov;
}

// ===================== single-pass pooling ===============================
__global__ void pool_fused(const float* __restrict__ a, const __hip_bfloat16* __restrict__ h2,
                           const int* __restrict__ batch, float* __restrict__ g) {
    const int b = blockIdx.x, c = threadIdx.x;
    __shared__ int sb[2];
    if (c < 2) {
        int key = b + c, lo = 0, hi = NN;
        while (lo < hi) { int mid = (lo + hi) >> 1; if (batch[mid] < key) lo = mid + 1; else hi = mid; }
        sb[c] = lo;
    }
    __syncthreads();
    const int lo = sb[0], hi = sb[1];
    float m = -3.4e38f;
    for (int n = lo; n < hi; n++) m = fmaxf(m, a[(size_t)n * HC + c]);
    float den = 0.f, num = 0.f;
    for (int n = lo; n < hi; n++) {
        float w = __expf(a[(size_t)n * HC + c] - m);
        den += w;
        num += __bfloat162float(h2[(size_t)n * HC + c]) * w;
    }
    g[b * HC + c] = num / (den + 1e-16f);
}

// ===================== head MLP ==========================================
__global__ void mlp_lin1(const float* __restrict__ g, const float* __restrict__ Wo1,
                         const float* __restrict__ bo1, float* __restrict__ y) {
    const int c = threadIdx.x;
    const int r = blockIdx.x;
    float acc = bo1[c];
#pragma unroll 4
    for (int k = 0; k < HC; k++) acc = fmaf(g[r * HC + k], Wo1[k * HC + c], acc);
    y[r * HC + c] = acc;
}
__global__ void bn_relu(float* __restrict__ y, const float* __restrict__ gamma,
                        const float* __restrict__ beta) {
    const int c = threadIdx.x;
    float s = 0.f, sq = 0.f;
    for (int r = 0; r < BB; r++) { float v = y[r * HC + c]; s += v; sq += v * v; }
    float mu  = s * (1.f / BB);
    float var = sq * (1.f / BB) - mu * mu;
    float inv = rsqrtf(var + 1e-5f) * gamma[c];
    float bt  = beta[c];
    for (int r = 0; r < BB; r++) {
        float v = (y[r * HC + c] - mu) * inv + bt;
        y[r * HC + c] = v > 0.f ? v : 0.f;
    }
}
__global__ void mlp_lin2(const float* __restrict__ y, const float* __restrict__ Wo2,
                         const float* __restrict__ bo2, float* __restrict__ out) {
    const int j = blockIdx.x * 256 + threadIdx.x;
    const int r = blockIdx.y;
    if (j >= 2001) return;
    float acc = bo2[j];
#pragma unroll 4
    for (int k = 0; k < HC; k++) acc = fmaf(y[r * HC + k], Wo2[k * 2001 + j], acc);
    out[r * 2001 + j] = acc > 0.f ? acc : 0.01f * acc;
}

// ===================== launcher ==========================================
extern "C" void kernel_launch(void* const* d_in, const int* in_sizes, int n_in,
                              void* d_out, int out_size, void* d_ws, size_t ws_size,
                              hipStream_t stream) {
    const float* x     = (const float*)d_in[0];
    const int*   ei    = (const int*)d_in[1];
    const float* ea    = (const float*)d_in[2];
    const int*   batch = (const int*)d_in[3];
    const float* W0 = (const float*)d_in[4];  const float* b0 = (const float*)d_in[5];
    const float* Wl1 = (const float*)d_in[6]; const float* bl1 = (const float*)d_in[7];
    const float* Wr1 = (const float*)d_in[8]; const float* br1 = (const float*)d_in[9];
    const float* We1 = (const float*)d_in[10]; const float* att1 = (const float*)d_in[11];
    const float* bias1 = (const float*)d_in[12];
    const float* Wl2 = (const float*)d_in[13]; const float* bl2 = (const float*)d_in[14];
    const float* Wr2 = (const float*)d_in[15]; const float* br2 = (const float*)d_in[16];
    const float* We2 = (const float*)d_in[17]; const float* att2 = (const float*)d_in[18];
    const float* bias2 = (const float*)d_in[19];
    const float* Wp = (const float*)d_in[20]; const float* bp = (const float*)d_in[21];
    const float* Wo1 = (const float*)d_in[22]; const float* bo1 = (const float*)d_in[23];
    const float* gamma = (const float*)d_in[24]; const float* beta = (const float*)d_in[25];
    const float* Wo2 = (const float*)d_in[26]; const float* bo2 = (const float*)d_in[27];
    float* out = (float*)d_out;

    // ---- workspace carve-up (256B aligned), ~110 MB ----
    char* p = (char*)d_ws;
    auto alloc = [&](size_t bytes) { char* r = p; p += (bytes + 255) & ~(size_t)255; return r; };
    const int MP = 30016;      // padded node rows (469*64)
    __hip_bfloat16* xpad  = (__hip_bfloat16*)alloc((size_t)MP * 32 * 2);
    __hip_bfloat16* W0t   = (__hip_bfloat16*)alloc(128 * 32 * 2);
    __hip_bfloat16* W1t   = (__hip_bfloat16*)alloc(512 * 128 * 2);
    __hip_bfloat16* We1t  = (__hip_bfloat16*)alloc(256 * 64 * 2);
    __hip_bfloat16* W2t   = (__hip_bfloat16*)alloc(512 * 256 * 2);
    __hip_bfloat16* We2t  = (__hip_bfloat16*)alloc(256 * 64 * 2);
    __hip_bfloat16* Wpt   = (__hip_bfloat16*)alloc(256 * 256 * 2);
    float* bcat1 = (float*)alloc(512 * 4);
    float* bcat2 = (float*)alloc(512 * 4);
    __hip_bfloat16* h0b  = (__hip_bfloat16*)alloc((size_t)MP * 128 * 2);
    __hip_bfloat16* xlrb = (__hip_bfloat16*)alloc((size_t)MP * 512 * 2);
    __hip_bfloat16* h1b  = (__hip_bfloat16*)alloc((size_t)MP * 256 * 2);
    __hip_bfloat16* h2b  = (__hip_bfloat16*)alloc((size_t)MP * 256 * 2);
    float* abuf = (float*)alloc((size_t)MP * 256 * 4);
    float* logit = (float*)alloc((size_t)EE * 4 * 4);
    int* deg    = (int*)alloc(NN * 4);
    int* cursor = (int*)alloc(NN * 4);
    int* partial= (int*)alloc(NN * 4);
    int* bsum   = (int*)alloc(256 * 4);
    int* start  = (int*)alloc((NN + 4) * 4);
    int* eidx   = (int*)alloc((size_t)EE * 4);
    float* g    = (float*)alloc(BB * HC * 4);
    float* ybuf = (float*)alloc(BB * HC * 4);

    const int NB = (NN + 255) / 256;

    // ---- input / weight packing ----
    pack_x<<<(NN * 32 + 255) / 256, 256, 0, stream>>>(x, xpad);
    PackJobs pj;
    pj.j[0] = {W0,  W0t, 13, 128, 32, 0};
    pj.j[1] = {Wl1, W1t, 128, 256, 128, 0};
    pj.j[2] = {Wr1, W1t, 128, 256, 128, 256};
    pj.j[3] = {We1, We1t, 51, 256, 64, 0};
    pj.j[4] = {Wl2, W2t, 256, 256, 256, 0};
    pj.j[5] = {Wr2, W2t, 256, 256, 256, 256};
    pj.j[6] = {We2, We2t, 51, 256, 64, 0};
    pj.j[7] = {Wp,  Wpt, 256, 256, 256, 0};
    pack_all<<<dim3(64, 8), 256, 0, stream>>>(pj);
    cat2<<<2, 256, 0, stream>>>(bl1, br1, bcat1);
    cat2<<<2, 256, 0, stream>>>(bl2, br2, bcat2);

    // ---- CSR build ----
    hipMemsetAsync(deg, 0, NN * 4, stream);
    hipMemsetAsync(cursor, 0, NN * 4, stream);
    hist_deg<<<(EE + 255) / 256, 256, 0, stream>>>(ei, deg);
    scan1<<<NB, 256, 0, stream>>>(deg, partial, bsum);
    scan2<<<1, 256, 0, stream>>>(bsum, NB);
    scan3<<<NB + 1, 256, 0, stream>>>(partial, bsum, start);
    scatter_e<<<(EE + 255) / 256, 256, 0, stream>>>(ei, cursor, start, eidx);

    // ---- init transform ----
    mfma_gemm<2><<<dim3(469, 1), 256, 0, stream>>>(
        (const ushort*)xpad, (const ushort*)W0t, b0, nullptr, h0b, NN, 128, 32);

    // ---- GAT layer 1 ----
    mfma_gemm<4><<<dim3(469, 2), 256, 0, stream>>>(
        (const ushort*)h0b, (const ushort*)W1t, bcat1, nullptr, xlrb, NN, 512, 128);
    edge_fused<<<4688, 256, 0, stream>>>(ea, (const ushort*)We1t, att1, ei,
                                         (const ushort*)xlrb, logit);
    aggregate_csr<<<(NN + 3) / 4, 256, 0, stream>>>(
        (const ushort*)xlrb, logit, ei, eidx, start, bias1, (ushort*)h1b);

    // ---- GAT layer 2 ----
    mfma_gemm<4><<<dim3(469, 2), 256, 0, stream>>>(
        (const ushort*)h1b, (const ushort*)W2t, bcat2, nullptr, xlrb, NN, 512, 256);
    edge_fused<<<4688, 256, 0, stream>>>(ea, (const ushort*)We2t, att2, ei,
                                         (const ushort*)xlrb, logit);
    aggregate_csr<<<(NN + 3) / 4, 256, 0, stream>>>(
        (const ushort*)xlrb, logit, ei, eidx, start, bias2, (ushort*)h2b);

    // ---- attention pooling ----
    mfma_gemm<4><<<dim3(469, 1), 256, 0, stream>>>(
        (const ushort*)h2b, (const ushort*)Wpt, bp, abuf, nullptr, NN, 256, 256);
    pool_fused<<<BB, 256, 0, stream>>>(abuf, h2b, batch, g);

    // ---- head MLP ----
    mlp_lin1<<<BB, HC, 0, stream>>>(g, Wo1, bo1, ybuf);
    bn_relu<<<1, HC, 0, stream>>>(ybuf, gamma, beta);
    mlp_lin2<<<dim3(8, BB), 256, 0, stream>>>(ybuf, Wo2, bo2, out);
}

// Round 5
// 720.368 us; speedup vs baseline: 2.6501x; 1.2194x over previous
//
#include <hip/hip_runtime.h>
#include <hip/hip_bf16.h>

#define NN 30000
#define EE 300000
#define BB 64
#define HH 4
#define CC 64
#define HC 256

typedef __attribute__((ext_vector_type(8))) short short8;
typedef __attribute__((ext_vector_type(4))) float floatx4;

__device__ __forceinline__ float b2f(short x) {
    return __uint_as_float(((unsigned)(unsigned short)x) << 16);
}
__device__ __forceinline__ unsigned short f2b(float f) {
    __hip_bfloat16 h = __float2bfloat16(f);
    return *(unsigned short*)&h;
}

#define GLD16(gp, lp) __builtin_amdgcn_global_load_lds( \
    (const __attribute__((address_space(1))) void*)(gp), \
    (__attribute__((address_space(3))) void*)(lp), 16, 0, 0)

// ===================== bf16 MFMA GEMM (dense transforms) =================
template<int CT>
__global__ __launch_bounds__(256) void mfma_gemm(
    const ushort* __restrict__ A, const ushort* __restrict__ Bt,
    const float* __restrict__ bias, float* __restrict__ outF,
    __hip_bfloat16* __restrict__ outB, int M, int Nc, int K) {
    __shared__ __align__(16) ushort lA[64 * 32];
    __shared__ __align__(16) ushort lB[CT * 64 * 32];
    const int tid = threadIdx.x, lane = tid & 63, wv = tid >> 6;
    const int row0 = blockIdx.x * 64, col0 = blockIdx.y * (CT * 64);

    floatx4 acc[4][CT];
#pragma unroll
    for (int r = 0; r < 4; r++)
#pragma unroll
        for (int c = 0; c < CT; c++) acc[r][c] = (floatx4){0.f, 0.f, 0.f, 0.f};

    const int arow = tid >> 2;
    const int sl   = (tid & 3) ^ ((tid >> 3) & 3);
    const ushort* ga = A + (size_t)(row0 + arow) * K + sl * 8;
    const int m16 = lane & 15, q = lane >> 4;

    for (int k0 = 0; k0 < K; k0 += 32) {
        __syncthreads();
        GLD16(ga + k0, &lA[tid * 8]);
#pragma unroll
        for (int j = 0; j < CT; j++) {
            const ushort* gb = Bt + (size_t)(col0 + j * 64 + arow) * K + k0 + sl * 8;
            GLD16(gb, &lB[j * 2048 + tid * 8]);
        }
        __syncthreads();
        short8 aF[4], bF[CT];
#pragma unroll
        for (int r = 0; r < 4; r++) {
            int rr = r * 16 + m16;
            aF[r] = *(const short8*)&lA[rr * 32 + ((q ^ ((rr >> 1) & 3)) << 3)];
        }
#pragma unroll
        for (int c = 0; c < CT; c++) {
            int nr = (wv * CT + c) * 16 + m16;
            bF[c] = *(const short8*)&lB[nr * 32 + ((q ^ ((nr >> 1) & 3)) << 3)];
        }
#pragma unroll
        for (int r = 0; r < 4; r++)
#pragma unroll
            for (int c = 0; c < CT; c++)
                acc[r][c] = __builtin_amdgcn_mfma_f32_16x16x32_bf16(aF[r], bF[c], acc[r][c], 0, 0, 0);
    }

#pragma unroll
    for (int c = 0; c < CT; c++) {
        int col = col0 + (wv * CT + c) * 16 + m16;
        float bv = bias ? bias[col] : 0.f;
#pragma unroll
        for (int r = 0; r < 4; r++)
#pragma unroll
            for (int j = 0; j < 4; j++) {
                int row = row0 + r * 16 + q * 4 + j;
                if (row < M) {
                    float v = acc[r][c][j] + bv;
                    if (outB) outB[(size_t)row * Nc + col] = __float2bfloat16(v);
                    else      outF[(size_t)row * Nc + col] = v;
                }
            }
    }
}

// ===================== fused ea@We GEMM + edge logit =====================
__global__ __launch_bounds__(256) void edge_fused(
    const float* __restrict__ ea, const ushort* __restrict__ Bt,
    const float* __restrict__ att, const int* __restrict__ ei,
    const ushort* __restrict__ xlr, float* __restrict__ logit) {
    __shared__ __align__(16) char smem[40960];
    ushort* lA  = (ushort*)smem;            // 64 x 64  (8 KB)
    ushort* lB  = (ushort*)(smem + 8192);   // 256 x 64 (32 KB)
    ushort* eeS = (ushort*)smem;            // 64 x 256 (32 KB) alias
    __shared__ float satt[256];
    const int tid = threadIdx.x, lane = tid & 63, wv = tid >> 6;
    const int e0 = blockIdx.x * 64;
    satt[tid] = att[tid];

    {
        const int row = tid >> 2, cg = tid & 3;
        const int e = e0 + row;
        float tmp[16];
#pragma unroll
        for (int m = 0; m < 16; m++) {
            int k = cg * 16 + m;
            tmp[m] = (e < EE && k < 51) ? ea[(size_t)e * 51 + k] : 0.f;
        }
#pragma unroll
        for (int cc = 0; cc < 2; cc++) {
            short8 v8;
#pragma unroll
            for (int j = 0; j < 8; j++) v8[j] = (short)f2b(tmp[cc * 8 + j]);
            int c = cg * 2 + cc;
            *(short8*)&lA[row * 64 + ((c ^ (row & 7)) << 3)] = v8;
        }
    }
    {
        const int n = tid;
#pragma unroll
        for (int c = 0; c < 8; c++) {
            short8 bv = *(const short8*)&Bt[(size_t)n * 64 + c * 8];
            *(short8*)&lB[n * 64 + ((c ^ (n & 7)) << 3)] = bv;
        }
    }
    __syncthreads();

    const int m16 = lane & 15, q = lane >> 4;
    floatx4 acc[4][4];
#pragma unroll
    for (int r = 0; r < 4; r++)
#pragma unroll
        for (int c = 0; c < 4; c++) acc[r][c] = (floatx4){0.f, 0.f, 0.f, 0.f};
#pragma unroll
    for (int k0 = 0; k0 < 2; k0++) {
        short8 aF[4], bF[4];
#pragma unroll
        for (int r = 0; r < 4; r++) {
            int rr = r * 16 + m16;
            aF[r] = *(const short8*)&lA[rr * 64 + (((k0 * 4 + q) ^ (rr & 7)) << 3)];
        }
#pragma unroll
        for (int c = 0; c < 4; c++) {
            int nr = (wv * 4 + c) * 16 + m16;
            bF[c] = *(const short8*)&lB[nr * 64 + (((k0 * 4 + q) ^ (nr & 7)) << 3)];
        }
#pragma unroll
        for (int r = 0; r < 4; r++)
#pragma unroll
            for (int c = 0; c < 4; c++)
                acc[r][c] = __builtin_amdgcn_mfma_f32_16x16x32_bf16(aF[r], bF[c], acc[r][c], 0, 0, 0);
    }
    __syncthreads();

#pragma unroll
    for (int r = 0; r < 4; r++)
#pragma unroll
        for (int cc = 0; cc < 4; cc++)
#pragma unroll
            for (int j = 0; j < 4; j++) {
                int row = r * 16 + q * 4 + j;
                int col = (wv * 4 + cc) * 16 + m16;
                eeS[row * 256 + (((col >> 3) ^ (row & 31)) << 3) + (col & 7)] =
                    f2b(acc[r][cc][j]);
            }
    __syncthreads();

    const int el = tid >> 2, h = tid & 3;
    const int e = e0 + el;
    if (e < EE) {
        int src = ei[e], dstn = ei[EE + e];
        const ushort* xlp = xlr + (size_t)src * 512 + h * 64;
        const ushort* xrp = xlr + (size_t)dstn * 512 + 256 + h * 64;
        float s = 0.f;
#pragma unroll
        for (int c = 0; c < 8; c++) {
            short8 xlv = *(const short8*)(xlp + c * 8);
            short8 xrv = *(const short8*)(xrp + c * 8);
            short8 eev = *(const short8*)&eeS[el * 256 + (((h * 8 + c) ^ (el & 31)) << 3)];
#pragma unroll
            for (int j = 0; j < 8; j++) {
                float v = b2f(xlv[j]) + b2f(xrv[j]) + b2f(eev[j]);
                v = v > 0.f ? v : 0.2f * v;
                s += v * satt[h * 64 + c * 8 + j];
            }
        }
        logit[(size_t)e * 4 + h] = s;
    }
}

// ===================== packing ===========================================
__global__ void pack_x(const float* __restrict__ x, __hip_bfloat16* __restrict__ d) {
    int i = blockIdx.x * 256 + threadIdx.x;
    if (i >= NN * 32) return;
    int n = i >> 5, k = i & 31;
    d[i] = __float2bfloat16(k < 13 ? x[n * 13 + k] : 0.f);
}
struct PackJob { const float* W; __hip_bfloat16* dst; int K, Nc, Kpad, rowoff; };
struct PackJobs { PackJob j[8]; };
__global__ void pack_all(PackJobs jobs) {
    PackJob jb = jobs.j[blockIdx.y];
    int tot = jb.Nc * jb.Kpad;
    for (int i = blockIdx.x * 256 + threadIdx.x; i < tot; i += gridDim.x * 256) {
        int n = i / jb.Kpad, k = i - n * jb.Kpad;
        float v = (k < jb.K) ? jb.W[k * jb.Nc + n] : 0.f;
        jb.dst[(size_t)(jb.rowoff + n) * jb.Kpad + k] = __float2bfloat16(v);
    }
}
__global__ void cat2(const float* __restrict__ a, const float* __restrict__ b,
                     float* __restrict__ o) {
    int i = blockIdx.x * 256 + threadIdx.x;
    if (i < 512) o[i] = i < 256 ? a[i] : b[i - 256];
}

// ===================== CSR build =========================================
__global__ void hist_deg(const int* __restrict__ ei, int* __restrict__ deg) {
    int e = blockIdx.x * 256 + threadIdx.x;
    if (e < EE) atomicAdd(&deg[ei[EE + e]], 1);
}
__global__ void scan1(const int* __restrict__ deg, int* __restrict__ partial,
                      int* __restrict__ bsum) {
    __shared__ int sh[256];
    int t = threadIdx.x, i = blockIdx.x * 256 + t;
    int v = (i < NN) ? deg[i] : 0;
    sh[t] = v; __syncthreads();
    for (int off = 1; off < 256; off <<= 1) {
        int x = (t >= off) ? sh[t - off] : 0;
        __syncthreads();
        sh[t] += x;
        __syncthreads();
    }
    if (i < NN) partial[i] = sh[t] - v;
    if (t == 255) bsum[blockIdx.x] = sh[255];
}
__global__ void scan2(int* __restrict__ bsum, int nb) {
    __shared__ int sh[256];
    int t = threadIdx.x;
    int v = (t < nb) ? bsum[t] : 0;
    sh[t] = v; __syncthreads();
    for (int off = 1; off < 256; off <<= 1) {
        int x = (t >= off) ? sh[t - off] : 0;
        __syncthreads();
        sh[t] += x;
        __syncthreads();
    }
    if (t < nb) bsum[t] = sh[t] - v;
}
__global__ void scan3(const int* __restrict__ partial, const int* __restrict__ bsum,
                      int* __restrict__ start) {
    int i = blockIdx.x * 256 + threadIdx.x;
    if (i < NN) start[i] = partial[i] + bsum[i >> 8];
    else if (i == NN) start[NN] = EE;
}
__global__ void scatter_e(const int* __restrict__ ei, int* __restrict__ cursor,
                          const int* __restrict__ start, int* __restrict__ eidx) {
    int e = blockIdx.x * 256 + threadIdx.x;
    if (e >= EE) return;
    int d = ei[EE + e];
    int p = atomicAdd(&cursor[d], 1);
    eidx[start[d] + p] = e;
}

// ===================== fused segment softmax + aggregate =================
__global__ __launch_bounds__(256) void aggregate_csr(
    const ushort* __restrict__ xlr, const float* __restrict__ logit,
    const int* __restrict__ ei, const int* __restrict__ eidx,
    const int* __restrict__ start, const float* __restrict__ bias,
    ushort* __restrict__ outb) {
    const int lane = threadIdx.x & 63, wv = threadIdx.x >> 6;
    const int dst = blockIdx.x * 4 + wv;
    if (dst >= NN) return;
    const int s0 = start[dst];
    const int deg = start[dst + 1] - s0;
    const int h = lane >> 4;

    float m[4] = {-3.4e38f, -3.4e38f, -3.4e38f, -3.4e38f};
    float lg[4] = {0.f, 0.f, 0.f, 0.f};
    int mysrc = 0;
    if (lane < deg) {
        int e = eidx[s0 + lane];
        mysrc = ei[e];
        float4 l4 = ((const float4*)logit)[e];
        lg[0] = l4.x; lg[1] = l4.y; lg[2] = l4.z; lg[3] = l4.w;
        m[0] = l4.x; m[1] = l4.y; m[2] = l4.z; m[3] = l4.w;
    }
    for (int i = 64 + lane; i < deg; i += 64) {
        int e = eidx[s0 + i];
        float4 l4 = ((const float4*)logit)[e];
        m[0] = fmaxf(m[0], l4.x); m[1] = fmaxf(m[1], l4.y);
        m[2] = fmaxf(m[2], l4.z); m[3] = fmaxf(m[3], l4.w);
    }
#pragma unroll
    for (int off = 32; off; off >>= 1)
#pragma unroll
        for (int k = 0; k < 4; k++) m[k] = fmaxf(m[k], __shfl_xor(m[k], off));

    float w[4], d[4];
#pragma unroll
    for (int k = 0; k < 4; k++) {
        w[k] = (lane < deg) ? __expf(lg[k] - m[k]) : 0.f;
        d[k] = w[k];
    }
    for (int i = 64 + lane; i < deg; i += 64) {
        int e = eidx[s0 + i];
        float4 l4 = ((const float4*)logit)[e];
        d[0] += __expf(l4.x - m[0]); d[1] += __expf(l4.y - m[1]);
        d[2] += __expf(l4.z - m[2]); d[3] += __expf(l4.w - m[3]);
    }
#pragma unroll
    for (int off = 32; off; off >>= 1)
#pragma unroll
        for (int k = 0; k < 4; k++) d[k] += __shfl_xor(d[k], off);
    const float dh = 1.f / (((h == 0) ? d[0] : (h == 1) ? d[1] : (h == 2) ? d[2] : d[3]) + 1e-16f);
    const float mh = (h == 0) ? m[0] : (h == 1) ? m[1] : (h == 2) ? m[2] : m[3];

    float4 b4 = ((const float4*)bias)[lane];
    float a0 = b4.x, a1 = b4.y, a2 = b4.z, a3 = b4.w;

    const int dcap = deg < 64 ? deg : 64;
    for (int i = 0; i < dcap; i++) {
        int srcv = __shfl(mysrc, i);
        float s0v = __shfl(w[0], i), s1v = __shfl(w[1], i);
        float s2v = __shfl(w[2], i), s3v = __shfl(w[3], i);
        float aw = ((h == 0) ? s0v : (h == 1) ? s1v : (h == 2) ? s2v : s3v) * dh;
        ushort4 xv = *(const ushort4*)(xlr + (size_t)srcv * 512 + lane * 4);
        a0 += b2f(xv.x) * aw; a1 += b2f(xv.y) * aw;
        a2 += b2f(xv.z) * aw; a3 += b2f(xv.w) * aw;
    }
    for (int i = 64; i < deg; i++) {
        int e = eidx[s0 + i];
        int srcv = ei[e];
        float4 l4 = ((const float4*)logit)[e];
        float lh = (h == 0) ? l4.x : (h == 1) ? l4.y : (h == 2) ? l4.z : l4.w;
        float aw = __expf(lh - mh) * dh;
        ushort4 xv = *(const ushort4*)(xlr + (size_t)srcv * 512 + lane * 4);
        a0 += b2f(xv.x) * aw; a1 += b2f(xv.y) * aw;
        a2 += b2f(xv.z) * aw; a3 += b2f(xv.w) * aw;
    }
    ushort4 ov;
    ov.x = f2b(a0); ov.y = f2b(a1); ov.z = f2b(a2); ov.w = f2b(a3);
    *(ushort4*)(outb + (size_t)dst * 256 + lane * 4) = ov;
}

// ===================== pooling: chunk-parallel, 3 kernels ================
__device__ __forceinline__ unsigned fmap(float f) {
    unsigned u = __float_as_uint(f);
    return (u & 0x80000000u) ? ~u : (u | 0x80000000u);
}
__device__ __forceinline__ float funmap(unsigned u) {
    return (u & 0x80000000u) ? __uint_as_float(u & 0x7FFFFFFFu)
                             : __uint_as_float(~u);
}

// pass 1: per-graph channel max via run-length + atomicMax (am zero-init ok:
// 0 < fmap(any finite float))
__global__ void pool_max(const float* __restrict__ a, const int* __restrict__ batch,
                         unsigned* __restrict__ am) {
    const int c = threadIdx.x;
    const int n0 = blockIdx.x * 64;
    int curb = batch[n0];
    float m = -3.4e38f;
    const int nend = min(n0 + 64, NN);
    for (int n = n0; n < nend; n++) {
        int b = batch[n];
        float v = a[(size_t)n * HC + c];
        if (b != curb) { atomicMax(&am[curb * HC + c], fmap(m)); curb = b; m = v; }
        else           { m = fmaxf(m, v); }
    }
    atomicMax(&am[curb * HC + c], fmap(m));
}
// pass 2: den & num accumulated together; no aw writeback
__global__ void pool_sums(const float* __restrict__ a, const __hip_bfloat16* __restrict__ h2,
                          const int* __restrict__ batch, const unsigned* __restrict__ am,
                          float* __restrict__ den, float* __restrict__ num) {
    const int c = threadIdx.x;
    const int n0 = blockIdx.x * 64;
    int curb = batch[n0];
    float sd = 0.f, sn = 0.f;
    float mcur = funmap(am[curb * HC + c]);
    const int nend = min(n0 + 64, NN);
    for (int n = n0; n < nend; n++) {
        int b = batch[n];
        if (b != curb) {
            atomicAdd(&den[curb * HC + c], sd);
            atomicAdd(&num[curb * HC + c], sn);
            curb = b; sd = 0.f; sn = 0.f; mcur = funmap(am[b * HC + c]);
        }
        float w = __expf(a[(size_t)n * HC + c] - mcur);
        sd += w;
        sn += __bfloat162float(h2[(size_t)n * HC + c]) * w;
    }
    atomicAdd(&den[curb * HC + c], sd);
    atomicAdd(&num[curb * HC + c], sn);
}
__global__ void pool_div(const float* __restrict__ num, const float* __restrict__ den,
                         float* __restrict__ g) {
    int i = blockIdx.x * 256 + threadIdx.x;
    g[i] = num[i] / (den[i] + 1e-16f);
}

// ===================== head MLP ==========================================
__global__ void mlp_lin1(const float* __restrict__ g, const float* __restrict__ Wo1,
                         const float* __restrict__ bo1, float* __restrict__ y) {
    const int c = threadIdx.x;
    const int r = blockIdx.x;
    float acc = bo1[c];
#pragma unroll 4
    for (int k = 0; k < HC; k++) acc = fmaf(g[r * HC + k], Wo1[k * HC + c], acc);
    y[r * HC + c] = acc;
}
__global__ void bn_relu(float* __restrict__ y, const float* __restrict__ gamma,
                        const float* __restrict__ beta) {
    const int c = threadIdx.x;
    float s = 0.f, sq = 0.f;
    for (int r = 0; r < BB; r++) { float v = y[r * HC + c]; s += v; sq += v * v; }
    float mu  = s * (1.f / BB);
    float var = sq * (1.f / BB) - mu * mu;
    float inv = rsqrtf(var + 1e-5f) * gamma[c];
    float bt  = beta[c];
    for (int r = 0; r < BB; r++) {
        float v = (y[r * HC + c] - mu) * inv + bt;
        y[r * HC + c] = v > 0.f ? v : 0.f;
    }
}
__global__ void mlp_lin2(const float* __restrict__ y, const float* __restrict__ Wo2,
                         const float* __restrict__ bo2, float* __restrict__ out) {
    const int j = blockIdx.x * 256 + threadIdx.x;
    const int r = blockIdx.y;
    if (j >= 2001) return;
    float acc = bo2[j];
#pragma unroll 4
    for (int k = 0; k < HC; k++) acc = fmaf(y[r * HC + k], Wo2[k * 2001 + j], acc);
    out[r * 2001 + j] = acc > 0.f ? acc : 0.01f * acc;
}

// ===================== launcher ==========================================
extern "C" void kernel_launch(void* const* d_in, const int* in_sizes, int n_in,
                              void* d_out, int out_size, void* d_ws, size_t ws_size,
                              hipStream_t stream) {
    const float* x     = (const float*)d_in[0];
    const int*   ei    = (const int*)d_in[1];
    const float* ea    = (const float*)d_in[2];
    const int*   batch = (const int*)d_in[3];
    const float* W0 = (const float*)d_in[4];  const float* b0 = (const float*)d_in[5];
    const float* Wl1 = (const float*)d_in[6]; const float* bl1 = (const float*)d_in[7];
    const float* Wr1 = (const float*)d_in[8]; const float* br1 = (const float*)d_in[9];
    const float* We1 = (const float*)d_in[10]; const float* att1 = (const float*)d_in[11];
    const float* bias1 = (const float*)d_in[12];
    const float* Wl2 = (const float*)d_in[13]; const float* bl2 = (const float*)d_in[14];
    const float* Wr2 = (const float*)d_in[15]; const float* br2 = (const float*)d_in[16];
    const float* We2 = (const float*)d_in[17]; const float* att2 = (const float*)d_in[18];
    const float* bias2 = (const float*)d_in[19];
    const float* Wp = (const float*)d_in[20]; const float* bp = (const float*)d_in[21];
    const float* Wo1 = (const float*)d_in[22]; const float* bo1 = (const float*)d_in[23];
    const float* gamma = (const float*)d_in[24]; const float* beta = (const float*)d_in[25];
    const float* Wo2 = (const float*)d_in[26]; const float* bo2 = (const float*)d_in[27];
    float* out = (float*)d_out;

    // ---- workspace carve-up (256B aligned), ~110 MB ----
    char* p = (char*)d_ws;
    auto alloc = [&](size_t bytes) { char* r = p; p += (bytes + 255) & ~(size_t)255; return r; };
    const int MP = 30016;
    __hip_bfloat16* xpad  = (__hip_bfloat16*)alloc((size_t)MP * 32 * 2);
    __hip_bfloat16* W0t   = (__hip_bfloat16*)alloc(128 * 32 * 2);
    __hip_bfloat16* W1t   = (__hip_bfloat16*)alloc(512 * 128 * 2);
    __hip_bfloat16* We1t  = (__hip_bfloat16*)alloc(256 * 64 * 2);
    __hip_bfloat16* W2t   = (__hip_bfloat16*)alloc(512 * 256 * 2);
    __hip_bfloat16* We2t  = (__hip_bfloat16*)alloc(256 * 64 * 2);
    __hip_bfloat16* Wpt   = (__hip_bfloat16*)alloc(256 * 256 * 2);
    float* bcat1 = (float*)alloc(512 * 4);
    float* bcat2 = (float*)alloc(512 * 4);
    __hip_bfloat16* h0b  = (__hip_bfloat16*)alloc((size_t)MP * 128 * 2);
    __hip_bfloat16* xlrb = (__hip_bfloat16*)alloc((size_t)MP * 512 * 2);
    __hip_bfloat16* h1b  = (__hip_bfloat16*)alloc((size_t)MP * 256 * 2);
    __hip_bfloat16* h2b  = (__hip_bfloat16*)alloc((size_t)MP * 256 * 2);
    float* abuf = (float*)alloc((size_t)MP * 256 * 4);
    float* logit = (float*)alloc((size_t)EE * 4 * 4);
    int* deg    = (int*)alloc(NN * 4);
    int* cursor = (int*)alloc(NN * 4);
    int* partial= (int*)alloc(NN * 4);
    int* bsum   = (int*)alloc(256 * 4);
    int* start  = (int*)alloc((NN + 4) * 4);
    int* eidx   = (int*)alloc((size_t)EE * 4);
    unsigned* am = (unsigned*)alloc(BB * HC * 4);
    float* den  = (float*)alloc(BB * HC * 4);
    float* num  = (float*)alloc(BB * HC * 4);
    float* g    = (float*)alloc(BB * HC * 4);
    float* ybuf = (float*)alloc(BB * HC * 4);

    const int NB = (NN + 255) / 256;

    // ---- input / weight packing ----
    pack_x<<<(NN * 32 + 255) / 256, 256, 0, stream>>>(x, xpad);
    PackJobs pj;
    pj.j[0] = {W0,  W0t, 13, 128, 32, 0};
    pj.j[1] = {Wl1, W1t, 128, 256, 128, 0};
    pj.j[2] = {Wr1, W1t, 128, 256, 128, 256};
    pj.j[3] = {We1, We1t, 51, 256, 64, 0};
    pj.j[4] = {Wl2, W2t, 256, 256, 256, 0};
    pj.j[5] = {Wr2, W2t, 256, 256, 256, 256};
    pj.j[6] = {We2, We2t, 51, 256, 64, 0};
    pj.j[7] = {Wp,  Wpt, 256, 256, 256, 0};
    pack_all<<<dim3(64, 8), 256, 0, stream>>>(pj);
    cat2<<<2, 256, 0, stream>>>(bl1, br1, bcat1);
    cat2<<<2, 256, 0, stream>>>(bl2, br2, bcat2);

    // ---- CSR build ----
    hipMemsetAsync(deg, 0, NN * 4, stream);
    hipMemsetAsync(cursor, 0, NN * 4, stream);
    hist_deg<<<(EE + 255) / 256, 256, 0, stream>>>(ei, deg);
    scan1<<<NB, 256, 0, stream>>>(deg, partial, bsum);
    scan2<<<1, 256, 0, stream>>>(bsum, NB);
    scan3<<<NB + 1, 256, 0, stream>>>(partial, bsum, start);
    scatter_e<<<(EE + 255) / 256, 256, 0, stream>>>(ei, cursor, start, eidx);

    // ---- init transform ----
    mfma_gemm<2><<<dim3(469, 1), 256, 0, stream>>>(
        (const ushort*)xpad, (const ushort*)W0t, b0, nullptr, h0b, NN, 128, 32);

    // ---- GAT layer 1 ----
    mfma_gemm<4><<<dim3(469, 2), 256, 0, stream>>>(
        (const ushort*)h0b, (const ushort*)W1t, bcat1, nullptr, xlrb, NN, 512, 128);
    edge_fused<<<4688, 256, 0, stream>>>(ea, (const ushort*)We1t, att1, ei,
                                         (const ushort*)xlrb, logit);
    aggregate_csr<<<(NN + 3) / 4, 256, 0, stream>>>(
        (const ushort*)xlrb, logit, ei, eidx, start, bias1, (ushort*)h1b);

    // ---- GAT layer 2 ----
    mfma_gemm<4><<<dim3(469, 2), 256, 0, stream>>>(
        (const ushort*)h1b, (const ushort*)W2t, bcat2, nullptr, xlrb, NN, 512, 256);
    edge_fused<<<4688, 256, 0, stream>>>(ea, (const ushort*)We2t, att2, ei,
                                         (const ushort*)xlrb, logit);
    aggregate_csr<<<(NN + 3) / 4, 256, 0, stream>>>(
        (const ushort*)xlrb, logit, ei, eidx, start, bias2, (ushort*)h2b);

    // ---- attention pooling (chunk-parallel) ----
    mfma_gemm<4><<<dim3(469, 1), 256, 0, stream>>>(
        (const ushort*)h2b, (const ushort*)Wpt, bp, abuf, nullptr, NN, 256, 256);
    hipMemsetAsync(am, 0, BB * HC * 4, stream);
    hipMemsetAsync(den, 0, BB * HC * 4, stream);
    hipMemsetAsync(num, 0, BB * HC * 4, stream);
    const int poolGrid = (NN + 63) / 64;
    pool_max<<<poolGrid, HC, 0, stream>>>(abuf, batch, am);
    pool_sums<<<poolGrid, HC, 0, stream>>>(abuf, h2b, batch, am, den, num);
    pool_div<<<BB, HC, 0, stream>>>(num, den, g);

    // ---- head MLP ----
    mlp_lin1<<<BB, HC, 0, stream>>>(g, Wo1, bo1, ybuf);
    bn_relu<<<1, HC, 0, stream>>>(ybuf, gamma, beta);
    mlp_lin2<<<dim3(8, BB), 256, 0, stream>>>(ybuf, Wo2, bo2, out);
}

// Round 6
// 691.840 us; speedup vs baseline: 2.7593x; 1.0412x over previous
//
#include <hip/hip_runtime.h>
#include <hip/hip_bf16.h>

#define NN 30000
#define EE 300000
#define BB 64
#define HH 4
#define CC 64
#define HC 256

typedef __attribute__((ext_vector_type(8))) short short8;
typedef __attribute__((ext_vector_type(4))) float floatx4;

__device__ __forceinline__ float b2f(short x) {
    return __uint_as_float(((unsigned)(unsigned short)x) << 16);
}
__device__ __forceinline__ unsigned short f2b(float f) {
    __hip_bfloat16 h = __float2bfloat16(f);
    return *(unsigned short*)&h;
}

#define GLD16(gp, lp) __builtin_amdgcn_global_load_lds( \
    (const __attribute__((address_space(1))) void*)(gp), \
    (__attribute__((address_space(3))) void*)(lp), 16, 0, 0)

// 5-bit rotate-left-by-2: puts head bits of chunk index into low bank bits
#define ROT2(x) ((((x) << 2) | ((x) >> 3)) & 31)

// ===================== bf16 MFMA GEMM (dense transforms) =================
template<int CT>
__global__ __launch_bounds__(256) void mfma_gemm(
    const ushort* __restrict__ A, const ushort* __restrict__ Bt,
    const float* __restrict__ bias, float* __restrict__ outF,
    __hip_bfloat16* __restrict__ outB, int M, int Nc, int K) {
    __shared__ __align__(16) ushort lA[64 * 32];
    __shared__ __align__(16) ushort lB[CT * 64 * 32];
    const int tid = threadIdx.x, lane = tid & 63, wv = tid >> 6;
    const int row0 = blockIdx.x * 64, col0 = blockIdx.y * (CT * 64);

    floatx4 acc[4][CT];
#pragma unroll
    for (int r = 0; r < 4; r++)
#pragma unroll
        for (int c = 0; c < CT; c++) acc[r][c] = (floatx4){0.f, 0.f, 0.f, 0.f};

    const int arow = tid >> 2;
    const int sl   = (tid & 3) ^ ((tid >> 3) & 3);
    const ushort* ga = A + (size_t)(row0 + arow) * K + sl * 8;
    const int m16 = lane & 15, q = lane >> 4;

    for (int k0 = 0; k0 < K; k0 += 32) {
        __syncthreads();
        GLD16(ga + k0, &lA[tid * 8]);
#pragma unroll
        for (int j = 0; j < CT; j++) {
            const ushort* gb = Bt + (size_t)(col0 + j * 64 + arow) * K + k0 + sl * 8;
            GLD16(gb, &lB[j * 2048 + tid * 8]);
        }
        __syncthreads();
        short8 aF[4], bF[CT];
#pragma unroll
        for (int r = 0; r < 4; r++) {
            int rr = r * 16 + m16;
            aF[r] = *(const short8*)&lA[rr * 32 + ((q ^ ((rr >> 1) & 3)) << 3)];
        }
#pragma unroll
        for (int c = 0; c < CT; c++) {
            int nr = (wv * CT + c) * 16 + m16;
            bF[c] = *(const short8*)&lB[nr * 32 + ((q ^ ((nr >> 1) & 3)) << 3)];
        }
#pragma unroll
        for (int r = 0; r < 4; r++)
#pragma unroll
            for (int c = 0; c < CT; c++)
                acc[r][c] = __builtin_amdgcn_mfma_f32_16x16x32_bf16(aF[r], bF[c], acc[r][c], 0, 0, 0);
    }

#pragma unroll
    for (int c = 0; c < CT; c++) {
        int col = col0 + (wv * CT + c) * 16 + m16;
        float bv = bias ? bias[col] : 0.f;
#pragma unroll
        for (int r = 0; r < 4; r++)
#pragma unroll
            for (int j = 0; j < 4; j++) {
                int row = row0 + r * 16 + q * 4 + j;
                if (row < M) {
                    float v = acc[r][c][j] + bv;
                    if (outB) outB[(size_t)row * Nc + col] = __float2bfloat16(v);
                    else      outF[(size_t)row * Nc + col] = v;
                }
            }
    }
}

// ===================== fused ea@We GEMM + edge logit (CSR order) =========
// Block = 64 CSR positions i0..i0+63 (dst-sorted). ea rows gathered via
// eidx; xr[dst] clustered (L1-hot); logits written sequentially at CSR pos.
__global__ __launch_bounds__(256) void edge_fused(
    const float* __restrict__ ea, const ushort* __restrict__ Bt,
    const float* __restrict__ att, const int* __restrict__ eidx,
    const int* __restrict__ src_csr, const int* __restrict__ dst_csr,
    const ushort* __restrict__ xlr, float* __restrict__ logitp) {
    __shared__ __align__(16) char smem[40960];
    ushort* lA  = (ushort*)smem;            // 64 x 64  (8 KB)
    ushort* lB  = (ushort*)(smem + 8192);   // 256 x 64 (32 KB)
    ushort* eeS = (ushort*)smem;            // 64 x 256 (32 KB) alias
    __shared__ float satt[256];
    const int tid = threadIdx.x, lane = tid & 63, wv = tid >> 6;
    const int i0 = blockIdx.x * 64;
    satt[tid] = att[tid];

    // ---- stage A: gathered ea rows -> bf16, XOR-swizzled [row][64] ----
    {
        const int row = tid >> 2, cg = tid & 3;
        const int i = i0 + row;
        const int e = (i < EE) ? eidx[i] : -1;
        float tmp[16];
#pragma unroll
        for (int m = 0; m < 16; m++) {
            int k = cg * 16 + m;
            tmp[m] = (e >= 0 && k < 51) ? ea[(size_t)e * 51 + k] : 0.f;
        }
#pragma unroll
        for (int cc = 0; cc < 2; cc++) {
            short8 v8;
#pragma unroll
            for (int j = 0; j < 8; j++) v8[j] = (short)f2b(tmp[cc * 8 + j]);
            int c = cg * 2 + cc;
            *(short8*)&lA[row * 64 + ((c ^ (row & 7)) << 3)] = v8;
        }
    }
    // ---- stage B: Bt [256][64] bf16 ----
    {
        const int n = tid;
#pragma unroll
        for (int c = 0; c < 8; c++) {
            short8 bv = *(const short8*)&Bt[(size_t)n * 64 + c * 8];
            *(short8*)&lB[n * 64 + ((c ^ (n & 7)) << 3)] = bv;
        }
    }
    __syncthreads();

    // ---- MFMA: [64,64] x [64,256] ----
    const int m16 = lane & 15, q = lane >> 4;
    floatx4 acc[4][4];
#pragma unroll
    for (int r = 0; r < 4; r++)
#pragma unroll
        for (int c = 0; c < 4; c++) acc[r][c] = (floatx4){0.f, 0.f, 0.f, 0.f};
#pragma unroll
    for (int k0 = 0; k0 < 2; k0++) {
        short8 aF[4], bF[4];
#pragma unroll
        for (int r = 0; r < 4; r++) {
            int rr = r * 16 + m16;
            aF[r] = *(const short8*)&lA[rr * 64 + (((k0 * 4 + q) ^ (rr & 7)) << 3)];
        }
#pragma unroll
        for (int c = 0; c < 4; c++) {
            int nr = (wv * 4 + c) * 16 + m16;
            bF[c] = *(const short8*)&lB[nr * 64 + (((k0 * 4 + q) ^ (nr & 7)) << 3)];
        }
#pragma unroll
        for (int r = 0; r < 4; r++)
#pragma unroll
            for (int c = 0; c < 4; c++)
                acc[r][c] = __builtin_amdgcn_mfma_f32_16x16x32_bf16(aF[r], bF[c], acc[r][c], 0, 0, 0);
    }
    __syncthreads();

    // ---- park ee tile in LDS (ROT2-swizzled chunks) ----
#pragma unroll
    for (int r = 0; r < 4; r++)
#pragma unroll
        for (int cc = 0; cc < 4; cc++)
#pragma unroll
            for (int j = 0; j < 4; j++) {
                int row = r * 16 + q * 4 + j;
                int col = (wv * 4 + cc) * 16 + m16;
                int chunk = col >> 3;
                eeS[row * 256 + ((ROT2(chunk) ^ (row & 31)) << 3) + (col & 7)] =
                    f2b(acc[r][cc][j]);
            }
    __syncthreads();

    // ---- logit: thread = (CSR position el, head h) ----
    const int el = tid >> 2, h = tid & 3;
    const int i = i0 + el;
    if (i < EE) {
        int src = src_csr[i], dstn = dst_csr[i];
        const ushort* xlp = xlr + (size_t)src * 512 + h * 64;
        const ushort* xrp = xlr + (size_t)dstn * 512 + 256 + h * 64;
        float s = 0.f;
#pragma unroll
        for (int c = 0; c < 8; c++) {
            short8 xlv = *(const short8*)(xlp + c * 8);
            short8 xrv = *(const short8*)(xrp + c * 8);
            int chunk = h * 8 + c;
            short8 eev = *(const short8*)&eeS[el * 256 + ((ROT2(chunk) ^ (el & 31)) << 3)];
#pragma unroll
            for (int j = 0; j < 8; j++) {
                float v = b2f(xlv[j]) + b2f(xrv[j]) + b2f(eev[j]);
                v = v > 0.f ? v : 0.2f * v;
                s += v * satt[h * 64 + c * 8 + j];
            }
        }
        logitp[(size_t)i * 4 + h] = s;   // sequential (CSR order)
    }
}

// ===================== packing ===========================================
__global__ void pack_x(const float* __restrict__ x, __hip_bfloat16* __restrict__ d) {
    int i = blockIdx.x * 256 + threadIdx.x;
    if (i >= NN * 32) return;
    int n = i >> 5, k = i & 31;
    d[i] = __float2bfloat16(k < 13 ? x[n * 13 + k] : 0.f);
}
struct PackJob { const float* W; __hip_bfloat16* dst; int K, Nc, Kpad, rowoff; };
struct PackJobs { PackJob j[8]; };
__global__ void pack_all(PackJobs jobs) {
    PackJob jb = jobs.j[blockIdx.y];
    int tot = jb.Nc * jb.Kpad;
    for (int i = blockIdx.x * 256 + threadIdx.x; i < tot; i += gridDim.x * 256) {
        int n = i / jb.Kpad, k = i - n * jb.Kpad;
        float v = (k < jb.K) ? jb.W[k * jb.Nc + n] : 0.f;
        jb.dst[(size_t)(jb.rowoff + n) * jb.Kpad + k] = __float2bfloat16(v);
    }
}
__global__ void cat2(const float* __restrict__ a, const float* __restrict__ b,
                     float* __restrict__ o) {
    int i = blockIdx.x * 256 + threadIdx.x;
    if (i < 512) o[i] = i < 256 ? a[i] : b[i - 256];
}

// ===================== CSR build =========================================
__global__ void hist_deg(const int* __restrict__ ei, int* __restrict__ deg) {
    int e = blockIdx.x * 256 + threadIdx.x;
    if (e < EE) atomicAdd(&deg[ei[EE + e]], 1);
}
__global__ void scan1(const int* __restrict__ deg, int* __restrict__ partial,
                      int* __restrict__ bsum) {
    __shared__ int sh[256];
    int t = threadIdx.x, i = blockIdx.x * 256 + t;
    int v = (i < NN) ? deg[i] : 0;
    sh[t] = v; __syncthreads();
    for (int off = 1; off < 256; off <<= 1) {
        int x = (t >= off) ? sh[t - off] : 0;
        __syncthreads();
        sh[t] += x;
        __syncthreads();
    }
    if (i < NN) partial[i] = sh[t] - v;
    if (t == 255) bsum[blockIdx.x] = sh[255];
}
__global__ void scan2(int* __restrict__ bsum, int nb) {
    __shared__ int sh[256];
    int t = threadIdx.x;
    int v = (t < nb) ? bsum[t] : 0;
    sh[t] = v; __syncthreads();
    for (int off = 1; off < 256; off <<= 1) {
        int x = (t >= off) ? sh[t - off] : 0;
        __syncthreads();
        sh[t] += x;
        __syncthreads();
    }
    if (t < nb) bsum[t] = sh[t] - v;
}
__global__ void scan3(const int* __restrict__ partial, const int* __restrict__ bsum,
                      int* __restrict__ start) {
    int i = blockIdx.x * 256 + threadIdx.x;
    if (i < NN) start[i] = partial[i] + bsum[i >> 8];
    else if (i == NN) start[NN] = EE;
}
__global__ void scatter_e(const int* __restrict__ ei, int* __restrict__ cursor,
                          const int* __restrict__ start, int* __restrict__ eidx,
                          int* __restrict__ src_csr, int* __restrict__ dst_csr) {
    int e = blockIdx.x * 256 + threadIdx.x;
    if (e >= EE) return;
    int s = ei[e];
    int d = ei[EE + e];
    int p = atomicAdd(&cursor[d], 1);
    int pos = start[d] + p;
    eidx[pos] = e;
    src_csr[pos] = s;
    dst_csr[pos] = d;
}

// ===================== fused segment softmax + aggregate =================
// wave = one dst node; logit & src reads now coalesced (CSR-ordered).
__global__ __launch_bounds__(256) void aggregate_csr(
    const ushort* __restrict__ xlr, const float* __restrict__ logitp,
    const int* __restrict__ src_csr, const int* __restrict__ start,
    const float* __restrict__ bias, ushort* __restrict__ outb) {
    const int lane = threadIdx.x & 63, wv = threadIdx.x >> 6;
    const int dst = blockIdx.x * 4 + wv;
    if (dst >= NN) return;
    const int s0 = start[dst];
    const int deg = start[dst + 1] - s0;
    const int h = lane >> 4;

    float m[4] = {-3.4e38f, -3.4e38f, -3.4e38f, -3.4e38f};
    float lg[4] = {0.f, 0.f, 0.f, 0.f};
    int mysrc = 0;
    if (lane < deg) {
        mysrc = src_csr[s0 + lane];
        float4 l4 = ((const float4*)logitp)[s0 + lane];
        lg[0] = l4.x; lg[1] = l4.y; lg[2] = l4.z; lg[3] = l4.w;
        m[0] = l4.x; m[1] = l4.y; m[2] = l4.z; m[3] = l4.w;
    }
    for (int i = 64 + lane; i < deg; i += 64) {
        float4 l4 = ((const float4*)logitp)[s0 + i];
        m[0] = fmaxf(m[0], l4.x); m[1] = fmaxf(m[1], l4.y);
        m[2] = fmaxf(m[2], l4.z); m[3] = fmaxf(m[3], l4.w);
    }
#pragma unroll
    for (int off = 32; off; off >>= 1)
#pragma unroll
        for (int k = 0; k < 4; k++) m[k] = fmaxf(m[k], __shfl_xor(m[k], off));

    float w[4], d[4];
#pragma unroll
    for (int k = 0; k < 4; k++) {
        w[k] = (lane < deg) ? __expf(lg[k] - m[k]) : 0.f;
        d[k] = w[k];
    }
    for (int i = 64 + lane; i < deg; i += 64) {
        float4 l4 = ((const float4*)logitp)[s0 + i];
        d[0] += __expf(l4.x - m[0]); d[1] += __expf(l4.y - m[1]);
        d[2] += __expf(l4.z - m[2]); d[3] += __expf(l4.w - m[3]);
    }
#pragma unroll
    for (int off = 32; off; off >>= 1)
#pragma unroll
        for (int k = 0; k < 4; k++) d[k] += __shfl_xor(d[k], off);
    const float dh = 1.f / (((h == 0) ? d[0] : (h == 1) ? d[1] : (h == 2) ? d[2] : d[3]) + 1e-16f);
    const float mh = (h == 0) ? m[0] : (h == 1) ? m[1] : (h == 2) ? m[2] : m[3];

    float4 b4 = ((const float4*)bias)[lane];
    float a0 = b4.x, a1 = b4.y, a2 = b4.z, a3 = b4.w;

    const int dcap = deg < 64 ? deg : 64;
    for (int i = 0; i < dcap; i++) {
        int srcv = __shfl(mysrc, i);
        float s0v = __shfl(w[0], i), s1v = __shfl(w[1], i);
        float s2v = __shfl(w[2], i), s3v = __shfl(w[3], i);
        float aw = ((h == 0) ? s0v : (h == 1) ? s1v : (h == 2) ? s2v : s3v) * dh;
        ushort4 xv = *(const ushort4*)(xlr + (size_t)srcv * 512 + lane * 4);
        a0 += b2f(xv.x) * aw; a1 += b2f(xv.y) * aw;
        a2 += b2f(xv.z) * aw; a3 += b2f(xv.w) * aw;
    }
    for (int i = 64; i < deg; i++) {
        int srcv = src_csr[s0 + i];
        float4 l4 = ((const float4*)logitp)[s0 + i];
        float lh = (h == 0) ? l4.x : (h == 1) ? l4.y : (h == 2) ? l4.z : l4.w;
        float aw = __expf(lh - mh) * dh;
        ushort4 xv = *(const ushort4*)(xlr + (size_t)srcv * 512 + lane * 4);
        a0 += b2f(xv.x) * aw; a1 += b2f(xv.y) * aw;
        a2 += b2f(xv.z) * aw; a3 += b2f(xv.w) * aw;
    }
    ushort4 ov;
    ov.x = f2b(a0); ov.y = f2b(a1); ov.z = f2b(a2); ov.w = f2b(a3);
    *(ushort4*)(outb + (size_t)dst * 256 + lane * 4) = ov;
}

// ===================== pooling: chunk-parallel ===========================
__device__ __forceinline__ unsigned fmap(float f) {
    unsigned u = __float_as_uint(f);
    return (u & 0x80000000u) ? ~u : (u | 0x80000000u);
}
__device__ __forceinline__ float funmap(unsigned u) {
    return (u & 0x80000000u) ? __uint_as_float(u & 0x7FFFFFFFu)
                             : __uint_as_float(~u);
}

__global__ void pool_max(const float* __restrict__ a, const int* __restrict__ batch,
                         unsigned* __restrict__ am) {
    const int c = threadIdx.x;
    const int n0 = blockIdx.x * 64;
    int curb = batch[n0];
    float m = -3.4e38f;
    const int nend = min(n0 + 64, NN);
    for (int n = n0; n < nend; n++) {
        int b = batch[n];
        float v = a[(size_t)n * HC + c];
        if (b != curb) { atomicMax(&am[curb * HC + c], fmap(m)); curb = b; m = v; }
        else           { m = fmaxf(m, v); }
    }
    atomicMax(&am[curb * HC + c], fmap(m));
}
__global__ void pool_sums(const float* __restrict__ a, const __hip_bfloat16* __restrict__ h2,
                          const int* __restrict__ batch, const unsigned* __restrict__ am,
                          float* __restrict__ den, float* __restrict__ num) {
    const int c = threadIdx.x;
    const int n0 = blockIdx.x * 64;
    int curb = batch[n0];
    float sd = 0.f, sn = 0.f;
    float mcur = funmap(am[curb * HC + c]);
    const int nend = min(n0 + 64, NN);
    for (int n = n0; n < nend; n++) {
        int b = batch[n];
        if (b != curb) {
            atomicAdd(&den[curb * HC + c], sd);
            atomicAdd(&num[curb * HC + c], sn);
            curb = b; sd = 0.f; sn = 0.f; mcur = funmap(am[b * HC + c]);
        }
        float w = __expf(a[(size_t)n * HC + c] - mcur);
        sd += w;
        sn += __bfloat162float(h2[(size_t)n * HC + c]) * w;
    }
    atomicAdd(&den[curb * HC + c], sd);
    atomicAdd(&num[curb * HC + c], sn);
}
__global__ void pool_div(const float* __restrict__ num, const float* __restrict__ den,
                         float* __restrict__ g) {
    int i = blockIdx.x * 256 + threadIdx.x;
    g[i] = num[i] / (den[i] + 1e-16f);
}

// ===================== head MLP ==========================================
__global__ void mlp_lin1(const float* __restrict__ g, const float* __restrict__ Wo1,
                         const float* __restrict__ bo1, float* __restrict__ y) {
    const int c = threadIdx.x;
    const int r = blockIdx.x;
    float acc = bo1[c];
#pragma unroll 4
    for (int k = 0; k < HC; k++) acc = fmaf(g[r * HC + k], Wo1[k * HC + c], acc);
    y[r * HC + c] = acc;
}
__global__ void bn_relu(float* __restrict__ y, const float* __restrict__ gamma,
                        const float* __restrict__ beta) {
    const int c = threadIdx.x;
    float s = 0.f, sq = 0.f;
    for (int r = 0; r < BB; r++) { float v = y[r * HC + c]; s += v; sq += v * v; }
    float mu  = s * (1.f / BB);
    float var = sq * (1.f / BB) - mu * mu;
    float inv = rsqrtf(var + 1e-5f) * gamma[c];
    float bt  = beta[c];
    for (int r = 0; r < BB; r++) {
        float v = (y[r * HC + c] - mu) * inv + bt;
        y[r * HC + c] = v > 0.f ? v : 0.f;
    }
}
__global__ void mlp_lin2(const float* __restrict__ y, const float* __restrict__ Wo2,
                         const float* __restrict__ bo2, float* __restrict__ out) {
    const int j = blockIdx.x * 256 + threadIdx.x;
    const int r = blockIdx.y;
    if (j >= 2001) return;
    float acc = bo2[j];
#pragma unroll 4
    for (int k = 0; k < HC; k++) acc = fmaf(y[r * HC + k], Wo2[k * 2001 + j], acc);
    out[r * 2001 + j] = acc > 0.f ? acc : 0.01f * acc;
}

// ===================== launcher ==========================================
extern "C" void kernel_launch(void* const* d_in, const int* in_sizes, int n_in,
                              void* d_out, int out_size, void* d_ws, size_t ws_size,
                              hipStream_t stream) {
    const float* x     = (const float*)d_in[0];
    const int*   ei    = (const int*)d_in[1];
    const float* ea    = (const float*)d_in[2];
    const int*   batch = (const int*)d_in[3];
    const float* W0 = (const float*)d_in[4];  const float* b0 = (const float*)d_in[5];
    const float* Wl1 = (const float*)d_in[6]; const float* bl1 = (const float*)d_in[7];
    const float* Wr1 = (const float*)d_in[8]; const float* br1 = (const float*)d_in[9];
    const float* We1 = (const float*)d_in[10]; const float* att1 = (const float*)d_in[11];
    const float* bias1 = (const float*)d_in[12];
    const float* Wl2 = (const float*)d_in[13]; const float* bl2 = (const float*)d_in[14];
    const float* Wr2 = (const float*)d_in[15]; const float* br2 = (const float*)d_in[16];
    const float* We2 = (const float*)d_in[17]; const float* att2 = (const float*)d_in[18];
    const float* bias2 = (const float*)d_in[19];
    const float* Wp = (const float*)d_in[20]; const float* bp = (const float*)d_in[21];
    const float* Wo1 = (const float*)d_in[22]; const float* bo1 = (const float*)d_in[23];
    const float* gamma = (const float*)d_in[24]; const float* beta = (const float*)d_in[25];
    const float* Wo2 = (const float*)d_in[26]; const float* bo2 = (const float*)d_in[27];
    float* out = (float*)d_out;

    // ---- workspace carve-up (256B aligned), ~115 MB ----
    char* p = (char*)d_ws;
    auto alloc = [&](size_t bytes) { char* r = p; p += (bytes + 255) & ~(size_t)255; return r; };
    const int MP = 30016;
    __hip_bfloat16* xpad  = (__hip_bfloat16*)alloc((size_t)MP * 32 * 2);
    __hip_bfloat16* W0t   = (__hip_bfloat16*)alloc(128 * 32 * 2);
    __hip_bfloat16* W1t   = (__hip_bfloat16*)alloc(512 * 128 * 2);
    __hip_bfloat16* We1t  = (__hip_bfloat16*)alloc(256 * 64 * 2);
    __hip_bfloat16* W2t   = (__hip_bfloat16*)alloc(512 * 256 * 2);
    __hip_bfloat16* We2t  = (__hip_bfloat16*)alloc(256 * 64 * 2);
    __hip_bfloat16* Wpt   = (__hip_bfloat16*)alloc(256 * 256 * 2);
    float* bcat1 = (float*)alloc(512 * 4);
    float* bcat2 = (float*)alloc(512 * 4);
    __hip_bfloat16* h0b  = (__hip_bfloat16*)alloc((size_t)MP * 128 * 2);
    __hip_bfloat16* xlrb = (__hip_bfloat16*)alloc((size_t)MP * 512 * 2);
    __hip_bfloat16* h1b  = (__hip_bfloat16*)alloc((size_t)MP * 256 * 2);
    __hip_bfloat16* h2b  = (__hip_bfloat16*)alloc((size_t)MP * 256 * 2);
    float* abuf = (float*)alloc((size_t)MP * 256 * 4);
    float* logit = (float*)alloc((size_t)EE * 4 * 4);
    int* deg    = (int*)alloc(NN * 4);
    int* cursor = (int*)alloc(NN * 4);
    int* partial= (int*)alloc(NN * 4);
    int* bsum   = (int*)alloc(256 * 4);
    int* start  = (int*)alloc((NN + 4) * 4);
    int* eidx   = (int*)alloc((size_t)EE * 4);
    int* src_csr= (int*)alloc((size_t)EE * 4);
    int* dst_csr= (int*)alloc((size_t)EE * 4);
    unsigned* am = (unsigned*)alloc(BB * HC * 4);
    float* den  = (float*)alloc(BB * HC * 4);
    float* num  = (float*)alloc(BB * HC * 4);
    float* g    = (float*)alloc(BB * HC * 4);
    float* ybuf = (float*)alloc(BB * HC * 4);

    const int NB = (NN + 255) / 256;

    // ---- input / weight packing ----
    pack_x<<<(NN * 32 + 255) / 256, 256, 0, stream>>>(x, xpad);
    PackJobs pj;
    pj.j[0] = {W0,  W0t, 13, 128, 32, 0};
    pj.j[1] = {Wl1, W1t, 128, 256, 128, 0};
    pj.j[2] = {Wr1, W1t, 128, 256, 128, 256};
    pj.j[3] = {We1, We1t, 51, 256, 64, 0};
    pj.j[4] = {Wl2, W2t, 256, 256, 256, 0};
    pj.j[5] = {Wr2, W2t, 256, 256, 256, 256};
    pj.j[6] = {We2, We2t, 51, 256, 64, 0};
    pj.j[7] = {Wp,  Wpt, 256, 256, 256, 0};
    pack_all<<<dim3(64, 8), 256, 0, stream>>>(pj);
    cat2<<<2, 256, 0, stream>>>(bl1, br1, bcat1);
    cat2<<<2, 256, 0, stream>>>(bl2, br2, bcat2);

    // ---- CSR build ----
    hipMemsetAsync(deg, 0, NN * 4, stream);
    hipMemsetAsync(cursor, 0, NN * 4, stream);
    hist_deg<<<(EE + 255) / 256, 256, 0, stream>>>(ei, deg);
    scan1<<<NB, 256, 0, stream>>>(deg, partial, bsum);
    scan2<<<1, 256, 0, stream>>>(bsum, NB);
    scan3<<<NB + 1, 256, 0, stream>>>(partial, bsum, start);
    scatter_e<<<(EE + 255) / 256, 256, 0, stream>>>(ei, cursor, start, eidx, src_csr, dst_csr);

    // ---- init transform ----
    mfma_gemm<2><<<dim3(469, 1), 256, 0, stream>>>(
        (const ushort*)xpad, (const ushort*)W0t, b0, nullptr, h0b, NN, 128, 32);

    // ---- GAT layer 1 ----
    mfma_gemm<4><<<dim3(469, 2), 256, 0, stream>>>(
        (const ushort*)h0b, (const ushort*)W1t, bcat1, nullptr, xlrb, NN, 512, 128);
    edge_fused<<<4688, 256, 0, stream>>>(ea, (const ushort*)We1t, att1, eidx,
                                         src_csr, dst_csr, (const ushort*)xlrb, logit);
    aggregate_csr<<<(NN + 3) / 4, 256, 0, stream>>>(
        (const ushort*)xlrb, logit, src_csr, start, bias1, (ushort*)h1b);

    // ---- GAT layer 2 ----
    mfma_gemm<4><<<dim3(469, 2), 256, 0, stream>>>(
        (const ushort*)h1b, (const ushort*)W2t, bcat2, nullptr, xlrb, NN, 512, 256);
    edge_fused<<<4688, 256, 0, stream>>>(ea, (const ushort*)We2t, att2, eidx,
                                         src_csr, dst_csr, (const ushort*)xlrb, logit);
    aggregate_csr<<<(NN + 3) / 4, 256, 0, stream>>>(
        (const ushort*)xlrb, logit, src_csr, start, bias2, (ushort*)h2b);

    // ---- attention pooling (chunk-parallel) ----
    mfma_gemm<4><<<dim3(469, 1), 256, 0, stream>>>(
        (const ushort*)h2b, (const ushort*)Wpt, bp, abuf, nullptr, NN, 256, 256);
    hipMemsetAsync(am, 0, BB * HC * 4, stream);
    hipMemsetAsync(den, 0, BB * HC * 4, stream);
    hipMemsetAsync(num, 0, BB * HC * 4, stream);
    const int poolGrid = (NN + 63) / 64;
    pool_max<<<poolGrid, HC, 0, stream>>>(abuf, batch, am);
    pool_sums<<<poolGrid, HC, 0, stream>>>(abuf, h2b, batch, am, den, num);
    pool_div<<<BB, HC, 0, stream>>>(num, den, g);

    // ---- head MLP ----
    mlp_lin1<<<BB, HC, 0, stream>>>(g, Wo1, bo1, ybuf);
    bn_relu<<<1, HC, 0, stream>>>(ybuf, gamma, beta);
    mlp_lin2<<<dim3(8, BB), 256, 0, stream>>>(ybuf, Wo2, bo2, out);
}

// Round 7
// 646.414 us; speedup vs baseline: 2.9533x; 1.0703x over previous
//
#include <hip/hip_runtime.h>
#include <hip/hip_bf16.h>

#define NN 30000
#define EE 300000
#define BB 64
#define HH 4
#define CC 64
#define HC 256

typedef __attribute__((ext_vector_type(8))) short short8;
typedef __attribute__((ext_vector_type(4))) float floatx4;

__device__ __forceinline__ float b2f(short x) {
    return __uint_as_float(((unsigned)(unsigned short)x) << 16);
}
__device__ __forceinline__ unsigned short f2b(float f) {
    __hip_bfloat16 h = __float2bfloat16(f);
    return *(unsigned short*)&h;
}

#define GLD16(gp, lp) __builtin_amdgcn_global_load_lds( \
    (const __attribute__((address_space(1))) void*)(gp), \
    (__attribute__((address_space(3))) void*)(lp), 16, 0, 0)

// 5-bit rotate-left-by-2
#define ROT2(x) ((((x) << 2) | ((x) >> 3)) & 31)

// ===================== bf16 MFMA GEMM (dense transforms) =================
template<int CT>
__global__ __launch_bounds__(256) void mfma_gemm(
    const ushort* __restrict__ A, const ushort* __restrict__ Bt,
    const float* __restrict__ bias, float* __restrict__ outF,
    __hip_bfloat16* __restrict__ outB, int M, int Nc, int K) {
    __shared__ __align__(16) ushort lA[64 * 32];
    __shared__ __align__(16) ushort lB[CT * 64 * 32];
    const int tid = threadIdx.x, lane = tid & 63, wv = tid >> 6;
    const int row0 = blockIdx.x * 64, col0 = blockIdx.y * (CT * 64);

    floatx4 acc[4][CT];
#pragma unroll
    for (int r = 0; r < 4; r++)
#pragma unroll
        for (int c = 0; c < CT; c++) acc[r][c] = (floatx4){0.f, 0.f, 0.f, 0.f};

    const int arow = tid >> 2;
    const int sl   = (tid & 3) ^ ((tid >> 3) & 3);
    const ushort* ga = A + (size_t)(row0 + arow) * K + sl * 8;
    const int m16 = lane & 15, q = lane >> 4;

    for (int k0 = 0; k0 < K; k0 += 32) {
        __syncthreads();
        GLD16(ga + k0, &lA[tid * 8]);
#pragma unroll
        for (int j = 0; j < CT; j++) {
            const ushort* gb = Bt + (size_t)(col0 + j * 64 + arow) * K + k0 + sl * 8;
            GLD16(gb, &lB[j * 2048 + tid * 8]);
        }
        __syncthreads();
        short8 aF[4], bF[CT];
#pragma unroll
        for (int r = 0; r < 4; r++) {
            int rr = r * 16 + m16;
            aF[r] = *(const short8*)&lA[rr * 32 + ((q ^ ((rr >> 1) & 3)) << 3)];
        }
#pragma unroll
        for (int c = 0; c < CT; c++) {
            int nr = (wv * CT + c) * 16 + m16;
            bF[c] = *(const short8*)&lB[nr * 32 + ((q ^ ((nr >> 1) & 3)) << 3)];
        }
#pragma unroll
        for (int r = 0; r < 4; r++)
#pragma unroll
            for (int c = 0; c < CT; c++)
                acc[r][c] = __builtin_amdgcn_mfma_f32_16x16x32_bf16(aF[r], bF[c], acc[r][c], 0, 0, 0);
    }

#pragma unroll
    for (int c = 0; c < CT; c++) {
        int col = col0 + (wv * CT + c) * 16 + m16;
        float bv = bias ? bias[col] : 0.f;
#pragma unroll
        for (int r = 0; r < 4; r++)
#pragma unroll
            for (int j = 0; j < 4; j++) {
                int row = row0 + r * 16 + q * 4 + j;
                if (row < M) {
                    float v = acc[r][c][j] + bv;
                    if (outB) outB[(size_t)row * Nc + col] = __float2bfloat16(v);
                    else      outF[(size_t)row * Nc + col] = v;
                }
            }
    }
}

// ===================== ea -> A-fragment-order bf16 (CSR tiles) ===========
// ea_frag[tile][((r*8+ch)*16+m16)*8+j] = bf16(ea[eidx[tile*64+r*16+m16]][ch*8+j])
__global__ void permute_ea_frag(const float* __restrict__ ea,
                                const int* __restrict__ eidx,
                                ushort* __restrict__ ea_frag) {
    const int t = threadIdx.x, tile = blockIdx.x;
    const int r  = t >> 6;
    const int ch = (t >> 3) & 7;
    const int m0 = (t * 2) & 15;
    ushort* outp = ea_frag + (size_t)tile * 4096 + t * 16;
#pragma unroll
    for (int half = 0; half < 2; half++) {
        int row = r * 16 + m0 + half;
        int gi = tile * 64 + row;
        int e = (gi < EE) ? eidx[gi] : -1;
        short8 v8;
#pragma unroll
        for (int j = 0; j < 8; j++) {
            int k = ch * 8 + j;
            float v = (e >= 0 && k < 51) ? ea[(size_t)e * 51 + k] : 0.f;
            v8[j] = (short)f2b(v);
        }
        *(short8*)(outp + half * 8) = v8;
    }
}

// ===================== We -> B-fragment-order bf16 =======================
// Wfrag[((nt*8+ch)*16+m16)*8+j] = bf16(We[(ch*8+j)*256 + nt*16+m16])
__global__ void pack_we_frag(const float* __restrict__ WeA,
                             const float* __restrict__ WeB,
                             ushort* __restrict__ WfA, ushort* __restrict__ WfB) {
    const float* We = blockIdx.y ? WeB : WeA;
    ushort* Wf = blockIdx.y ? WfB : WfA;
    int o = blockIdx.x * 256 + threadIdx.x;   // 64 blocks * 256 = 16384
    int j = o & 7, m16 = (o >> 3) & 15, ch = (o >> 7) & 7, nt = o >> 10;
    int n = nt * 16 + m16, k = ch * 8 + j;
    float v = (k < 51) ? We[k * 256 + n] : 0.f;
    Wf[o] = f2b(v);
}

// ===================== fused ee-MFMA + edge logit (one barrier) ==========
__global__ __launch_bounds__(256, 4) void edge_fused(
    const ushort* __restrict__ ea_frag, const ushort* __restrict__ Wfrag,
    const float* __restrict__ att,
    const int* __restrict__ src_csr, const int* __restrict__ dst_csr,
    const ushort* __restrict__ xlr, float* __restrict__ logitp) {
    __shared__ __align__(16) ushort eeS[64 * 256];   // 32 KB
    __shared__ float satt[256];
    const int tid = threadIdx.x, lane = tid & 63, wv = tid >> 6;
    const int i0 = blockIdx.x * 64;
    satt[tid] = att[tid];
    const int m16 = lane & 15, q = lane >> 4;

    floatx4 acc[4][4];
#pragma unroll
    for (int r = 0; r < 4; r++)
#pragma unroll
        for (int c = 0; c < 4; c++) acc[r][c] = (floatx4){0.f, 0.f, 0.f, 0.f};

    const ushort* af = ea_frag + (size_t)blockIdx.x * 4096;
#pragma unroll
    for (int k0 = 0; k0 < 2; k0++) {
        short8 aF[4], bF[4];
#pragma unroll
        for (int r = 0; r < 4; r++)
            aF[r] = *(const short8*)&af[((r * 8 + k0 * 4 + q) * 16 + m16) * 8];
#pragma unroll
        for (int c = 0; c < 4; c++)
            bF[c] = *(const short8*)&Wfrag[(((wv * 4 + c) * 8 + k0 * 4 + q) * 16 + m16) * 8];
#pragma unroll
        for (int r = 0; r < 4; r++)
#pragma unroll
            for (int c = 0; c < 4; c++)
                acc[r][c] = __builtin_amdgcn_mfma_f32_16x16x32_bf16(aF[r], bF[c], acc[r][c], 0, 0, 0);
    }

    // park ee tile: P = ROT2(chunk) ^ ((row>>2)&3)
#pragma unroll
    for (int r = 0; r < 4; r++)
#pragma unroll
        for (int cc = 0; cc < 4; cc++)
#pragma unroll
            for (int j = 0; j < 4; j++) {
                int row = r * 16 + q * 4 + j;
                int col = (wv * 4 + cc) * 16 + m16;
                int chunk = col >> 3;
                int P = ROT2(chunk) ^ ((row >> 2) & 3);
                eeS[row * 256 + (P << 3) + (col & 7)] = f2b(acc[r][cc][j]);
            }
    __syncthreads();

    // logit: thread = (CSR position el, head h)
    const int el = tid >> 2, h = tid & 3;
    const int i = i0 + el;
    if (i < EE) {
        int src = src_csr[i], dstn = dst_csr[i];
        const ushort* xlp = xlr + (size_t)src * 512 + h * 64;
        const ushort* xrp = xlr + (size_t)dstn * 512 + 256 + h * 64;
        float s = 0.f;
#pragma unroll
        for (int c = 0; c < 8; c++) {
            short8 xlv = *(const short8*)(xlp + c * 8);
            short8 xrv = *(const short8*)(xrp + c * 8);
            int chunk = h * 8 + c;
            int P = ROT2(chunk) ^ ((el >> 2) & 3);
            short8 eev = *(const short8*)&eeS[el * 256 + (P << 3)];
#pragma unroll
            for (int j = 0; j < 8; j++) {
                float v = b2f(xlv[j]) + b2f(xrv[j]) + b2f(eev[j]);
                v = v > 0.f ? v : 0.2f * v;
                s += v * satt[h * 64 + c * 8 + j];
            }
        }
        logitp[(size_t)i * 4 + h] = s;
    }
}

// ===================== packing ===========================================
__global__ void pack_x(const float* __restrict__ x, __hip_bfloat16* __restrict__ d) {
    int i = blockIdx.x * 256 + threadIdx.x;
    if (i >= NN * 32) return;
    int n = i >> 5, k = i & 31;
    d[i] = __float2bfloat16(k < 13 ? x[n * 13 + k] : 0.f);
}
struct PackJob { const float* W; __hip_bfloat16* dst; int K, Nc, Kpad, rowoff; };
struct PackJobs { PackJob j[6]; };
__global__ void pack_all(PackJobs jobs) {
    PackJob jb = jobs.j[blockIdx.y];
    int tot = jb.Nc * jb.Kpad;
    for (int i = blockIdx.x * 256 + threadIdx.x; i < tot; i += gridDim.x * 256) {
        int n = i / jb.Kpad, k = i - n * jb.Kpad;
        float v = (k < jb.K) ? jb.W[k * jb.Nc + n] : 0.f;
        jb.dst[(size_t)(jb.rowoff + n) * jb.Kpad + k] = __float2bfloat16(v);
    }
}
__global__ void cat2(const float* __restrict__ a, const float* __restrict__ b,
                     float* __restrict__ o) {
    int i = blockIdx.x * 256 + threadIdx.x;
    if (i < 512) o[i] = i < 256 ? a[i] : b[i - 256];
}

// ===================== CSR build =========================================
__global__ void hist_deg(const int* __restrict__ ei, int* __restrict__ deg) {
    int e = blockIdx.x * 256 + threadIdx.x;
    if (e < EE) atomicAdd(&deg[ei[EE + e]], 1);
}
__global__ void scan1(const int* __restrict__ deg, int* __restrict__ partial,
                      int* __restrict__ bsum) {
    __shared__ int sh[256];
    int t = threadIdx.x, i = blockIdx.x * 256 + t;
    int v = (i < NN) ? deg[i] : 0;
    sh[t] = v; __syncthreads();
    for (int off = 1; off < 256; off <<= 1) {
        int x = (t >= off) ? sh[t - off] : 0;
        __syncthreads();
        sh[t] += x;
        __syncthreads();
    }
    if (i < NN) partial[i] = sh[t] - v;
    if (t == 255) bsum[blockIdx.x] = sh[255];
}
__global__ void scan2(int* __restrict__ bsum, int nb) {
    __shared__ int sh[256];
    int t = threadIdx.x;
    int v = (t < nb) ? bsum[t] : 0;
    sh[t] = v; __syncthreads();
    for (int off = 1; off < 256; off <<= 1) {
        int x = (t >= off) ? sh[t - off] : 0;
        __syncthreads();
        sh[t] += x;
        __syncthreads();
    }
    if (t < nb) bsum[t] = sh[t] - v;
}
__global__ void scan3(const int* __restrict__ partial, const int* __restrict__ bsum,
                      int* __restrict__ start) {
    int i = blockIdx.x * 256 + threadIdx.x;
    if (i < NN) start[i] = partial[i] + bsum[i >> 8];
    else if (i == NN) start[NN] = EE;
}
__global__ void scatter_e(const int* __restrict__ ei, int* __restrict__ cursor,
                          const int* __restrict__ start, int* __restrict__ eidx,
                          int* __restrict__ src_csr, int* __restrict__ dst_csr) {
    int e = blockIdx.x * 256 + threadIdx.x;
    if (e >= EE) return;
    int s = ei[e];
    int d = ei[EE + e];
    int p = atomicAdd(&cursor[d], 1);
    int pos = start[d] + p;
    eidx[pos] = e;
    src_csr[pos] = s;
    dst_csr[pos] = d;
}

// ===================== fused segment softmax + aggregate =================
__global__ __launch_bounds__(256) void aggregate_csr(
    const ushort* __restrict__ xlr, const float* __restrict__ logitp,
    const int* __restrict__ src_csr, const int* __restrict__ start,
    const float* __restrict__ bias, ushort* __restrict__ outb) {
    const int lane = threadIdx.x & 63, wv = threadIdx.x >> 6;
    const int dst = blockIdx.x * 4 + wv;
    if (dst >= NN) return;
    const int s0 = start[dst];
    const int deg = start[dst + 1] - s0;
    const int h = lane >> 4;

    float m[4] = {-3.4e38f, -3.4e38f, -3.4e38f, -3.4e38f};
    float lg[4] = {0.f, 0.f, 0.f, 0.f};
    int mysrc = 0;
    if (lane < deg) {
        mysrc = src_csr[s0 + lane];
        float4 l4 = ((const float4*)logitp)[s0 + lane];
        lg[0] = l4.x; lg[1] = l4.y; lg[2] = l4.z; lg[3] = l4.w;
        m[0] = l4.x; m[1] = l4.y; m[2] = l4.z; m[3] = l4.w;
    }
    for (int i = 64 + lane; i < deg; i += 64) {
        float4 l4 = ((const float4*)logitp)[s0 + i];
        m[0] = fmaxf(m[0], l4.x); m[1] = fmaxf(m[1], l4.y);
        m[2] = fmaxf(m[2], l4.z); m[3] = fmaxf(m[3], l4.w);
    }
#pragma unroll
    for (int off = 32; off; off >>= 1)
#pragma unroll
        for (int k = 0; k < 4; k++) m[k] = fmaxf(m[k], __shfl_xor(m[k], off));

    float w[4], d[4];
#pragma unroll
    for (int k = 0; k < 4; k++) {
        w[k] = (lane < deg) ? __expf(lg[k] - m[k]) : 0.f;
        d[k] = w[k];
    }
    for (int i = 64 + lane; i < deg; i += 64) {
        float4 l4 = ((const float4*)logitp)[s0 + i];
        d[0] += __expf(l4.x - m[0]); d[1] += __expf(l4.y - m[1]);
        d[2] += __expf(l4.z - m[2]); d[3] += __expf(l4.w - m[3]);
    }
#pragma unroll
    for (int off = 32; off; off >>= 1)
#pragma unroll
        for (int k = 0; k < 4; k++) d[k] += __shfl_xor(d[k], off);
    const float dh = 1.f / (((h == 0) ? d[0] : (h == 1) ? d[1] : (h == 2) ? d[2] : d[3]) + 1e-16f);
    const float mh = (h == 0) ? m[0] : (h == 1) ? m[1] : (h == 2) ? m[2] : m[3];

    float4 b4 = ((const float4*)bias)[lane];
    float a0 = b4.x, a1 = b4.y, a2 = b4.z, a3 = b4.w;

    const int dcap = deg < 64 ? deg : 64;
    for (int i = 0; i < dcap; i++) {
        int srcv = __shfl(mysrc, i);
        float s0v = __shfl(w[0], i), s1v = __shfl(w[1], i);
        float s2v = __shfl(w[2], i), s3v = __shfl(w[3], i);
        float aw = ((h == 0) ? s0v : (h == 1) ? s1v : (h == 2) ? s2v : s3v) * dh;
        ushort4 xv = *(const ushort4*)(xlr + (size_t)srcv * 512 + lane * 4);
        a0 += b2f(xv.x) * aw; a1 += b2f(xv.y) * aw;
        a2 += b2f(xv.z) * aw; a3 += b2f(xv.w) * aw;
    }
    for (int i = 64; i < deg; i++) {
        int srcv = src_csr[s0 + i];
        float4 l4 = ((const float4*)logitp)[s0 + i];
        float lh = (h == 0) ? l4.x : (h == 1) ? l4.y : (h == 2) ? l4.z : l4.w;
        float aw = __expf(lh - mh) * dh;
        ushort4 xv = *(const ushort4*)(xlr + (size_t)srcv * 512 + lane * 4);
        a0 += b2f(xv.x) * aw; a1 += b2f(xv.y) * aw;
        a2 += b2f(xv.z) * aw; a3 += b2f(xv.w) * aw;
    }
    ushort4 ov;
    ov.x = f2b(a0); ov.y = f2b(a1); ov.z = f2b(a2); ov.w = f2b(a3);
    *(ushort4*)(outb + (size_t)dst * 256 + lane * 4) = ov;
}

// ===================== pooling: chunk-parallel ===========================
__device__ __forceinline__ unsigned fmap(float f) {
    unsigned u = __float_as_uint(f);
    return (u & 0x80000000u) ? ~u : (u | 0x80000000u);
}
__device__ __forceinline__ float funmap(unsigned u) {
    return (u & 0x80000000u) ? __uint_as_float(u & 0x7FFFFFFFu)
                             : __uint_as_float(~u);
}

__global__ void pool_max(const float* __restrict__ a, const int* __restrict__ batch,
                         unsigned* __restrict__ am) {
    const int c = threadIdx.x;
    const int n0 = blockIdx.x * 64;
    int curb = batch[n0];
    float m = -3.4e38f;
    const int nend = min(n0 + 64, NN);
    for (int n = n0; n < nend; n++) {
        int b = batch[n];
        float v = a[(size_t)n * HC + c];
        if (b != curb) { atomicMax(&am[curb * HC + c], fmap(m)); curb = b; m = v; }
        else           { m = fmaxf(m, v); }
    }
    atomicMax(&am[curb * HC + c], fmap(m));
}
__global__ void pool_sums(const float* __restrict__ a, const __hip_bfloat16* __restrict__ h2,
                          const int* __restrict__ batch, const unsigned* __restrict__ am,
                          float* __restrict__ den, float* __restrict__ num) {
    const int c = threadIdx.x;
    const int n0 = blockIdx.x * 64;
    int curb = batch[n0];
    float sd = 0.f, sn = 0.f;
    float mcur = funmap(am[curb * HC + c]);
    const int nend = min(n0 + 64, NN);
    for (int n = n0; n < nend; n++) {
        int b = batch[n];
        if (b != curb) {
            atomicAdd(&den[curb * HC + c], sd);
            atomicAdd(&num[curb * HC + c], sn);
            curb = b; sd = 0.f; sn = 0.f; mcur = funmap(am[b * HC + c]);
        }
        float w = __expf(a[(size_t)n * HC + c] - mcur);
        sd += w;
        sn += __bfloat162float(h2[(size_t)n * HC + c]) * w;
    }
    atomicAdd(&den[curb * HC + c], sd);
    atomicAdd(&num[curb * HC + c], sn);
}
__global__ void pool_div(const float* __restrict__ num, const float* __restrict__ den,
                         float* __restrict__ g) {
    int i = blockIdx.x * 256 + threadIdx.x;
    g[i] = num[i] / (den[i] + 1e-16f);
}

// ===================== head MLP ==========================================
__global__ void mlp_lin1(const float* __restrict__ g, const float* __restrict__ Wo1,
                         const float* __restrict__ bo1, float* __restrict__ y) {
    const int c = threadIdx.x;
    const int r = blockIdx.x;
    float acc = bo1[c];
#pragma unroll 4
    for (int k = 0; k < HC; k++) acc = fmaf(g[r * HC + k], Wo1[k * HC + c], acc);
    y[r * HC + c] = acc;
}
__global__ void bn_relu(float* __restrict__ y, const float* __restrict__ gamma,
                        const float* __restrict__ beta) {
    const int c = threadIdx.x;
    float s = 0.f, sq = 0.f;
    for (int r = 0; r < BB; r++) { float v = y[r * HC + c]; s += v; sq += v * v; }
    float mu  = s * (1.f / BB);
    float var = sq * (1.f / BB) - mu * mu;
    float inv = rsqrtf(var + 1e-5f) * gamma[c];
    float bt  = beta[c];
    for (int r = 0; r < BB; r++) {
        float v = (y[r * HC + c] - mu) * inv + bt;
        y[r * HC + c] = v > 0.f ? v : 0.f;
    }
}
__global__ void mlp_lin2(const float* __restrict__ y, const float* __restrict__ Wo2,
                         const float* __restrict__ bo2, float* __restrict__ out) {
    const int j = blockIdx.x * 256 + threadIdx.x;
    const int r = blockIdx.y;
    if (j >= 2001) return;
    float acc = bo2[j];
#pragma unroll 4
    for (int k = 0; k < HC; k++) acc = fmaf(y[r * HC + k], Wo2[k * 2001 + j], acc);
    out[r * 2001 + j] = acc > 0.f ? acc : 0.01f * acc;
}

// ===================== launcher ==========================================
extern "C" void kernel_launch(void* const* d_in, const int* in_sizes, int n_in,
                              void* d_out, int out_size, void* d_ws, size_t ws_size,
                              hipStream_t stream) {
    const float* x     = (const float*)d_in[0];
    const int*   ei    = (const int*)d_in[1];
    const float* ea    = (const float*)d_in[2];
    const int*   batch = (const int*)d_in[3];
    const float* W0 = (const float*)d_in[4];  const float* b0 = (const float*)d_in[5];
    const float* Wl1 = (const float*)d_in[6]; const float* bl1 = (const float*)d_in[7];
    const float* Wr1 = (const float*)d_in[8]; const float* br1 = (const float*)d_in[9];
    const float* We1 = (const float*)d_in[10]; const float* att1 = (const float*)d_in[11];
    const float* bias1 = (const float*)d_in[12];
    const float* Wl2 = (const float*)d_in[13]; const float* bl2 = (const float*)d_in[14];
    const float* Wr2 = (const float*)d_in[15]; const float* br2 = (const float*)d_in[16];
    const float* We2 = (const float*)d_in[17]; const float* att2 = (const float*)d_in[18];
    const float* bias2 = (const float*)d_in[19];
    const float* Wp = (const float*)d_in[20]; const float* bp = (const float*)d_in[21];
    const float* Wo1 = (const float*)d_in[22]; const float* bo1 = (const float*)d_in[23];
    const float* gamma = (const float*)d_in[24]; const float* beta = (const float*)d_in[25];
    const float* Wo2 = (const float*)d_in[26]; const float* bo2 = (const float*)d_in[27];
    float* out = (float*)d_out;

    // ---- workspace carve-up (256B aligned), ~154 MB ----
    char* p = (char*)d_ws;
    auto alloc = [&](size_t bytes) { char* r = p; p += (bytes + 255) & ~(size_t)255; return r; };
    const int MP = 30016;
    const int ET = 4688;                 // CSR tiles of 64
    __hip_bfloat16* xpad  = (__hip_bfloat16*)alloc((size_t)MP * 32 * 2);
    __hip_bfloat16* W0t   = (__hip_bfloat16*)alloc(128 * 32 * 2);
    __hip_bfloat16* W1t   = (__hip_bfloat16*)alloc(512 * 128 * 2);
    __hip_bfloat16* W2t   = (__hip_bfloat16*)alloc(512 * 256 * 2);
    __hip_bfloat16* Wpt   = (__hip_bfloat16*)alloc(256 * 256 * 2);
    ushort* Wef1 = (ushort*)alloc(256 * 64 * 2);
    ushort* Wef2 = (ushort*)alloc(256 * 64 * 2);
    float* bcat1 = (float*)alloc(512 * 4);
    float* bcat2 = (float*)alloc(512 * 4);
    __hip_bfloat16* h0b  = (__hip_bfloat16*)alloc((size_t)MP * 128 * 2);
    __hip_bfloat16* xlrb = (__hip_bfloat16*)alloc((size_t)MP * 512 * 2);
    __hip_bfloat16* h1b  = (__hip_bfloat16*)alloc((size_t)MP * 256 * 2);
    __hip_bfloat16* h2b  = (__hip_bfloat16*)alloc((size_t)MP * 256 * 2);
    ushort* ea_frag = (ushort*)alloc((size_t)ET * 4096 * 2);   // 38.4 MB
    float* abuf = (float*)alloc((size_t)MP * 256 * 4);
    float* logit = (float*)alloc((size_t)EE * 4 * 4);
    int* deg    = (int*)alloc(NN * 4);
    int* cursor = (int*)alloc(NN * 4);
    int* partial= (int*)alloc(NN * 4);
    int* bsum   = (int*)alloc(256 * 4);
    int* start  = (int*)alloc((NN + 4) * 4);
    int* eidx   = (int*)alloc((size_t)EE * 4);
    int* src_csr= (int*)alloc((size_t)EE * 4);
    int* dst_csr= (int*)alloc((size_t)EE * 4);
    unsigned* am = (unsigned*)alloc(BB * HC * 4);
    float* den  = (float*)alloc(BB * HC * 4);
    float* num  = (float*)alloc(BB * HC * 4);
    float* g    = (float*)alloc(BB * HC * 4);
    float* ybuf = (float*)alloc(BB * HC * 4);

    const int NB = (NN + 255) / 256;

    // ---- input / weight packing ----
    pack_x<<<(NN * 32 + 255) / 256, 256, 0, stream>>>(x, xpad);
    PackJobs pj;
    pj.j[0] = {W0,  W0t, 13, 128, 32, 0};
    pj.j[1] = {Wl1, W1t, 128, 256, 128, 0};
    pj.j[2] = {Wr1, W1t, 128, 256, 128, 256};
    pj.j[3] = {Wl2, W2t, 256, 256, 256, 0};
    pj.j[4] = {Wr2, W2t, 256, 256, 256, 256};
    pj.j[5] = {Wp,  Wpt, 256, 256, 256, 0};
    pack_all<<<dim3(64, 6), 256, 0, stream>>>(pj);
    pack_we_frag<<<dim3(64, 2), 256, 0, stream>>>(We1, We2, Wef1, Wef2);
    cat2<<<2, 256, 0, stream>>>(bl1, br1, bcat1);
    cat2<<<2, 256, 0, stream>>>(bl2, br2, bcat2);

    // ---- CSR build ----
    hipMemsetAsync(deg, 0, NN * 4, stream);
    hipMemsetAsync(cursor, 0, NN * 4, stream);
    hist_deg<<<(EE + 255) / 256, 256, 0, stream>>>(ei, deg);
    scan1<<<NB, 256, 0, stream>>>(deg, partial, bsum);
    scan2<<<1, 256, 0, stream>>>(bsum, NB);
    scan3<<<NB + 1, 256, 0, stream>>>(partial, bsum, start);
    scatter_e<<<(EE + 255) / 256, 256, 0, stream>>>(ei, cursor, start, eidx, src_csr, dst_csr);
    permute_ea_frag<<<ET, 256, 0, stream>>>(ea, eidx, ea_frag);

    // ---- init transform ----
    mfma_gemm<2><<<dim3(469, 1), 256, 0, stream>>>(
        (const ushort*)xpad, (const ushort*)W0t, b0, nullptr, h0b, NN, 128, 32);

    // ---- GAT layer 1 ----
    mfma_gemm<4><<<dim3(469, 2), 256, 0, stream>>>(
        (const ushort*)h0b, (const ushort*)W1t, bcat1, nullptr, xlrb, NN, 512, 128);
    edge_fused<<<ET, 256, 0, stream>>>(ea_frag, Wef1, att1, src_csr, dst_csr,
                                       (const ushort*)xlrb, logit);
    aggregate_csr<<<(NN + 3) / 4, 256, 0, stream>>>(
        (const ushort*)xlrb, logit, src_csr, start, bias1, (ushort*)h1b);

    // ---- GAT layer 2 ----
    mfma_gemm<4><<<dim3(469, 2), 256, 0, stream>>>(
        (const ushort*)h1b, (const ushort*)W2t, bcat2, nullptr, xlrb, NN, 512, 256);
    edge_fused<<<ET, 256, 0, stream>>>(ea_frag, Wef2, att2, src_csr, dst_csr,
                                       (const ushort*)xlrb, logit);
    aggregate_csr<<<(NN + 3) / 4, 256, 0, stream>>>(
        (const ushort*)xlrb, logit, src_csr, start, bias2, (ushort*)h2b);

    // ---- attention pooling (chunk-parallel) ----
    mfma_gemm<4><<<dim3(469, 1), 256, 0, stream>>>(
        (const ushort*)h2b, (const ushort*)Wpt, bp, abuf, nullptr, NN, 256, 256);
    hipMemsetAsync(am, 0, BB * HC * 4, stream);
    hipMemsetAsync(den, 0, BB * HC * 4, stream);
    hipMemsetAsync(num, 0, BB * HC * 4, stream);
    const int poolGrid = (NN + 63) / 64;
    pool_max<<<poolGrid, HC, 0, stream>>>(abuf, batch, am);
    pool_sums<<<poolGrid, HC, 0, stream>>>(abuf, h2b, batch, am, den, num);
    pool_div<<<BB, HC, 0, stream>>>(num, den, g);

    // ---- head MLP ----
    mlp_lin1<<<BB, HC, 0, stream>>>(g, Wo1, bo1, ybuf);
    bn_relu<<<1, HC, 0, stream>>>(ybuf, gamma, beta);
    mlp_lin2<<<dim3(8, BB), 256, 0, stream>>>(ybuf, Wo2, bo2, out);
}

// Round 8
// 627.218 us; speedup vs baseline: 3.0436x; 1.0306x over previous
//
#include <hip/hip_runtime.h>
#include <hip/hip_bf16.h>

#define NN 30000
#define EE 300000
#define BB 64
#define HH 4
#define CC 64
#define HC 256

typedef __attribute__((ext_vector_type(8))) short short8;
typedef __attribute__((ext_vector_type(4))) float floatx4;

__device__ __forceinline__ float b2f(short x) {
    return __uint_as_float(((unsigned)(unsigned short)x) << 16);
}
__device__ __forceinline__ unsigned short f2b(float f) {
    __hip_bfloat16 h = __float2bfloat16(f);
    return *(unsigned short*)&h;
}

#define GLD16(gp, lp) __builtin_amdgcn_global_load_lds( \
    (const __attribute__((address_space(1))) void*)(gp), \
    (__attribute__((address_space(3))) void*)(lp), 16, 0, 0)

// 5-bit rotate-left-by-2
#define ROT2(x) ((((x) << 2) | ((x) >> 3)) & 31)
// full eeS swizzle: 3-bit spread (bits from row2..3 and row0)
#define EESWZ(chunk, row) (ROT2(chunk) ^ (((row) >> 2) & 3) ^ (((row) & 1) << 2))

// ===================== bf16 MFMA GEMM (dense transforms) =================
template<int CT>
__global__ __launch_bounds__(256) void mfma_gemm(
    const ushort* __restrict__ A, const ushort* __restrict__ Bt,
    const float* __restrict__ bias, float* __restrict__ outF,
    __hip_bfloat16* __restrict__ outB, int M, int Nc, int K) {
    __shared__ __align__(16) ushort lA[64 * 32];
    __shared__ __align__(16) ushort lB[CT * 64 * 32];
    const int tid = threadIdx.x, lane = tid & 63, wv = tid >> 6;
    const int row0 = blockIdx.x * 64, col0 = blockIdx.y * (CT * 64);

    floatx4 acc[4][CT];
#pragma unroll
    for (int r = 0; r < 4; r++)
#pragma unroll
        for (int c = 0; c < CT; c++) acc[r][c] = (floatx4){0.f, 0.f, 0.f, 0.f};

    const int arow = tid >> 2;
    const int sl   = (tid & 3) ^ ((tid >> 3) & 3);
    const ushort* ga = A + (size_t)(row0 + arow) * K + sl * 8;
    const int m16 = lane & 15, q = lane >> 4;

    for (int k0 = 0; k0 < K; k0 += 32) {
        __syncthreads();
        GLD16(ga + k0, &lA[tid * 8]);
#pragma unroll
        for (int j = 0; j < CT; j++) {
            const ushort* gb = Bt + (size_t)(col0 + j * 64 + arow) * K + k0 + sl * 8;
            GLD16(gb, &lB[j * 2048 + tid * 8]);
        }
        __syncthreads();
        short8 aF[4], bF[CT];
#pragma unroll
        for (int r = 0; r < 4; r++) {
            int rr = r * 16 + m16;
            aF[r] = *(const short8*)&lA[rr * 32 + ((q ^ ((rr >> 1) & 3)) << 3)];
        }
#pragma unroll
        for (int c = 0; c < CT; c++) {
            int nr = (wv * CT + c) * 16 + m16;
            bF[c] = *(const short8*)&lB[nr * 32 + ((q ^ ((nr >> 1) & 3)) << 3)];
        }
#pragma unroll
        for (int r = 0; r < 4; r++)
#pragma unroll
            for (int c = 0; c < CT; c++)
                acc[r][c] = __builtin_amdgcn_mfma_f32_16x16x32_bf16(aF[r], bF[c], acc[r][c], 0, 0, 0);
    }

#pragma unroll
    for (int c = 0; c < CT; c++) {
        int col = col0 + (wv * CT + c) * 16 + m16;
        float bv = bias ? bias[col] : 0.f;
#pragma unroll
        for (int r = 0; r < 4; r++)
#pragma unroll
            for (int j = 0; j < 4; j++) {
                int row = row0 + r * 16 + q * 4 + j;
                if (row < M) {
                    float v = acc[r][c][j] + bv;
                    if (outB) outB[(size_t)row * Nc + col] = __float2bfloat16(v);
                    else      outF[(size_t)row * Nc + col] = v;
                }
            }
    }
}

// ===================== ea -> A-fragment-order bf16 (CSR tiles) ===========
__global__ void permute_ea_frag(const float* __restrict__ ea,
                                const int* __restrict__ eidx,
                                ushort* __restrict__ ea_frag) {
    const int t = threadIdx.x, tile = blockIdx.x;
    const int r  = t >> 6;
    const int ch = (t >> 3) & 7;
    const int m0 = (t * 2) & 15;
    ushort* outp = ea_frag + (size_t)tile * 4096 + t * 16;
#pragma unroll
    for (int half = 0; half < 2; half++) {
        int row = r * 16 + m0 + half;
        int gi = tile * 64 + row;
        int e = (gi < EE) ? eidx[gi] : -1;
        short8 v8;
#pragma unroll
        for (int j = 0; j < 8; j++) {
            int k = ch * 8 + j;
            float v = (e >= 0 && k < 51) ? ea[(size_t)e * 51 + k] : 0.f;
            v8[j] = (short)f2b(v);
        }
        *(short8*)(outp + half * 8) = v8;
    }
}

// ===================== We -> B-fragment-order bf16 =======================
__global__ void pack_we_frag(const float* __restrict__ WeA,
                             const float* __restrict__ WeB,
                             ushort* __restrict__ WfA, ushort* __restrict__ WfB) {
    const float* We = blockIdx.y ? WeB : WeA;
    ushort* Wf = blockIdx.y ? WfB : WfA;
    int o = blockIdx.x * 256 + threadIdx.x;
    int j = o & 7, m16 = (o >> 3) & 15, ch = (o >> 7) & 7, nt = o >> 10;
    int n = nt * 16 + m16, k = ch * 8 + j;
    float v = (k < 51) ? We[k * 256 + n] : 0.f;
    Wf[o] = f2b(v);
}

// ===================== fused ee-MFMA + edge logit (one barrier) ==========
__global__ __launch_bounds__(256, 4) void edge_fused(
    const ushort* __restrict__ ea_frag, const ushort* __restrict__ Wfrag,
    const float* __restrict__ att,
    const int* __restrict__ src_csr, const int* __restrict__ dst_csr,
    const ushort* __restrict__ xlr, float* __restrict__ logitp) {
    __shared__ __align__(16) ushort eeS[64 * 256];   // 32 KB
    __shared__ float satt[256];
    const int tid = threadIdx.x, lane = tid & 63, wv = tid >> 6;
    const int i0 = blockIdx.x * 64;
    satt[tid] = att[tid];
    const int m16 = lane & 15, q = lane >> 4;

    floatx4 acc[4][4];
#pragma unroll
    for (int r = 0; r < 4; r++)
#pragma unroll
        for (int c = 0; c < 4; c++) acc[r][c] = (floatx4){0.f, 0.f, 0.f, 0.f};

    const ushort* af = ea_frag + (size_t)blockIdx.x * 4096;
#pragma unroll
    for (int k0 = 0; k0 < 2; k0++) {
        short8 aF[4], bF[4];
#pragma unroll
        for (int r = 0; r < 4; r++)
            aF[r] = *(const short8*)&af[((r * 8 + k0 * 4 + q) * 16 + m16) * 8];
#pragma unroll
        for (int c = 0; c < 4; c++)
            bF[c] = *(const short8*)&Wfrag[(((wv * 4 + c) * 8 + k0 * 4 + q) * 16 + m16) * 8];
#pragma unroll
        for (int r = 0; r < 4; r++)
#pragma unroll
            for (int c = 0; c < 4; c++)
                acc[r][c] = __builtin_amdgcn_mfma_f32_16x16x32_bf16(aF[r], bF[c], acc[r][c], 0, 0, 0);
    }

    // park ee tile with 3-bit swizzle
#pragma unroll
    for (int r = 0; r < 4; r++)
#pragma unroll
        for (int cc = 0; cc < 4; cc++)
#pragma unroll
            for (int j = 0; j < 4; j++) {
                int row = r * 16 + q * 4 + j;
                int col = (wv * 4 + cc) * 16 + m16;
                int chunk = col >> 3;
                int P = EESWZ(chunk, row);
                eeS[row * 256 + (P << 3) + (col & 7)] = f2b(acc[r][cc][j]);
            }
    __syncthreads();

    // logit: thread = (CSR position el, head h)
    const int el = tid >> 2, h = tid & 3;
    const int i = i0 + el;
    if (i < EE) {
        int src = src_csr[i], dstn = dst_csr[i];
        const ushort* xlp = xlr + (size_t)src * 512 + h * 64;
        const ushort* xrp = xlr + (size_t)dstn * 512 + 256 + h * 64;
        float s = 0.f;
#pragma unroll
        for (int c = 0; c < 8; c++) {
            short8 xlv = *(const short8*)(xlp + c * 8);
            short8 xrv = *(const short8*)(xrp + c * 8);
            int chunk = h * 8 + c;
            int P = EESWZ(chunk, el);
            short8 eev = *(const short8*)&eeS[el * 256 + (P << 3)];
#pragma unroll
            for (int j = 0; j < 8; j++) {
                float v = b2f(xlv[j]) + b2f(xrv[j]) + b2f(eev[j]);
                v = v > 0.f ? v : 0.2f * v;
                s += v * satt[h * 64 + c * 8 + j];
            }
        }
        logitp[(size_t)i * 4 + h] = s;
    }
}

// ===================== packing ===========================================
__global__ void pack_x(const float* __restrict__ x, __hip_bfloat16* __restrict__ d,
                       int* __restrict__ deg) {
    int i = blockIdx.x * 256 + threadIdx.x;
    if (i < NN) deg[i] = 0;                     // folded memset (hist_deg runs later)
    if (i >= NN * 32) return;
    int n = i >> 5, k = i & 31;
    d[i] = __float2bfloat16(k < 13 ? x[n * 13 + k] : 0.f);
}
struct PackJob { const float* W; __hip_bfloat16* dst; int K, Nc, Kpad, rowoff; };
struct PackJobs { PackJob j[6]; };
__global__ void pack_all(PackJobs jobs) {
    PackJob jb = jobs.j[blockIdx.y];
    int tot = jb.Nc * jb.Kpad;
    for (int i = blockIdx.x * 256 + threadIdx.x; i < tot; i += gridDim.x * 256) {
        int n = i / jb.Kpad, k = i - n * jb.Kpad;
        float v = (k < jb.K) ? jb.W[k * jb.Nc + n] : 0.f;
        jb.dst[(size_t)(jb.rowoff + n) * jb.Kpad + k] = __float2bfloat16(v);
    }
}
__global__ void cat2(const float* __restrict__ a, const float* __restrict__ b,
                     float* __restrict__ o) {
    int i = blockIdx.x * 256 + threadIdx.x;
    if (i < 512) o[i] = i < 256 ? a[i] : b[i - 256];
}

// ===================== CSR build =========================================
__global__ void hist_deg(const int* __restrict__ ei, int* __restrict__ deg) {
    int e = blockIdx.x * 256 + threadIdx.x;
    if (e < EE) atomicAdd(&deg[ei[EE + e]], 1);
}
__global__ void scan1(const int* __restrict__ deg, int* __restrict__ partial,
                      int* __restrict__ bsum) {
    __shared__ int sh[256];
    int t = threadIdx.x, i = blockIdx.x * 256 + t;
    int v = (i < NN) ? deg[i] : 0;
    sh[t] = v; __syncthreads();
    for (int off = 1; off < 256; off <<= 1) {
        int x = (t >= off) ? sh[t - off] : 0;
        __syncthreads();
        sh[t] += x;
        __syncthreads();
    }
    if (i < NN) partial[i] = sh[t] - v;
    if (t == 255) bsum[blockIdx.x] = sh[255];
}
__global__ void scan2(int* __restrict__ bsum, int nb) {
    __shared__ int sh[256];
    int t = threadIdx.x;
    int v = (t < nb) ? bsum[t] : 0;
    sh[t] = v; __syncthreads();
    for (int off = 1; off < 256; off <<= 1) {
        int x = (t >= off) ? sh[t - off] : 0;
        __syncthreads();
        sh[t] += x;
        __syncthreads();
    }
    if (t < nb) bsum[t] = sh[t] - v;
}
__global__ void scan3(const int* __restrict__ partial, const int* __restrict__ bsum,
                      int* __restrict__ start, int* __restrict__ cursor) {
    int i = blockIdx.x * 256 + threadIdx.x;
    if (i < NN) { start[i] = partial[i] + bsum[i >> 8]; cursor[i] = 0; }
    else if (i == NN) start[NN] = EE;
}
__global__ void scatter_e(const int* __restrict__ ei, int* __restrict__ cursor,
                          const int* __restrict__ start, int* __restrict__ eidx,
                          int* __restrict__ src_csr, int* __restrict__ dst_csr) {
    int e = blockIdx.x * 256 + threadIdx.x;
    if (e >= EE) return;
    int s = ei[e];
    int d = ei[EE + e];
    int p = atomicAdd(&cursor[d], 1);
    int pos = start[d] + p;
    eidx[pos] = e;
    src_csr[pos] = s;
    dst_csr[pos] = d;
}

// ===================== fused segment softmax + aggregate =================
__global__ __launch_bounds__(256) void aggregate_csr(
    const ushort* __restrict__ xlr, const float* __restrict__ logitp,
    const int* __restrict__ src_csr, const int* __restrict__ start,
    const float* __restrict__ bias, ushort* __restrict__ outb) {
    const int lane = threadIdx.x & 63, wv = threadIdx.x >> 6;
    const int dst = blockIdx.x * 4 + wv;
    if (dst >= NN) return;
    const int s0 = start[dst];
    const int deg = start[dst + 1] - s0;
    const int h = lane >> 4;

    float m[4] = {-3.4e38f, -3.4e38f, -3.4e38f, -3.4e38f};
    float lg[4] = {0.f, 0.f, 0.f, 0.f};
    int mysrc = 0;
    if (lane < deg) {
        mysrc = src_csr[s0 + lane];
        float4 l4 = ((const float4*)logitp)[s0 + lane];
        lg[0] = l4.x; lg[1] = l4.y; lg[2] = l4.z; lg[3] = l4.w;
        m[0] = l4.x; m[1] = l4.y; m[2] = l4.z; m[3] = l4.w;
    }
    for (int i = 64 + lane; i < deg; i += 64) {
        float4 l4 = ((const float4*)logitp)[s0 + i];
        m[0] = fmaxf(m[0], l4.x); m[1] = fmaxf(m[1], l4.y);
        m[2] = fmaxf(m[2], l4.z); m[3] = fmaxf(m[3], l4.w);
    }
#pragma unroll
    for (int off = 32; off; off >>= 1)
#pragma unroll
        for (int k = 0; k < 4; k++) m[k] = fmaxf(m[k], __shfl_xor(m[k], off));

    float w[4], d[4];
#pragma unroll
    for (int k = 0; k < 4; k++) {
        w[k] = (lane < deg) ? __expf(lg[k] - m[k]) : 0.f;
        d[k] = w[k];
    }
    for (int i = 64 + lane; i < deg; i += 64) {
        float4 l4 = ((const float4*)logitp)[s0 + i];
        d[0] += __expf(l4.x - m[0]); d[1] += __expf(l4.y - m[1]);
        d[2] += __expf(l4.z - m[2]); d[3] += __expf(l4.w - m[3]);
    }
#pragma unroll
    for (int off = 32; off; off >>= 1)
#pragma unroll
        for (int k = 0; k < 4; k++) d[k] += __shfl_xor(d[k], off);
    const float dh = 1.f / (((h == 0) ? d[0] : (h == 1) ? d[1] : (h == 2) ? d[2] : d[3]) + 1e-16f);
    const float mh = (h == 0) ? m[0] : (h == 1) ? m[1] : (h == 2) ? m[2] : m[3];

    float4 b4 = ((const float4*)bias)[lane];
    float a0 = b4.x, a1 = b4.y, a2 = b4.z, a3 = b4.w;

    const int dcap = deg < 64 ? deg : 64;
    const ushort* xbase = xlr + (size_t)lane * 4;
    int i = 0;
    // 4-wide batching: 4 independent gathers in flight
    for (; i + 4 <= dcap; i += 4) {
        int sv[4]; float aw[4];
#pragma unroll
        for (int u = 0; u < 4; u++) {
            sv[u] = __shfl(mysrc, i + u);
            float s0v = __shfl(w[0], i + u), s1v = __shfl(w[1], i + u);
            float s2v = __shfl(w[2], i + u), s3v = __shfl(w[3], i + u);
            aw[u] = ((h == 0) ? s0v : (h == 1) ? s1v : (h == 2) ? s2v : s3v) * dh;
        }
        ushort4 xv[4];
#pragma unroll
        for (int u = 0; u < 4; u++)
            xv[u] = *(const ushort4*)(xbase + (size_t)sv[u] * 512);
#pragma unroll
        for (int u = 0; u < 4; u++) {
            a0 += b2f(xv[u].x) * aw[u]; a1 += b2f(xv[u].y) * aw[u];
            a2 += b2f(xv[u].z) * aw[u]; a3 += b2f(xv[u].w) * aw[u];
        }
    }
    for (; i < dcap; i++) {
        int srcv = __shfl(mysrc, i);
        float s0v = __shfl(w[0], i), s1v = __shfl(w[1], i);
        float s2v = __shfl(w[2], i), s3v = __shfl(w[3], i);
        float aw = ((h == 0) ? s0v : (h == 1) ? s1v : (h == 2) ? s2v : s3v) * dh;
        ushort4 xv = *(const ushort4*)(xbase + (size_t)srcv * 512);
        a0 += b2f(xv.x) * aw; a1 += b2f(xv.y) * aw;
        a2 += b2f(xv.z) * aw; a3 += b2f(xv.w) * aw;
    }
    for (int ii = 64; ii < deg; ii++) {
        int srcv = src_csr[s0 + ii];
        float4 l4 = ((const float4*)logitp)[s0 + ii];
        float lh = (h == 0) ? l4.x : (h == 1) ? l4.y : (h == 2) ? l4.z : l4.w;
        float aw = __expf(lh - mh) * dh;
        ushort4 xv = *(const ushort4*)(xbase + (size_t)srcv * 512);
        a0 += b2f(xv.x) * aw; a1 += b2f(xv.y) * aw;
        a2 += b2f(xv.z) * aw; a3 += b2f(xv.w) * aw;
    }
    ushort4 ov;
    ov.x = f2b(a0); ov.y = f2b(a1); ov.z = f2b(a2); ov.w = f2b(a3);
    *(ushort4*)(outb + (size_t)dst * 256 + lane * 4) = ov;
}

// ===================== pooling: chunk-parallel ===========================
__device__ __forceinline__ unsigned fmap(float f) {
    unsigned u = __float_as_uint(f);
    return (u & 0x80000000u) ? ~u : (u | 0x80000000u);
}
__device__ __forceinline__ float funmap(unsigned u) {
    return (u & 0x80000000u) ? __uint_as_float(u & 0x7FFFFFFFu)
                             : __uint_as_float(~u);
}

__global__ void pool_max(const float* __restrict__ a, const int* __restrict__ batch,
                         unsigned* __restrict__ am, float* __restrict__ den,
                         float* __restrict__ num) {
    const int c = threadIdx.x;
    if (blockIdx.x < BB) {                       // folded den/num zeroing
        den[blockIdx.x * HC + c] = 0.f;
        num[blockIdx.x * HC + c] = 0.f;
    }
    const int n0 = blockIdx.x * 64;
    int curb = batch[n0];
    float m = -3.4e38f;
    const int nend = min(n0 + 64, NN);
    for (int n = n0; n < nend; n++) {
        int b = batch[n];
        float v = a[(size_t)n * HC + c];
        if (b != curb) { atomicMax(&am[curb * HC + c], fmap(m)); curb = b; m = v; }
        else           { m = fmaxf(m, v); }
    }
    atomicMax(&am[curb * HC + c], fmap(m));
}
__global__ void pool_sums(const float* __restrict__ a, const __hip_bfloat16* __restrict__ h2,
                          const int* __restrict__ batch, const unsigned* __restrict__ am,
                          float* __restrict__ den, float* __restrict__ num) {
    const int c = threadIdx.x;
    const int n0 = blockIdx.x * 64;
    int curb = batch[n0];
    float sd = 0.f, sn = 0.f;
    float mcur = funmap(am[curb * HC + c]);
    const int nend = min(n0 + 64, NN);
    for (int n = n0; n < nend; n++) {
        int b = batch[n];
        if (b != curb) {
            atomicAdd(&den[curb * HC + c], sd);
            atomicAdd(&num[curb * HC + c], sn);
            curb = b; sd = 0.f; sn = 0.f; mcur = funmap(am[b * HC + c]);
        }
        float w = __expf(a[(size_t)n * HC + c] - mcur);
        sd += w;
        sn += __bfloat162float(h2[(size_t)n * HC + c]) * w;
    }
    atomicAdd(&den[curb * HC + c], sd);
    atomicAdd(&num[curb * HC + c], sn);
}

// ===================== head MLP ==========================================
__global__ void mlp_lin1(const float* __restrict__ num, const float* __restrict__ den,
                         const float* __restrict__ Wo1, const float* __restrict__ bo1,
                         float* __restrict__ y) {
    __shared__ float gsh[HC];
    const int c = threadIdx.x;
    const int r = blockIdx.x;
    gsh[c] = num[r * HC + c] / (den[r * HC + c] + 1e-16f);   // folded pool_div
    __syncthreads();
    float acc = bo1[c];
#pragma unroll 4
    for (int k = 0; k < HC; k++) acc = fmaf(gsh[k], Wo1[k * HC + c], acc);
    y[r * HC + c] = acc;
}
__global__ void bn_relu(float* __restrict__ y, const float* __restrict__ gamma,
                        const float* __restrict__ beta) {
    const int c = threadIdx.x;
    float s = 0.f, sq = 0.f;
    for (int r = 0; r < BB; r++) { float v = y[r * HC + c]; s += v; sq += v * v; }
    float mu  = s * (1.f / BB);
    float var = sq * (1.f / BB) - mu * mu;
    float inv = rsqrtf(var + 1e-5f) * gamma[c];
    float bt  = beta[c];
    for (int r = 0; r < BB; r++) {
        float v = (y[r * HC + c] - mu) * inv + bt;
        y[r * HC + c] = v > 0.f ? v : 0.f;
    }
}
__global__ void mlp_lin2(const float* __restrict__ y, const float* __restrict__ Wo2,
                         const float* __restrict__ bo2, float* __restrict__ out) {
    const int j = blockIdx.x * 256 + threadIdx.x;
    const int r = blockIdx.y;
    if (j >= 2001) return;
    float acc = bo2[j];
#pragma unroll 4
    for (int k = 0; k < HC; k++) acc = fmaf(y[r * HC + k], Wo2[k * 2001 + j], acc);
    out[r * 2001 + j] = acc > 0.f ? acc : 0.01f * acc;
}

// ===================== launcher ==========================================
extern "C" void kernel_launch(void* const* d_in, const int* in_sizes, int n_in,
                              void* d_out, int out_size, void* d_ws, size_t ws_size,
                              hipStream_t stream) {
    const float* x     = (const float*)d_in[0];
    const int*   ei    = (const int*)d_in[1];
    const float* ea    = (const float*)d_in[2];
    const int*   batch = (const int*)d_in[3];
    const float* W0 = (const float*)d_in[4];  const float* b0 = (const float*)d_in[5];
    const float* Wl1 = (const float*)d_in[6]; const float* bl1 = (const float*)d_in[7];
    const float* Wr1 = (const float*)d_in[8]; const float* br1 = (const float*)d_in[9];
    const float* We1 = (const float*)d_in[10]; const float* att1 = (const float*)d_in[11];
    const float* bias1 = (const float*)d_in[12];
    const float* Wl2 = (const float*)d_in[13]; const float* bl2 = (const float*)d_in[14];
    const float* Wr2 = (const float*)d_in[15]; const float* br2 = (const float*)d_in[16];
    const float* We2 = (const float*)d_in[17]; const float* att2 = (const float*)d_in[18];
    const float* bias2 = (const float*)d_in[19];
    const float* Wp = (const float*)d_in[20]; const float* bp = (const float*)d_in[21];
    const float* Wo1 = (const float*)d_in[22]; const float* bo1 = (const float*)d_in[23];
    const float* gamma = (const float*)d_in[24]; const float* beta = (const float*)d_in[25];
    const float* Wo2 = (const float*)d_in[26]; const float* bo2 = (const float*)d_in[27];
    float* out = (float*)d_out;

    // ---- workspace carve-up (256B aligned), ~154 MB ----
    char* p = (char*)d_ws;
    auto alloc = [&](size_t bytes) { char* r = p; p += (bytes + 255) & ~(size_t)255; return r; };
    const int MP = 30016;
    const int ET = 4688;
    __hip_bfloat16* xpad  = (__hip_bfloat16*)alloc((size_t)MP * 32 * 2);
    __hip_bfloat16* W0t   = (__hip_bfloat16*)alloc(128 * 32 * 2);
    __hip_bfloat16* W1t   = (__hip_bfloat16*)alloc(512 * 128 * 2);
    __hip_bfloat16* W2t   = (__hip_bfloat16*)alloc(512 * 256 * 2);
    __hip_bfloat16* Wpt   = (__hip_bfloat16*)alloc(256 * 256 * 2);
    ushort* Wef1 = (ushort*)alloc(256 * 64 * 2);
    ushort* Wef2 = (ushort*)alloc(256 * 64 * 2);
    float* bcat1 = (float*)alloc(512 * 4);
    float* bcat2 = (float*)alloc(512 * 4);
    __hip_bfloat16* h0b  = (__hip_bfloat16*)alloc((size_t)MP * 128 * 2);
    __hip_bfloat16* xlrb = (__hip_bfloat16*)alloc((size_t)MP * 512 * 2);
    __hip_bfloat16* h1b  = (__hip_bfloat16*)alloc((size_t)MP * 256 * 2);
    __hip_bfloat16* h2b  = (__hip_bfloat16*)alloc((size_t)MP * 256 * 2);
    ushort* ea_frag = (ushort*)alloc((size_t)ET * 4096 * 2);
    float* abuf = (float*)alloc((size_t)MP * 256 * 4);
    float* logit = (float*)alloc((size_t)EE * 4 * 4);
    int* deg    = (int*)alloc(NN * 4);
    int* cursor = (int*)alloc(NN * 4);
    int* partial= (int*)alloc(NN * 4);
    int* bsum   = (int*)alloc(256 * 4);
    int* start  = (int*)alloc((NN + 4) * 4);
    int* eidx   = (int*)alloc((size_t)EE * 4);
    int* src_csr= (int*)alloc((size_t)EE * 4);
    int* dst_csr= (int*)alloc((size_t)EE * 4);
    unsigned* am = (unsigned*)alloc(BB * HC * 4);
    float* den  = (float*)alloc(BB * HC * 4);
    float* num  = (float*)alloc(BB * HC * 4);
    float* ybuf = (float*)alloc(BB * HC * 4);

    const int NB = (NN + 255) / 256;

    // ---- input / weight packing (pack_x also zeroes deg) ----
    pack_x<<<(NN * 32 + 255) / 256, 256, 0, stream>>>(x, xpad, deg);
    PackJobs pj;
    pj.j[0] = {W0,  W0t, 13, 128, 32, 0};
    pj.j[1] = {Wl1, W1t, 128, 256, 128, 0};
    pj.j[2] = {Wr1, W1t, 128, 256, 128, 256};
    pj.j[3] = {Wl2, W2t, 256, 256, 256, 0};
    pj.j[4] = {Wr2, W2t, 256, 256, 256, 256};
    pj.j[5] = {Wp,  Wpt, 256, 256, 256, 0};
    pack_all<<<dim3(64, 6), 256, 0, stream>>>(pj);
    pack_we_frag<<<dim3(64, 2), 256, 0, stream>>>(We1, We2, Wef1, Wef2);
    cat2<<<2, 256, 0, stream>>>(bl1, br1, bcat1);
    cat2<<<2, 256, 0, stream>>>(bl2, br2, bcat2);

    // ---- CSR build ----
    hist_deg<<<(EE + 255) / 256, 256, 0, stream>>>(ei, deg);
    scan1<<<NB, 256, 0, stream>>>(deg, partial, bsum);
    scan2<<<1, 256, 0, stream>>>(bsum, NB);
    scan3<<<NB + 1, 256, 0, stream>>>(partial, bsum, start, cursor);
    scatter_e<<<(EE + 255) / 256, 256, 0, stream>>>(ei, cursor, start, eidx, src_csr, dst_csr);
    permute_ea_frag<<<ET, 256, 0, stream>>>(ea, eidx, ea_frag);

    // ---- init transform ----
    mfma_gemm<2><<<dim3(469, 1), 256, 0, stream>>>(
        (const ushort*)xpad, (const ushort*)W0t, b0, nullptr, h0b, NN, 128, 32);

    // ---- GAT layer 1 ----
    mfma_gemm<4><<<dim3(469, 2), 256, 0, stream>>>(
        (const ushort*)h0b, (const ushort*)W1t, bcat1, nullptr, xlrb, NN, 512, 128);
    edge_fused<<<ET, 256, 0, stream>>>(ea_frag, Wef1, att1, src_csr, dst_csr,
                                       (const ushort*)xlrb, logit);
    aggregate_csr<<<(NN + 3) / 4, 256, 0, stream>>>(
        (const ushort*)xlrb, logit, src_csr, start, bias1, (ushort*)h1b);

    // ---- GAT layer 2 ----
    mfma_gemm<4><<<dim3(469, 2), 256, 0, stream>>>(
        (const ushort*)h1b, (const ushort*)W2t, bcat2, nullptr, xlrb, NN, 512, 256);
    edge_fused<<<ET, 256, 0, stream>>>(ea_frag, Wef2, att2, src_csr, dst_csr,
                                       (const ushort*)xlrb, logit);
    aggregate_csr<<<(NN + 3) / 4, 256, 0, stream>>>(
        (const ushort*)xlrb, logit, src_csr, start, bias2, (ushort*)h2b);

    // ---- attention pooling (chunk-parallel) ----
    mfma_gemm<4><<<dim3(469, 1), 256, 0, stream>>>(
        (const ushort*)h2b, (const ushort*)Wpt, bp, abuf, nullptr, NN, 256, 256);
    hipMemsetAsync(am, 0, BB * HC * 4, stream);
    const int poolGrid = (NN + 63) / 64;
    pool_max<<<poolGrid, HC, 0, stream>>>(abuf, batch, am, den, num);
    pool_sums<<<poolGrid, HC, 0, stream>>>(abuf, h2b, batch, am, den, num);

    // ---- head MLP ----
    mlp_lin1<<<BB, HC, 0, stream>>>(num, den, Wo1, bo1, ybuf);
    bn_relu<<<1, HC, 0, stream>>>(ybuf, gamma, beta);
    mlp_lin2<<<dim3(8, BB), 256, 0, stream>>>(ybuf, Wo2, bo2, out);
}

// Round 9
// 598.442 us; speedup vs baseline: 3.1900x; 1.0481x over previous
//
#include <hip/hip_runtime.h>
#include <hip/hip_bf16.h>

#define NN 30000
#define EE 300000
#define BB 64
#define HH 4
#define CC 64
#define HC 256

typedef __attribute__((ext_vector_type(8))) short short8;
typedef __attribute__((ext_vector_type(4))) float floatx4;

__device__ __forceinline__ float b2f(short x) {
    return __uint_as_float(((unsigned)(unsigned short)x) << 16);
}
__device__ __forceinline__ unsigned short f2b(float f) {
    __hip_bfloat16 h = __float2bfloat16(f);
    return *(unsigned short*)&h;
}

#define GLD16(gp, lp) __builtin_amdgcn_global_load_lds( \
    (const __attribute__((address_space(1))) void*)(gp), \
    (__attribute__((address_space(3))) void*)(lp), 16, 0, 0)

// 5-bit rotate-left-by-2
#define ROT2(x) ((((x) << 2) | ((x) >> 3)) & 31)
// eeS swizzle: 3-bit spread
#define EESWZ(chunk, row) (ROT2(chunk) ^ (((row) >> 2) & 3) ^ (((row) & 1) << 2))

// ===================== bf16 MFMA GEMM (dense transforms) =================
// bf16-output path uses an LDS-staged coalesced epilogue (b128 stores).
template<int CT>
__global__ __launch_bounds__(256) void mfma_gemm(
    const ushort* __restrict__ A, const ushort* __restrict__ Bt,
    const float* __restrict__ bias, float* __restrict__ outF,
    __hip_bfloat16* __restrict__ outB, int M, int Nc, int K) {
    constexpr int SMEM_USHORTS =
        ((64 * 32 + CT * 64 * 32) > (64 * CT * 64)) ? (64 * 32 + CT * 64 * 32)
                                                    : (64 * CT * 64);
    __shared__ __align__(16) ushort smem[SMEM_USHORTS];
    ushort* lA = smem;
    ushort* lB = smem + 64 * 32;
    const int tid = threadIdx.x, lane = tid & 63, wv = tid >> 6;
    const int row0 = blockIdx.x * 64, col0 = blockIdx.y * (CT * 64);

    floatx4 acc[4][CT];
#pragma unroll
    for (int r = 0; r < 4; r++)
#pragma unroll
        for (int c = 0; c < CT; c++) acc[r][c] = (floatx4){0.f, 0.f, 0.f, 0.f};

    const int arow = tid >> 2;
    const int sl   = (tid & 3) ^ ((tid >> 3) & 3);
    const ushort* ga = A + (size_t)(row0 + arow) * K + sl * 8;
    const int m16 = lane & 15, q = lane >> 4;

    for (int k0 = 0; k0 < K; k0 += 32) {
        __syncthreads();
        GLD16(ga + k0, &lA[tid * 8]);
#pragma unroll
        for (int j = 0; j < CT; j++) {
            const ushort* gb = Bt + (size_t)(col0 + j * 64 + arow) * K + k0 + sl * 8;
            GLD16(gb, &lB[j * 2048 + tid * 8]);
        }
        __syncthreads();
        short8 aF[4], bF[CT];
#pragma unroll
        for (int r = 0; r < 4; r++) {
            int rr = r * 16 + m16;
            aF[r] = *(const short8*)&lA[rr * 32 + ((q ^ ((rr >> 1) & 3)) << 3)];
        }
#pragma unroll
        for (int c = 0; c < CT; c++) {
            int nr = (wv * CT + c) * 16 + m16;
            bF[c] = *(const short8*)&lB[nr * 32 + ((q ^ ((nr >> 1) & 3)) << 3)];
        }
#pragma unroll
        for (int r = 0; r < 4; r++)
#pragma unroll
            for (int c = 0; c < CT; c++)
                acc[r][c] = __builtin_amdgcn_mfma_f32_16x16x32_bf16(aF[r], bF[c], acc[r][c], 0, 0, 0);
    }

    if (outB != nullptr) {
        // ---- LDS-staged coalesced bf16 epilogue ----
        __syncthreads();   // all waves done with lA/lB before reuse
#pragma unroll
        for (int c = 0; c < CT; c++) {
            int lcol = (wv * CT + c) * 16 + m16;
            float bv = bias ? bias[col0 + lcol] : 0.f;
            int ch = lcol >> 3, c7 = lcol & 7;
#pragma unroll
            for (int r = 0; r < 4; r++)
#pragma unroll
                for (int j = 0; j < 4; j++) {
                    int row = r * 16 + q * 4 + j;
                    smem[row * (CT * 64) + ((ch ^ (row & 7)) << 3) + c7] =
                        f2b(acc[r][c][j] + bv);
                }
        }
        __syncthreads();
        constexpr int SH = (CT == 4) ? 5 : 4;    // log2(chunks per row)
#pragma unroll
        for (int s = 0; s < CT * 2; s++) {
            int g = tid + 256 * s;
            int row = g >> SH, ch = g & (CT * 8 - 1);
            int grow = row0 + row;
            if (grow < M) {
                short8 v = *(const short8*)&smem[row * (CT * 64) + ((ch ^ (row & 7)) << 3)];
                *(short8*)((ushort*)outB + (size_t)grow * Nc + col0 + ch * 8) = v;
            }
        }
    } else {
        // ---- fp32 scalar epilogue (pool GEMM only) ----
#pragma unroll
        for (int c = 0; c < CT; c++) {
            int col = col0 + (wv * CT + c) * 16 + m16;
            float bv = bias ? bias[col] : 0.f;
#pragma unroll
            for (int r = 0; r < 4; r++)
#pragma unroll
                for (int j = 0; j < 4; j++) {
                    int row = row0 + r * 16 + q * 4 + j;
                    if (row < M) outF[(size_t)row * Nc + col] = acc[r][c][j] + bv;
                }
        }
    }
}

// ===================== ea -> A-fragment-order bf16 (CSR tiles) ===========
// chunk 7 (k=56..63) is pure zero padding -> never written, never read.
__global__ void permute_ea_frag(const float* __restrict__ ea,
                                const int* __restrict__ eidx,
                                ushort* __restrict__ ea_frag) {
    const int t = threadIdx.x, tile = blockIdx.x;
    const int r  = t >> 6;
    const int ch = (t >> 3) & 7;
    if (ch == 7) return;
    const int m0 = (t * 2) & 15;
    ushort* outp = ea_frag + (size_t)tile * 4096 + t * 16;
#pragma unroll
    for (int half = 0; half < 2; half++) {
        int row = r * 16 + m0 + half;
        int gi = tile * 64 + row;
        int e = (gi < EE) ? eidx[gi] : -1;
        short8 v8;
#pragma unroll
        for (int j = 0; j < 8; j++) {
            int k = ch * 8 + j;
            float v = (e >= 0 && k < 51) ? ea[(size_t)e * 51 + k] : 0.f;
            v8[j] = (short)f2b(v);
        }
        *(short8*)(outp + half * 8) = v8;
    }
}

// ===================== We -> B-fragment-order bf16 =======================
__global__ void pack_we_frag(const float* __restrict__ WeA,
                             const float* __restrict__ WeB,
                             ushort* __restrict__ WfA, ushort* __restrict__ WfB) {
    const float* We = blockIdx.y ? WeB : WeA;
    ushort* Wf = blockIdx.y ? WfB : WfA;
    int o = blockIdx.x * 256 + threadIdx.x;
    int j = o & 7, m16 = (o >> 3) & 15, ch = (o >> 7) & 7, nt = o >> 10;
    int n = nt * 16 + m16, k = ch * 8 + j;
    float v = (k < 51) ? We[k * 256 + n] : 0.f;
    Wf[o] = f2b(v);
}

// ===================== fused ee-MFMA + edge logit (one barrier) ==========
// XCD-swizzled tiles: consecutive CSR ranges stay on one XCD's L2.
__global__ __launch_bounds__(256, 4) void edge_fused(
    const ushort* __restrict__ ea_frag, const ushort* __restrict__ Wfrag,
    const float* __restrict__ att,
    const int* __restrict__ src_csr, const int* __restrict__ dst_csr,
    const ushort* __restrict__ xlr, float* __restrict__ logitp) {
    __shared__ __align__(16) ushort eeS[64 * 256];   // 32 KB
    __shared__ float satt[256];
    const int tid = threadIdx.x, lane = tid & 63, wv = tid >> 6;
    const int tile = ((int)blockIdx.x & 7) * 586 + ((int)blockIdx.x >> 3); // 4688=8*586
    const int i0 = tile * 64;
    satt[tid] = att[tid];
    const int m16 = lane & 15, q = lane >> 4;

    floatx4 acc[4][4];
#pragma unroll
    for (int r = 0; r < 4; r++)
#pragma unroll
        for (int c = 0; c < 4; c++) acc[r][c] = (floatx4){0.f, 0.f, 0.f, 0.f};

    short8 zz;
#pragma unroll
    for (int z = 0; z < 8; z++) zz[z] = 0;

    const ushort* af = ea_frag + (size_t)tile * 4096;
#pragma unroll
    for (int k0 = 0; k0 < 2; k0++) {
        short8 aF[4], bF[4];
        const bool live = !(k0 == 1 && q == 3);   // chunk 7 is all zeros
        if (live) {
#pragma unroll
            for (int r = 0; r < 4; r++)
                aF[r] = *(const short8*)&af[((r * 8 + k0 * 4 + q) * 16 + m16) * 8];
#pragma unroll
            for (int c = 0; c < 4; c++)
                bF[c] = *(const short8*)&Wfrag[(((wv * 4 + c) * 8 + k0 * 4 + q) * 16 + m16) * 8];
        } else {
#pragma unroll
            for (int r = 0; r < 4; r++) aF[r] = zz;
#pragma unroll
            for (int c = 0; c < 4; c++) bF[c] = zz;
        }
#pragma unroll
        for (int r = 0; r < 4; r++)
#pragma unroll
            for (int c = 0; c < 4; c++)
                acc[r][c] = __builtin_amdgcn_mfma_f32_16x16x32_bf16(aF[r], bF[c], acc[r][c], 0, 0, 0);
    }

    // park ee tile with 3-bit swizzle
#pragma unroll
    for (int r = 0; r < 4; r++)
#pragma unroll
        for (int cc = 0; cc < 4; cc++)
#pragma unroll
            for (int j = 0; j < 4; j++) {
                int row = r * 16 + q * 4 + j;
                int col = (wv * 4 + cc) * 16 + m16;
                int chunk = col >> 3;
                int P = EESWZ(chunk, row);
                eeS[row * 256 + (P << 3) + (col & 7)] = f2b(acc[r][cc][j]);
            }
    __syncthreads();

    // logit: thread = (CSR position el, head h)
    const int el = tid >> 2, h = tid & 3;
    const int i = i0 + el;
    if (i < EE) {
        int src = src_csr[i], dstn = dst_csr[i];
        const ushort* xlp = xlr + (size_t)src * 512 + h * 64;
        const ushort* xrp = xlr + (size_t)dstn * 512 + 256 + h * 64;
        float s = 0.f;
#pragma unroll
        for (int c = 0; c < 8; c++) {
            short8 xlv = *(const short8*)(xlp + c * 8);
            short8 xrv = *(const short8*)(xrp + c * 8);
            int chunk = h * 8 + c;
            int P = EESWZ(chunk, el);
            short8 eev = *(const short8*)&eeS[el * 256 + (P << 3)];
#pragma unroll
            for (int j = 0; j < 8; j++) {
                float v = b2f(xlv[j]) + b2f(xrv[j]) + b2f(eev[j]);
                v = v > 0.f ? v : 0.2f * v;
                s += v * satt[h * 64 + c * 8 + j];
            }
        }
        logitp[(size_t)i * 4 + h] = s;
    }
}

// ===================== packing ===========================================
__global__ void pack_x(const float* __restrict__ x, __hip_bfloat16* __restrict__ d,
                       int* __restrict__ deg) {
    int i = blockIdx.x * 256 + threadIdx.x;
    if (i < NN) deg[i] = 0;
    if (i >= NN * 32) return;
    int n = i >> 5, k = i & 31;
    d[i] = __float2bfloat16(k < 13 ? x[n * 13 + k] : 0.f);
}
struct PackJob { const float* W; __hip_bfloat16* dst; int K, Nc, Kpad, rowoff; };
struct PackJobs { PackJob j[6]; };
__global__ void pack_all(PackJobs jobs) {
    PackJob jb = jobs.j[blockIdx.y];
    int tot = jb.Nc * jb.Kpad;
    for (int i = blockIdx.x * 256 + threadIdx.x; i < tot; i += gridDim.x * 256) {
        int n = i / jb.Kpad, k = i - n * jb.Kpad;
        float v = (k < jb.K) ? jb.W[k * jb.Nc + n] : 0.f;
        jb.dst[(size_t)(jb.rowoff + n) * jb.Kpad + k] = __float2bfloat16(v);
    }
}
__global__ void cat2(const float* __restrict__ a, const float* __restrict__ b,
                     float* __restrict__ o) {
    int i = blockIdx.x * 256 + threadIdx.x;
    if (i < 512) o[i] = i < 256 ? a[i] : b[i - 256];
}

// ===================== CSR build =========================================
__global__ void hist_deg(const int* __restrict__ ei, int* __restrict__ deg) {
    int e = blockIdx.x * 256 + threadIdx.x;
    if (e < EE) atomicAdd(&deg[ei[EE + e]], 1);
}
__global__ void scan1(const int* __restrict__ deg, int* __restrict__ partial,
                      int* __restrict__ bsum) {
    __shared__ int sh[256];
    int t = threadIdx.x, i = blockIdx.x * 256 + t;
    int v = (i < NN) ? deg[i] : 0;
    sh[t] = v; __syncthreads();
    for (int off = 1; off < 256; off <<= 1) {
        int x = (t >= off) ? sh[t - off] : 0;
        __syncthreads();
        sh[t] += x;
        __syncthreads();
    }
    if (i < NN) partial[i] = sh[t] - v;
    if (t == 255) bsum[blockIdx.x] = sh[255];
}
__global__ void scan2(int* __restrict__ bsum, int nb) {
    __shared__ int sh[256];
    int t = threadIdx.x;
    int v = (t < nb) ? bsum[t] : 0;
    sh[t] = v; __syncthreads();
    for (int off = 1; off < 256; off <<= 1) {
        int x = (t >= off) ? sh[t - off] : 0;
        __syncthreads();
        sh[t] += x;
        __syncthreads();
    }
    if (t < nb) bsum[t] = sh[t] - v;
}
__global__ void scan3(const int* __restrict__ partial, const int* __restrict__ bsum,
                      int* __restrict__ start, int* __restrict__ cursor) {
    int i = blockIdx.x * 256 + threadIdx.x;
    if (i < NN) { start[i] = partial[i] + bsum[i >> 8]; cursor[i] = 0; }
    else if (i == NN) start[NN] = EE;
}
__global__ void scatter_e(const int* __restrict__ ei, int* __restrict__ cursor,
                          const int* __restrict__ start, int* __restrict__ eidx,
                          int* __restrict__ src_csr, int* __restrict__ dst_csr) {
    int e = blockIdx.x * 256 + threadIdx.x;
    if (e >= EE) return;
    int s = ei[e];
    int d = ei[EE + e];
    int p = atomicAdd(&cursor[d], 1);
    int pos = start[d] + p;
    eidx[pos] = e;
    src_csr[pos] = s;
    dst_csr[pos] = d;
}

// ===================== fused segment softmax + aggregate =================
__global__ __launch_bounds__(256) void aggregate_csr(
    const ushort* __restrict__ xlr, const float* __restrict__ logitp,
    const int* __restrict__ src_csr, const int* __restrict__ start,
    const float* __restrict__ bias, ushort* __restrict__ outb) {
    const int lane = threadIdx.x & 63, wv = threadIdx.x >> 6;
    const int dst = blockIdx.x * 4 + wv;
    if (dst >= NN) return;
    const int s0 = start[dst];
    const int deg = start[dst + 1] - s0;
    const int h = lane >> 4;

    float m[4] = {-3.4e38f, -3.4e38f, -3.4e38f, -3.4e38f};
    float lg[4] = {0.f, 0.f, 0.f, 0.f};
    int mysrc = 0;
    if (lane < deg) {
        mysrc = src_csr[s0 + lane];
        float4 l4 = ((const float4*)logitp)[s0 + lane];
        lg[0] = l4.x; lg[1] = l4.y; lg[2] = l4.z; lg[3] = l4.w;
        m[0] = l4.x; m[1] = l4.y; m[2] = l4.z; m[3] = l4.w;
    }
    for (int i = 64 + lane; i < deg; i += 64) {
        float4 l4 = ((const float4*)logitp)[s0 + i];
        m[0] = fmaxf(m[0], l4.x); m[1] = fmaxf(m[1], l4.y);
        m[2] = fmaxf(m[2], l4.z); m[3] = fmaxf(m[3], l4.w);
    }
#pragma unroll
    for (int off = 32; off; off >>= 1)
#pragma unroll
        for (int k = 0; k < 4; k++) m[k] = fmaxf(m[k], __shfl_xor(m[k], off));

    float w[4], d[4];
#pragma unroll
    for (int k = 0; k < 4; k++) {
        w[k] = (lane < deg) ? __expf(lg[k] - m[k]) : 0.f;
        d[k] = w[k];
    }
    for (int i = 64 + lane; i < deg; i += 64) {
        float4 l4 = ((const float4*)logitp)[s0 + i];
        d[0] += __expf(l4.x - m[0]); d[1] += __expf(l4.y - m[1]);
        d[2] += __expf(l4.z - m[2]); d[3] += __expf(l4.w - m[3]);
    }
#pragma unroll
    for (int off = 32; off; off >>= 1)
#pragma unroll
        for (int k = 0; k < 4; k++) d[k] += __shfl_xor(d[k], off);
    const float dh = 1.f / (((h == 0) ? d[0] : (h == 1) ? d[1] : (h == 2) ? d[2] : d[3]) + 1e-16f);
    const float mh = (h == 0) ? m[0] : (h == 1) ? m[1] : (h == 2) ? m[2] : m[3];

    float4 b4 = ((const float4*)bias)[lane];
    float a0 = b4.x, a1 = b4.y, a2 = b4.z, a3 = b4.w;

    const int dcap = deg < 64 ? deg : 64;
    const ushort* xbase = xlr + (size_t)lane * 4;
    int i = 0;
    for (; i + 4 <= dcap; i += 4) {
        int sv[4]; float aw[4];
#pragma unroll
        for (int u = 0; u < 4; u++) {
            sv[u] = __shfl(mysrc, i + u);
            float s0v = __shfl(w[0], i + u), s1v = __shfl(w[1], i + u);
            float s2v = __shfl(w[2], i + u), s3v = __shfl(w[3], i + u);
            aw[u] = ((h == 0) ? s0v : (h == 1) ? s1v : (h == 2) ? s2v : s3v) * dh;
        }
        ushort4 xv[4];
#pragma unroll
        for (int u = 0; u < 4; u++)
            xv[u] = *(const ushort4*)(xbase + (size_t)sv[u] * 512);
#pragma unroll
        for (int u = 0; u < 4; u++) {
            a0 += b2f(xv[u].x) * aw[u]; a1 += b2f(xv[u].y) * aw[u];
            a2 += b2f(xv[u].z) * aw[u]; a3 += b2f(xv[u].w) * aw[u];
        }
    }
    for (; i < dcap; i++) {
        int srcv = __shfl(mysrc, i);
        float s0v = __shfl(w[0], i), s1v = __shfl(w[1], i);
        float s2v = __shfl(w[2], i), s3v = __shfl(w[3], i);
        float aw = ((h == 0) ? s0v : (h == 1) ? s1v : (h == 2) ? s2v : s3v) * dh;
        ushort4 xv = *(const ushort4*)(xbase + (size_t)srcv * 512);
        a0 += b2f(xv.x) * aw; a1 += b2f(xv.y) * aw;
        a2 += b2f(xv.z) * aw; a3 += b2f(xv.w) * aw;
    }
    for (int ii = 64; ii < deg; ii++) {
        int srcv = src_csr[s0 + ii];
        float4 l4 = ((const float4*)logitp)[s0 + ii];
        float lh = (h == 0) ? l4.x : (h == 1) ? l4.y : (h == 2) ? l4.z : l4.w;
        float aw = __expf(lh - mh) * dh;
        ushort4 xv = *(const ushort4*)(xbase + (size_t)srcv * 512);
        a0 += b2f(xv.x) * aw; a1 += b2f(xv.y) * aw;
        a2 += b2f(xv.z) * aw; a3 += b2f(xv.w) * aw;
    }
    ushort4 ov;
    ov.x = f2b(a0); ov.y = f2b(a1); ov.z = f2b(a2); ov.w = f2b(a3);
    *(ushort4*)(outb + (size_t)dst * 256 + lane * 4) = ov;
}

// ===================== pooling: chunk-parallel ===========================
__device__ __forceinline__ unsigned fmap(float f) {
    unsigned u = __float_as_uint(f);
    return (u & 0x80000000u) ? ~u : (u | 0x80000000u);
}
__device__ __forceinline__ float funmap(unsigned u) {
    return (u & 0x80000000u) ? __uint_as_float(u & 0x7FFFFFFFu)
                             : __uint_as_float(~u);
}

__global__ void pool_max(const float* __restrict__ a, const int* __restrict__ batch,
                         unsigned* __restrict__ am, float* __restrict__ den,
                         float* __restrict__ num) {
    const int c = threadIdx.x;
    if (blockIdx.x < BB) {
        den[blockIdx.x * HC + c] = 0.f;
        num[blockIdx.x * HC + c] = 0.f;
    }
    const int n0 = blockIdx.x * 64;
    int curb = batch[n0];
    float m = -3.4e38f;
    const int nend = min(n0 + 64, NN);
    for (int n = n0; n < nend; n++) {
        int b = batch[n];
        float v = a[(size_t)n * HC + c];
        if (b != curb) { atomicMax(&am[curb * HC + c], fmap(m)); curb = b; m = v; }
        else           { m = fmaxf(m, v); }
    }
    atomicMax(&am[curb * HC + c], fmap(m));
}
__global__ void pool_sums(const float* __restrict__ a, const __hip_bfloat16* __restrict__ h2,
                          const int* __restrict__ batch, const unsigned* __restrict__ am,
                          float* __restrict__ den, float* __restrict__ num) {
    const int c = threadIdx.x;
    const int n0 = blockIdx.x * 64;
    int curb = batch[n0];
    float sd = 0.f, sn = 0.f;
    float mcur = funmap(am[curb * HC + c]);
    const int nend = min(n0 + 64, NN);
    for (int n = n0; n < nend; n++) {
        int b = batch[n];
        if (b != curb) {
            atomicAdd(&den[curb * HC + c], sd);
            atomicAdd(&num[curb * HC + c], sn);
            curb = b; sd = 0.f; sn = 0.f; mcur = funmap(am[b * HC + c]);
        }
        float w = __expf(a[(size_t)n * HC + c] - mcur);
        sd += w;
        sn += __bfloat162float(h2[(size_t)n * HC + c]) * w;
    }
    atomicAdd(&den[curb * HC + c], sd);
    atomicAdd(&num[curb * HC + c], sn);
}

// ===================== head MLP ==========================================
__global__ void mlp_lin1(const float* __restrict__ num, const float* __restrict__ den,
                         const float* __restrict__ Wo1, const float* __restrict__ bo1,
                         float* __restrict__ y) {
    __shared__ float gsh[HC];
    const int c = threadIdx.x;
    const int r = blockIdx.x;
    gsh[c] = num[r * HC + c] / (den[r * HC + c] + 1e-16f);
    __syncthreads();
    float acc = bo1[c];
#pragma unroll 4
    for (int k = 0; k < HC; k++) acc = fmaf(gsh[k], Wo1[k * HC + c], acc);
    y[r * HC + c] = acc;
}
__global__ void bn_relu(float* __restrict__ y, const float* __restrict__ gamma,
                        const float* __restrict__ beta) {
    const int c = threadIdx.x;
    float s = 0.f, sq = 0.f;
    for (int r = 0; r < BB; r++) { float v = y[r * HC + c]; s += v; sq += v * v; }
    float mu  = s * (1.f / BB);
    float var = sq * (1.f / BB) - mu * mu;
    float inv = rsqrtf(var + 1e-5f) * gamma[c];
    float bt  = beta[c];
    for (int r = 0; r < BB; r++) {
        float v = (y[r * HC + c] - mu) * inv + bt;
        y[r * HC + c] = v > 0.f ? v : 0.f;
    }
}
__global__ void mlp_lin2(const float* __restrict__ y, const float* __restrict__ Wo2,
                         const float* __restrict__ bo2, float* __restrict__ out) {
    const int j = blockIdx.x * 256 + threadIdx.x;
    const int r = blockIdx.y;
    if (j >= 2001) return;
    float acc = bo2[j];
#pragma unroll 4
    for (int k = 0; k < HC; k++) acc = fmaf(y[r * HC + k], Wo2[k * 2001 + j], acc);
    out[r * 2001 + j] = acc > 0.f ? acc : 0.01f * acc;
}

// ===================== launcher ==========================================
extern "C" void kernel_launch(void* const* d_in, const int* in_sizes, int n_in,
                              void* d_out, int out_size, void* d_ws, size_t ws_size,
                              hipStream_t stream) {
    const float* x     = (const float*)d_in[0];
    const int*   ei    = (const int*)d_in[1];
    const float* ea    = (const float*)d_in[2];
    const int*   batch = (const int*)d_in[3];
    const float* W0 = (const float*)d_in[4];  const float* b0 = (const float*)d_in[5];
    const float* Wl1 = (const float*)d_in[6]; const float* bl1 = (const float*)d_in[7];
    const float* Wr1 = (const float*)d_in[8]; const float* br1 = (const float*)d_in[9];
    const float* We1 = (const float*)d_in[10]; const float* att1 = (const float*)d_in[11];
    const float* bias1 = (const float*)d_in[12];
    const float* Wl2 = (const float*)d_in[13]; const float* bl2 = (const float*)d_in[14];
    const float* Wr2 = (const float*)d_in[15]; const float* br2 = (const float*)d_in[16];
    const float* We2 = (const float*)d_in[17]; const float* att2 = (const float*)d_in[18];
    const float* bias2 = (const float*)d_in[19];
    const float* Wp = (const float*)d_in[20]; const float* bp = (const float*)d_in[21];
    const float* Wo1 = (const float*)d_in[22]; const float* bo1 = (const float*)d_in[23];
    const float* gamma = (const float*)d_in[24]; const float* beta = (const float*)d_in[25];
    const float* Wo2 = (const float*)d_in[26]; const float* bo2 = (const float*)d_in[27];
    float* out = (float*)d_out;

    char* p = (char*)d_ws;
    auto alloc = [&](size_t bytes) { char* r = p; p += (bytes + 255) & ~(size_t)255; return r; };
    const int MP = 30016;
    const int ET = 4688;
    __hip_bfloat16* xpad  = (__hip_bfloat16*)alloc((size_t)MP * 32 * 2);
    __hip_bfloat16* W0t   = (__hip_bfloat16*)alloc(128 * 32 * 2);
    __hip_bfloat16* W1t   = (__hip_bfloat16*)alloc(512 * 128 * 2);
    __hip_bfloat16* W2t   = (__hip_bfloat16*)alloc(512 * 256 * 2);
    __hip_bfloat16* Wpt   = (__hip_bfloat16*)alloc(256 * 256 * 2);
    ushort* Wef1 = (ushort*)alloc(256 * 64 * 2);
    ushort* Wef2 = (ushort*)alloc(256 * 64 * 2);
    float* bcat1 = (float*)alloc(512 * 4);
    float* bcat2 = (float*)alloc(512 * 4);
    __hip_bfloat16* h0b  = (__hip_bfloat16*)alloc((size_t)MP * 128 * 2);
    __hip_bfloat16* xlrb = (__hip_bfloat16*)alloc((size_t)MP * 512 * 2);
    __hip_bfloat16* h1b  = (__hip_bfloat16*)alloc((size_t)MP * 256 * 2);
    __hip_bfloat16* h2b  = (__hip_bfloat16*)alloc((size_t)MP * 256 * 2);
    ushort* ea_frag = (ushort*)alloc((size_t)ET * 4096 * 2);
    float* abuf = (float*)alloc((size_t)MP * 256 * 4);
    float* logit = (float*)alloc((size_t)EE * 4 * 4);
    int* deg    = (int*)alloc(NN * 4);
    int* cursor = (int*)alloc(NN * 4);
    int* partial= (int*)alloc(NN * 4);
    int* bsum   = (int*)alloc(256 * 4);
    int* start  = (int*)alloc((NN + 4) * 4);
    int* eidx   = (int*)alloc((size_t)EE * 4);
    int* src_csr= (int*)alloc((size_t)EE * 4);
    int* dst_csr= (int*)alloc((size_t)EE * 4);
    unsigned* am = (unsigned*)alloc(BB * HC * 4);
    float* den  = (float*)alloc(BB * HC * 4);
    float* num  = (float*)alloc(BB * HC * 4);
    float* ybuf = (float*)alloc(BB * HC * 4);

    const int NB = (NN + 255) / 256;

    // ---- input / weight packing ----
    pack_x<<<(NN * 32 + 255) / 256, 256, 0, stream>>>(x, xpad, deg);
    PackJobs pj;
    pj.j[0] = {W0,  W0t, 13, 128, 32, 0};
    pj.j[1] = {Wl1, W1t, 128, 256, 128, 0};
    pj.j[2] = {Wr1, W1t, 128, 256, 128, 256};
    pj.j[3] = {Wl2, W2t, 256, 256, 256, 0};
    pj.j[4] = {Wr2, W2t, 256, 256, 256, 256};
    pj.j[5] = {Wp,  Wpt, 256, 256, 256, 0};
    pack_all<<<dim3(64, 6), 256, 0, stream>>>(pj);
    pack_we_frag<<<dim3(64, 2), 256, 0, stream>>>(We1, We2, Wef1, Wef2);
    cat2<<<2, 256, 0, stream>>>(bl1, br1, bcat1);
    cat2<<<2, 256, 0, stream>>>(bl2, br2, bcat2);

    // ---- CSR build ----
    hist_deg<<<(EE + 255) / 256, 256, 0, stream>>>(ei, deg);
    scan1<<<NB, 256, 0, stream>>>(deg, partial, bsum);
    scan2<<<1, 256, 0, stream>>>(bsum, NB);
    scan3<<<NB + 1, 256, 0, stream>>>(partial, bsum, start, cursor);
    scatter_e<<<(EE + 255) / 256, 256, 0, stream>>>(ei, cursor, start, eidx, src_csr, dst_csr);
    permute_ea_frag<<<ET, 256, 0, stream>>>(ea, eidx, ea_frag);

    // ---- init transform ----
    mfma_gemm<2><<<dim3(469, 1), 256, 0, stream>>>(
        (const ushort*)xpad, (const ushort*)W0t, b0, nullptr, h0b, NN, 128, 32);

    // ---- GAT layer 1 ----
    mfma_gemm<4><<<dim3(469, 2), 256, 0, stream>>>(
        (const ushort*)h0b, (const ushort*)W1t, bcat1, nullptr, xlrb, NN, 512, 128);
    edge_fused<<<ET, 256, 0, stream>>>(ea_frag, Wef1, att1, src_csr, dst_csr,
                                       (const ushort*)xlrb, logit);
    aggregate_csr<<<(NN + 3) / 4, 256, 0, stream>>>(
        (const ushort*)xlrb, logit, src_csr, start, bias1, (ushort*)h1b);

    // ---- GAT layer 2 ----
    mfma_gemm<4><<<dim3(469, 2), 256, 0, stream>>>(
        (const ushort*)h1b, (const ushort*)W2t, bcat2, nullptr, xlrb, NN, 512, 256);
    edge_fused<<<ET, 256, 0, stream>>>(ea_frag, Wef2, att2, src_csr, dst_csr,
                                       (const ushort*)xlrb, logit);
    aggregate_csr<<<(NN + 3) / 4, 256, 0, stream>>>(
        (const ushort*)xlrb, logit, src_csr, start, bias2, (ushort*)h2b);

    // ---- attention pooling (chunk-parallel) ----
    mfma_gemm<4><<<dim3(469, 1), 256, 0, stream>>>(
        (const ushort*)h2b, (const ushort*)Wpt, bp, abuf, nullptr, NN, 256, 256);
    hipMemsetAsync(am, 0, BB * HC * 4, stream);
    const int poolGrid = (NN + 63) / 64;
    pool_max<<<poolGrid, HC, 0, stream>>>(abuf, batch, am, den, num);
    pool_sums<<<poolGrid, HC, 0, stream>>>(abuf, h2b, batch, am, den, num);

    // ---- head MLP ----
    mlp_lin1<<<BB, HC, 0, stream>>>(num, den, Wo1, bo1, ybuf);
    bn_relu<<<1, HC, 0, stream>>>(ybuf, gamma, beta);
    mlp_lin2<<<dim3(8, BB), 256, 0, stream>>>(ybuf, Wo2, bo2, out);
}

// Round 10
// 581.019 us; speedup vs baseline: 3.2857x; 1.0300x over previous
//
#include <hip/hip_runtime.h>
#include <hip/hip_bf16.h>

#define NN 30000
#define EE 300000
#define BB 64
#define HH 4
#define CC 64
#define HC 256

typedef __attribute__((ext_vector_type(8))) short short8;
typedef __attribute__((ext_vector_type(4))) float floatx4;

__device__ __forceinline__ float b2f(short x) {
    return __uint_as_float(((unsigned)(unsigned short)x) << 16);
}
__device__ __forceinline__ unsigned short f2b(float f) {
    __hip_bfloat16 h = __float2bfloat16(f);
    return *(unsigned short*)&h;
}

#define GLD16(gp, lp) __builtin_amdgcn_global_load_lds( \
    (const __attribute__((address_space(1))) void*)(gp), \
    (__attribute__((address_space(3))) void*)(lp), 16, 0, 0)

#define ROT2(x) ((((x) << 2) | ((x) >> 3)) & 31)
#define EESWZ(chunk, row) (ROT2(chunk) ^ (((row) >> 2) & 3) ^ (((row) & 1) << 2))

// ===================== bf16 MFMA GEMM (dense transforms) =================
template<int CT>
__global__ __launch_bounds__(256) void mfma_gemm(
    const ushort* __restrict__ A, const ushort* __restrict__ Bt,
    const float* __restrict__ bias, float* __restrict__ outF,
    __hip_bfloat16* __restrict__ outB, int M, int Nc, int K) {
    constexpr int SMEM_USHORTS =
        ((64 * 32 + CT * 64 * 32) > (64 * CT * 64)) ? (64 * 32 + CT * 64 * 32)
                                                    : (64 * CT * 64);
    __shared__ __align__(16) ushort smem[SMEM_USHORTS];
    ushort* lA = smem;
    ushort* lB = smem + 64 * 32;
    const int tid = threadIdx.x, lane = tid & 63, wv = tid >> 6;
    const int row0 = blockIdx.x * 64, col0 = blockIdx.y * (CT * 64);

    floatx4 acc[4][CT];
#pragma unroll
    for (int r = 0; r < 4; r++)
#pragma unroll
        for (int c = 0; c < CT; c++) acc[r][c] = (floatx4){0.f, 0.f, 0.f, 0.f};

    const int arow = tid >> 2;
    const int sl   = (tid & 3) ^ ((tid >> 3) & 3);
    const ushort* ga = A + (size_t)(row0 + arow) * K + sl * 8;
    const int m16 = lane & 15, q = lane >> 4;

    for (int k0 = 0; k0 < K; k0 += 32) {
        __syncthreads();
        GLD16(ga + k0, &lA[tid * 8]);
#pragma unroll
        for (int j = 0; j < CT; j++) {
            const ushort* gb = Bt + (size_t)(col0 + j * 64 + arow) * K + k0 + sl * 8;
            GLD16(gb, &lB[j * 2048 + tid * 8]);
        }
        __syncthreads();
        short8 aF[4], bF[CT];
#pragma unroll
        for (int r = 0; r < 4; r++) {
            int rr = r * 16 + m16;
            aF[r] = *(const short8*)&lA[rr * 32 + ((q ^ ((rr >> 1) & 3)) << 3)];
        }
#pragma unroll
        for (int c = 0; c < CT; c++) {
            int nr = (wv * CT + c) * 16 + m16;
            bF[c] = *(const short8*)&lB[nr * 32 + ((q ^ ((nr >> 1) & 3)) << 3)];
        }
#pragma unroll
        for (int r = 0; r < 4; r++)
#pragma unroll
            for (int c = 0; c < CT; c++)
                acc[r][c] = __builtin_amdgcn_mfma_f32_16x16x32_bf16(aF[r], bF[c], acc[r][c], 0, 0, 0);
    }

    if (outB != nullptr) {
        __syncthreads();
#pragma unroll
        for (int c = 0; c < CT; c++) {
            int lcol = (wv * CT + c) * 16 + m16;
            float bv = bias ? bias[col0 + lcol] : 0.f;
            int ch = lcol >> 3, c7 = lcol & 7;
#pragma unroll
            for (int r = 0; r < 4; r++)
#pragma unroll
                for (int j = 0; j < 4; j++) {
                    int row = r * 16 + q * 4 + j;
                    smem[row * (CT * 64) + ((ch ^ (row & 7)) << 3) + c7] =
                        f2b(acc[r][c][j] + bv);
                }
        }
        __syncthreads();
        constexpr int SH = (CT == 4) ? 5 : 4;
#pragma unroll
        for (int s = 0; s < CT * 2; s++) {
            int g = tid + 256 * s;
            int row = g >> SH, ch = g & (CT * 8 - 1);
            int grow = row0 + row;
            if (grow < M) {
                short8 v = *(const short8*)&smem[row * (CT * 64) + ((ch ^ (row & 7)) << 3)];
                *(short8*)((ushort*)outB + (size_t)grow * Nc + col0 + ch * 8) = v;
            }
        }
    } else {
#pragma unroll
        for (int c = 0; c < CT; c++) {
            int col = col0 + (wv * CT + c) * 16 + m16;
            float bv = bias ? bias[col] : 0.f;
#pragma unroll
            for (int r = 0; r < 4; r++)
#pragma unroll
                for (int j = 0; j < 4; j++) {
                    int row = row0 + r * 16 + q * 4 + j;
                    if (row < M) outF[(size_t)row * Nc + col] = acc[r][c][j] + bv;
                }
        }
    }
}

// ===================== ea -> A-fragment-order bf16 (CSR tiles) ===========
__global__ void permute_ea_frag(const float* __restrict__ ea,
                                const int* __restrict__ eidx,
                                ushort* __restrict__ ea_frag) {
    const int t = threadIdx.x, tile = blockIdx.x;
    const int r  = t >> 6;
    const int ch = (t >> 3) & 7;
    if (ch == 7) return;
    const int m0 = (t * 2) & 15;
    ushort* outp = ea_frag + (size_t)tile * 4096 + t * 16;
#pragma unroll
    for (int half = 0; half < 2; half++) {
        int row = r * 16 + m0 + half;
        int gi = tile * 64 + row;
        int e = (gi < EE) ? eidx[gi] : -1;
        short8 v8;
#pragma unroll
        for (int j = 0; j < 8; j++) {
            int k = ch * 8 + j;
            float v = (e >= 0 && k < 51) ? ea[(size_t)e * 51 + k] : 0.f;
            v8[j] = (short)f2b(v);
        }
        *(short8*)(outp + half * 8) = v8;
    }
}

// ===================== We -> B-fragment-order bf16 =======================
__global__ void pack_we_frag(const float* __restrict__ WeA,
                             const float* __restrict__ WeB,
                             ushort* __restrict__ WfA, ushort* __restrict__ WfB) {
    const float* We = blockIdx.y ? WeB : WeA;
    ushort* Wf = blockIdx.y ? WfB : WfA;
    int o = blockIdx.x * 256 + threadIdx.x;
    int j = o & 7, m16 = (o >> 3) & 15, ch = (o >> 7) & 7, nt = o >> 10;
    int n = nt * 16 + m16, k = ch * 8 + j;
    float v = (k < 51) ? We[k * 256 + n] : 0.f;
    Wf[o] = f2b(v);
}

// ===================== fused ee-MFMA + edge logit ========================
// xl[src] gathers hoisted ABOVE the MFMA phase (latency hidden behind it).
__global__ __launch_bounds__(256, 3) void edge_fused(
    const ushort* __restrict__ ea_frag, const ushort* __restrict__ Wfrag,
    const float* __restrict__ att,
    const int* __restrict__ src_csr, const int* __restrict__ dst_csr,
    const ushort* __restrict__ xlr, float* __restrict__ logitp) {
    __shared__ __align__(16) ushort eeS[64 * 256];   // 32 KB
    __shared__ float satt[256];
    const int tid = threadIdx.x, lane = tid & 63, wv = tid >> 6;
    const int tile = ((int)blockIdx.x & 7) * 586 + ((int)blockIdx.x >> 3);
    const int i0 = tile * 64;
    satt[tid] = att[tid];
    const int m16 = lane & 15, q = lane >> 4;

    // ---- hoisted: edge ids + xl[src] gathers (consumed after barrier) ----
    const int el = tid >> 2, h = tid & 3;
    const int i = i0 + el;
    const bool live_e = (i < EE);
    const int ic = live_e ? i : (EE - 1);
    const int src = src_csr[ic], dstn = dst_csr[ic];
    const ushort* xlp = xlr + (size_t)src * 512 + h * 64;
    short8 xlv[8];
#pragma unroll
    for (int c = 0; c < 8; c++) xlv[c] = *(const short8*)(xlp + c * 8);

    floatx4 acc[4][4];
#pragma unroll
    for (int r = 0; r < 4; r++)
#pragma unroll
        for (int c = 0; c < 4; c++) acc[r][c] = (floatx4){0.f, 0.f, 0.f, 0.f};

    short8 zz;
#pragma unroll
    for (int z = 0; z < 8; z++) zz[z] = 0;

    const ushort* af = ea_frag + (size_t)tile * 4096;
#pragma unroll
    for (int k0 = 0; k0 < 2; k0++) {
        short8 aF[4], bF[4];
        const bool live = !(k0 == 1 && q == 3);
        if (live) {
#pragma unroll
            for (int r = 0; r < 4; r++)
                aF[r] = *(const short8*)&af[((r * 8 + k0 * 4 + q) * 16 + m16) * 8];
#pragma unroll
            for (int c = 0; c < 4; c++)
                bF[c] = *(const short8*)&Wfrag[(((wv * 4 + c) * 8 + k0 * 4 + q) * 16 + m16) * 8];
        } else {
#pragma unroll
            for (int r = 0; r < 4; r++) aF[r] = zz;
#pragma unroll
            for (int c = 0; c < 4; c++) bF[c] = zz;
        }
#pragma unroll
        for (int r = 0; r < 4; r++)
#pragma unroll
            for (int c = 0; c < 4; c++)
                acc[r][c] = __builtin_amdgcn_mfma_f32_16x16x32_bf16(aF[r], bF[c], acc[r][c], 0, 0, 0);
    }

#pragma unroll
    for (int r = 0; r < 4; r++)
#pragma unroll
        for (int cc = 0; cc < 4; cc++)
#pragma unroll
            for (int j = 0; j < 4; j++) {
                int row = r * 16 + q * 4 + j;
                int col = (wv * 4 + cc) * 16 + m16;
                int chunk = col >> 3;
                int P = EESWZ(chunk, row);
                eeS[row * 256 + (P << 3) + (col & 7)] = f2b(acc[r][cc][j]);
            }
    __syncthreads();

    if (live_e) {
        const ushort* xrp = xlr + (size_t)dstn * 512 + 256 + h * 64;
        float s = 0.f;
#pragma unroll
        for (int c = 0; c < 8; c++) {
            short8 xrv = *(const short8*)(xrp + c * 8);
            int chunk = h * 8 + c;
            int P = EESWZ(chunk, el);
            short8 eev = *(const short8*)&eeS[el * 256 + (P << 3)];
#pragma unroll
            for (int j = 0; j < 8; j++) {
                float v = b2f(xlv[c][j]) + b2f(xrv[j]) + b2f(eev[j]);
                v = v > 0.f ? v : 0.2f * v;
                s += v * satt[h * 64 + c * 8 + j];
            }
        }
        logitp[(size_t)i * 4 + h] = s;
    }
}

// ===================== packing ===========================================
__global__ void pack_x(const float* __restrict__ x, __hip_bfloat16* __restrict__ d,
                       int* __restrict__ deg) {
    int i = blockIdx.x * 256 + threadIdx.x;
    if (i < NN) deg[i] = 0;
    if (i >= NN * 32) return;
    int n = i >> 5, k = i & 31;
    d[i] = __float2bfloat16(k < 13 ? x[n * 13 + k] : 0.f);
}
struct PackJob { const float* W; __hip_bfloat16* dst; int K, Nc, Kpad, rowoff; };
struct PackJobs { PackJob j[6]; };
__global__ void pack_all(PackJobs jobs) {
    PackJob jb = jobs.j[blockIdx.y];
    int tot = jb.Nc * jb.Kpad;
    for (int i = blockIdx.x * 256 + threadIdx.x; i < tot; i += gridDim.x * 256) {
        int n = i / jb.Kpad, k = i - n * jb.Kpad;
        float v = (k < jb.K) ? jb.W[k * jb.Nc + n] : 0.f;
        jb.dst[(size_t)(jb.rowoff + n) * jb.Kpad + k] = __float2bfloat16(v);
    }
}
// both bias concats in one dispatch (blockIdx.y selects pair)
__global__ void cat2(const float* __restrict__ a1, const float* __restrict__ b1,
                     float* __restrict__ o1, const float* __restrict__ a2,
                     const float* __restrict__ b2, float* __restrict__ o2) {
    int i = blockIdx.x * 256 + threadIdx.x;
    const float* a = blockIdx.y ? a2 : a1;
    const float* b = blockIdx.y ? b2 : b1;
    float* o = blockIdx.y ? o2 : o1;
    if (i < 512) o[i] = i < 256 ? a[i] : b[i - 256];
}

// ===================== CSR build =========================================
__global__ void hist_deg(const int* __restrict__ ei, int* __restrict__ deg,
                         unsigned* __restrict__ am) {
    int e = blockIdx.x * 256 + threadIdx.x;
    if (e < BB * HC) am[e] = 0u;                 // folded am memset
    if (e < EE) atomicAdd(&deg[ei[EE + e]], 1);
}
__global__ void scan1(const int* __restrict__ deg, int* __restrict__ partial,
                      int* __restrict__ bsum) {
    __shared__ int sh[256];
    int t = threadIdx.x, i = blockIdx.x * 256 + t;
    int v = (i < NN) ? deg[i] : 0;
    sh[t] = v; __syncthreads();
    for (int off = 1; off < 256; off <<= 1) {
        int x = (t >= off) ? sh[t - off] : 0;
        __syncthreads();
        sh[t] += x;
        __syncthreads();
    }
    if (i < NN) partial[i] = sh[t] - v;
    if (t == 255) bsum[blockIdx.x] = sh[255];
}
__global__ void scan2(int* __restrict__ bsum, int nb) {
    __shared__ int sh[256];
    int t = threadIdx.x;
    int v = (t < nb) ? bsum[t] : 0;
    sh[t] = v; __syncthreads();
    for (int off = 1; off < 256; off <<= 1) {
        int x = (t >= off) ? sh[t - off] : 0;
        __syncthreads();
        sh[t] += x;
        __syncthreads();
    }
    if (t < nb) bsum[t] = sh[t] - v;
}
__global__ void scan3(const int* __restrict__ partial, const int* __restrict__ bsum,
                      int* __restrict__ start, int* __restrict__ cursor) {
    int i = blockIdx.x * 256 + threadIdx.x;
    if (i < NN) { start[i] = partial[i] + bsum[i >> 8]; cursor[i] = 0; }
    else if (i == NN) start[NN] = EE;
}
__global__ void scatter_e(const int* __restrict__ ei, int* __restrict__ cursor,
                          const int* __restrict__ start, int* __restrict__ eidx,
                          int* __restrict__ src_csr, int* __restrict__ dst_csr) {
    int e = blockIdx.x * 256 + threadIdx.x;
    if (e >= EE) return;
    int s = ei[e];
    int d = ei[EE + e];
    int p = atomicAdd(&cursor[d], 1);
    int pos = start[d] + p;
    eidx[pos] = e;
    src_csr[pos] = s;
    dst_csr[pos] = d;
}

// ===================== fused segment softmax + aggregate =================
__global__ __launch_bounds__(256) void aggregate_csr(
    const ushort* __restrict__ xlr, const float* __restrict__ logitp,
    const int* __restrict__ src_csr, const int* __restrict__ start,
    const float* __restrict__ bias, ushort* __restrict__ outb) {
    const int lane = threadIdx.x & 63, wv = threadIdx.x >> 6;
    const int dst = blockIdx.x * 4 + wv;
    if (dst >= NN) return;
    const int s0 = start[dst];
    const int deg = start[dst + 1] - s0;
    const int h = lane >> 4;

    float m[4] = {-3.4e38f, -3.4e38f, -3.4e38f, -3.4e38f};
    float lg[4] = {0.f, 0.f, 0.f, 0.f};
    int mysrc = 0;
    if (lane < deg) {
        mysrc = src_csr[s0 + lane];
        float4 l4 = ((const float4*)logitp)[s0 + lane];
        lg[0] = l4.x; lg[1] = l4.y; lg[2] = l4.z; lg[3] = l4.w;
        m[0] = l4.x; m[1] = l4.y; m[2] = l4.z; m[3] = l4.w;
    }
    for (int i = 64 + lane; i < deg; i += 64) {
        float4 l4 = ((const float4*)logitp)[s0 + i];
        m[0] = fmaxf(m[0], l4.x); m[1] = fmaxf(m[1], l4.y);
        m[2] = fmaxf(m[2], l4.z); m[3] = fmaxf(m[3], l4.w);
    }
#pragma unroll
    for (int off = 32; off; off >>= 1)
#pragma unroll
        for (int k = 0; k < 4; k++) m[k] = fmaxf(m[k], __shfl_xor(m[k], off));

    float w[4], d[4];
#pragma unroll
    for (int k = 0; k < 4; k++) {
        w[k] = (lane < deg) ? __expf(lg[k] - m[k]) : 0.f;
        d[k] = w[k];
    }
    for (int i = 64 + lane; i < deg; i += 64) {
        float4 l4 = ((const float4*)logitp)[s0 + i];
        d[0] += __expf(l4.x - m[0]); d[1] += __expf(l4.y - m[1]);
        d[2] += __expf(l4.z - m[2]); d[3] += __expf(l4.w - m[3]);
    }
#pragma unroll
    for (int off = 32; off; off >>= 1)
#pragma unroll
        for (int k = 0; k < 4; k++) d[k] += __shfl_xor(d[k], off);
    const float dh = 1.f / (((h == 0) ? d[0] : (h == 1) ? d[1] : (h == 2) ? d[2] : d[3]) + 1e-16f);
    const float mh = (h == 0) ? m[0] : (h == 1) ? m[1] : (h == 2) ? m[2] : m[3];

    float4 b4 = ((const float4*)bias)[lane];
    float a0 = b4.x, a1 = b4.y, a2 = b4.z, a3 = b4.w;

    const int dcap = deg < 64 ? deg : 64;
    const ushort* xbase = xlr + (size_t)lane * 4;
    int i = 0;
    for (; i + 4 <= dcap; i += 4) {
        int sv[4]; float aw[4];
#pragma unroll
        for (int u = 0; u < 4; u++) {
            sv[u] = __shfl(mysrc, i + u);
            float s0v = __shfl(w[0], i + u), s1v = __shfl(w[1], i + u);
            float s2v = __shfl(w[2], i + u), s3v = __shfl(w[3], i + u);
            aw[u] = ((h == 0) ? s0v : (h == 1) ? s1v : (h == 2) ? s2v : s3v) * dh;
        }
        ushort4 xv[4];
#pragma unroll
        for (int u = 0; u < 4; u++)
            xv[u] = *(const ushort4*)(xbase + (size_t)sv[u] * 512);
#pragma unroll
        for (int u = 0; u < 4; u++) {
            a0 += b2f(xv[u].x) * aw[u]; a1 += b2f(xv[u].y) * aw[u];
            a2 += b2f(xv[u].z) * aw[u]; a3 += b2f(xv[u].w) * aw[u];
        }
    }
    for (; i < dcap; i++) {
        int srcv = __shfl(mysrc, i);
        float s0v = __shfl(w[0], i), s1v = __shfl(w[1], i);
        float s2v = __shfl(w[2], i), s3v = __shfl(w[3], i);
        float aw = ((h == 0) ? s0v : (h == 1) ? s1v : (h == 2) ? s2v : s3v) * dh;
        ushort4 xv = *(const ushort4*)(xbase + (size_t)srcv * 512);
        a0 += b2f(xv.x) * aw; a1 += b2f(xv.y) * aw;
        a2 += b2f(xv.z) * aw; a3 += b2f(xv.w) * aw;
    }
    for (int ii = 64; ii < deg; ii++) {
        int srcv = src_csr[s0 + ii];
        float4 l4 = ((const float4*)logitp)[s0 + ii];
        float lh = (h == 0) ? l4.x : (h == 1) ? l4.y : (h == 2) ? l4.z : l4.w;
        float aw = __expf(lh - mh) * dh;
        ushort4 xv = *(const ushort4*)(xbase + (size_t)srcv * 512);
        a0 += b2f(xv.x) * aw; a1 += b2f(xv.y) * aw;
        a2 += b2f(xv.z) * aw; a3 += b2f(xv.w) * aw;
    }
    ushort4 ov;
    ov.x = f2b(a0); ov.y = f2b(a1); ov.z = f2b(a2); ov.w = f2b(a3);
    *(ushort4*)(outb + (size_t)dst * 256 + lane * 4) = ov;
}

// ===================== pooling: chunk-parallel (bf16 logits) =============
__device__ __forceinline__ unsigned fmap(float f) {
    unsigned u = __float_as_uint(f);
    return (u & 0x80000000u) ? ~u : (u | 0x80000000u);
}
__device__ __forceinline__ float funmap(unsigned u) {
    return (u & 0x80000000u) ? __uint_as_float(u & 0x7FFFFFFFu)
                             : __uint_as_float(~u);
}

__global__ void pool_max(const __hip_bfloat16* __restrict__ a, const int* __restrict__ batch,
                         unsigned* __restrict__ am, float* __restrict__ den,
                         float* __restrict__ num) {
    const int c = threadIdx.x;
    if (blockIdx.x < BB) {
        den[blockIdx.x * HC + c] = 0.f;
        num[blockIdx.x * HC + c] = 0.f;
    }
    const int n0 = blockIdx.x * 64;
    int curb = batch[n0];
    float m = -3.4e38f;
    const int nend = min(n0 + 64, NN);
    for (int n = n0; n < nend; n++) {
        int b = batch[n];
        float v = __bfloat162float(a[(size_t)n * HC + c]);
        if (b != curb) { atomicMax(&am[curb * HC + c], fmap(m)); curb = b; m = v; }
        else           { m = fmaxf(m, v); }
    }
    atomicMax(&am[curb * HC + c], fmap(m));
}
__global__ void pool_sums(const __hip_bfloat16* __restrict__ a,
                          const __hip_bfloat16* __restrict__ h2,
                          const int* __restrict__ batch, const unsigned* __restrict__ am,
                          float* __restrict__ den, float* __restrict__ num) {
    const int c = threadIdx.x;
    const int n0 = blockIdx.x * 64;
    int curb = batch[n0];
    float sd = 0.f, sn = 0.f;
    float mcur = funmap(am[curb * HC + c]);
    const int nend = min(n0 + 64, NN);
    for (int n = n0; n < nend; n++) {
        int b = batch[n];
        if (b != curb) {
            atomicAdd(&den[curb * HC + c], sd);
            atomicAdd(&num[curb * HC + c], sn);
            curb = b; sd = 0.f; sn = 0.f; mcur = funmap(am[b * HC + c]);
        }
        float w = __expf(__bfloat162float(a[(size_t)n * HC + c]) - mcur);
        sd += w;
        sn += __bfloat162float(h2[(size_t)n * HC + c]) * w;
    }
    atomicAdd(&den[curb * HC + c], sd);
    atomicAdd(&num[curb * HC + c], sn);
}

// ===================== head MLP ==========================================
__global__ void mlp_lin1(const float* __restrict__ num, const float* __restrict__ den,
                         const float* __restrict__ Wo1, const float* __restrict__ bo1,
                         float* __restrict__ y) {
    __shared__ float gsh[HC];
    const int c = threadIdx.x;
    const int r = blockIdx.x;
    gsh[c] = num[r * HC + c] / (den[r * HC + c] + 1e-16f);
    __syncthreads();
    float acc = bo1[c];
#pragma unroll 4
    for (int k = 0; k < HC; k++) acc = fmaf(gsh[k], Wo1[k * HC + c], acc);
    y[r * HC + c] = acc;
}
__global__ void bn_relu(float* __restrict__ y, const float* __restrict__ gamma,
                        const float* __restrict__ beta) {
    const int c = threadIdx.x;
    float s = 0.f, sq = 0.f;
    for (int r = 0; r < BB; r++) { float v = y[r * HC + c]; s += v; sq += v * v; }
    float mu  = s * (1.f / BB);
    float var = sq * (1.f / BB) - mu * mu;
    float inv = rsqrtf(var + 1e-5f) * gamma[c];
    float bt  = beta[c];
    for (int r = 0; r < BB; r++) {
        float v = (y[r * HC + c] - mu) * inv + bt;
        y[r * HC + c] = v > 0.f ? v : 0.f;
    }
}
__global__ void mlp_lin2(const float* __restrict__ y, const float* __restrict__ Wo2,
                         const float* __restrict__ bo2, float* __restrict__ out) {
    const int j = blockIdx.x * 256 + threadIdx.x;
    const int r = blockIdx.y;
    if (j >= 2001) return;
    float acc = bo2[j];
#pragma unroll 4
    for (int k = 0; k < HC; k++) acc = fmaf(y[r * HC + k], Wo2[k * 2001 + j], acc);
    out[r * 2001 + j] = acc > 0.f ? acc : 0.01f * acc;
}

// ===================== launcher ==========================================
extern "C" void kernel_launch(void* const* d_in, const int* in_sizes, int n_in,
                              void* d_out, int out_size, void* d_ws, size_t ws_size,
                              hipStream_t stream) {
    const float* x     = (const float*)d_in[0];
    const int*   ei    = (const int*)d_in[1];
    const float* ea    = (const float*)d_in[2];
    const int*   batch = (const int*)d_in[3];
    const float* W0 = (const float*)d_in[4];  const float* b0 = (const float*)d_in[5];
    const float* Wl1 = (const float*)d_in[6]; const float* bl1 = (const float*)d_in[7];
    const float* Wr1 = (const float*)d_in[8]; const float* br1 = (const float*)d_in[9];
    const float* We1 = (const float*)d_in[10]; const float* att1 = (const float*)d_in[11];
    const float* bias1 = (const float*)d_in[12];
    const float* Wl2 = (const float*)d_in[13]; const float* bl2 = (const float*)d_in[14];
    const float* Wr2 = (const float*)d_in[15]; const float* br2 = (const float*)d_in[16];
    const float* We2 = (const float*)d_in[17]; const float* att2 = (const float*)d_in[18];
    const float* bias2 = (const float*)d_in[19];
    const float* Wp = (const float*)d_in[20]; const float* bp = (const float*)d_in[21];
    const float* Wo1 = (const float*)d_in[22]; const float* bo1 = (const float*)d_in[23];
    const float* gamma = (const float*)d_in[24]; const float* beta = (const float*)d_in[25];
    const float* Wo2 = (const float*)d_in[26]; const float* bo2 = (const float*)d_in[27];
    float* out = (float*)d_out;

    char* p = (char*)d_ws;
    auto alloc = [&](size_t bytes) { char* r = p; p += (bytes + 255) & ~(size_t)255; return r; };
    const int MP = 30016;
    const int ET = 4688;
    __hip_bfloat16* xpad  = (__hip_bfloat16*)alloc((size_t)MP * 32 * 2);
    __hip_bfloat16* W0t   = (__hip_bfloat16*)alloc(128 * 32 * 2);
    __hip_bfloat16* W1t   = (__hip_bfloat16*)alloc(512 * 128 * 2);
    __hip_bfloat16* W2t   = (__hip_bfloat16*)alloc(512 * 256 * 2);
    __hip_bfloat16* Wpt   = (__hip_bfloat16*)alloc(256 * 256 * 2);
    ushort* Wef1 = (ushort*)alloc(256 * 64 * 2);
    ushort* Wef2 = (ushort*)alloc(256 * 64 * 2);
    float* bcat1 = (float*)alloc(512 * 4);
    float* bcat2 = (float*)alloc(512 * 4);
    __hip_bfloat16* h0b  = (__hip_bfloat16*)alloc((size_t)MP * 128 * 2);
    __hip_bfloat16* xlrb = (__hip_bfloat16*)alloc((size_t)MP * 512 * 2);
    __hip_bfloat16* h1b  = (__hip_bfloat16*)alloc((size_t)MP * 256 * 2);
    __hip_bfloat16* h2b  = (__hip_bfloat16*)alloc((size_t)MP * 256 * 2);
    ushort* ea_frag = (ushort*)alloc((size_t)ET * 4096 * 2);
    __hip_bfloat16* abuf = (__hip_bfloat16*)alloc((size_t)MP * 256 * 2);
    float* logit = (float*)alloc((size_t)EE * 4 * 4);
    int* deg    = (int*)alloc(NN * 4);
    int* cursor = (int*)alloc(NN * 4);
    int* partial= (int*)alloc(NN * 4);
    int* bsum   = (int*)alloc(256 * 4);
    int* start  = (int*)alloc((NN + 4) * 4);
    int* eidx   = (int*)alloc((size_t)EE * 4);
    int* src_csr= (int*)alloc((size_t)EE * 4);
    int* dst_csr= (int*)alloc((size_t)EE * 4);
    unsigned* am = (unsigned*)alloc(BB * HC * 4);
    float* den  = (float*)alloc(BB * HC * 4);
    float* num  = (float*)alloc(BB * HC * 4);
    float* ybuf = (float*)alloc(BB * HC * 4);

    const int NB = (NN + 255) / 256;

    // ---- input / weight packing ----
    pack_x<<<(NN * 32 + 255) / 256, 256, 0, stream>>>(x, xpad, deg);
    PackJobs pj;
    pj.j[0] = {W0,  W0t, 13, 128, 32, 0};
    pj.j[1] = {Wl1, W1t, 128, 256, 128, 0};
    pj.j[2] = {Wr1, W1t, 128, 256, 128, 256};
    pj.j[3] = {Wl2, W2t, 256, 256, 256, 0};
    pj.j[4] = {Wr2, W2t, 256, 256, 256, 256};
    pj.j[5] = {Wp,  Wpt, 256, 256, 256, 0};
    pack_all<<<dim3(64, 6), 256, 0, stream>>>(pj);
    pack_we_frag<<<dim3(64, 2), 256, 0, stream>>>(We1, We2, Wef1, Wef2);
    cat2<<<dim3(2, 2), 256, 0, stream>>>(bl1, br1, bcat1, bl2, br2, bcat2);

    // ---- CSR build ----
    hist_deg<<<(EE + 255) / 256, 256, 0, stream>>>(ei, deg, am);
    scan1<<<NB, 256, 0, stream>>>(deg, partial, bsum);
    scan2<<<1, 256, 0, stream>>>(bsum, NB);
    scan3<<<NB + 1, 256, 0, stream>>>(partial, bsum, start, cursor);
    scatter_e<<<(EE + 255) / 256, 256, 0, stream>>>(ei, cursor, start, eidx, src_csr, dst_csr);
    permute_ea_frag<<<ET, 256, 0, stream>>>(ea, eidx, ea_frag);

    // ---- init transform ----
    mfma_gemm<2><<<dim3(469, 1), 256, 0, stream>>>(
        (const ushort*)xpad, (const ushort*)W0t, b0, nullptr, h0b, NN, 128, 32);

    // ---- GAT layer 1 ----
    mfma_gemm<4><<<dim3(469, 2), 256, 0, stream>>>(
        (const ushort*)h0b, (const ushort*)W1t, bcat1, nullptr, xlrb, NN, 512, 128);
    edge_fused<<<ET, 256, 0, stream>>>(ea_frag, Wef1, att1, src_csr, dst_csr,
                                       (const ushort*)xlrb, logit);
    aggregate_csr<<<(NN + 3) / 4, 256, 0, stream>>>(
        (const ushort*)xlrb, logit, src_csr, start, bias1, (ushort*)h1b);

    // ---- GAT layer 2 ----
    mfma_gemm<4><<<dim3(469, 2), 256, 0, stream>>>(
        (const ushort*)h1b, (const ushort*)W2t, bcat2, nullptr, xlrb, NN, 512, 256);
    edge_fused<<<ET, 256, 0, stream>>>(ea_frag, Wef2, att2, src_csr, dst_csr,
                                       (const ushort*)xlrb, logit);
    aggregate_csr<<<(NN + 3) / 4, 256, 0, stream>>>(
        (const ushort*)xlrb, logit, src_csr, start, bias2, (ushort*)h2b);

    // ---- attention pooling (bf16 logits) ----
    mfma_gemm<4><<<dim3(469, 1), 256, 0, stream>>>(
        (const ushort*)h2b, (const ushort*)Wpt, bp, nullptr, abuf, NN, 256, 256);
    const int poolGrid = (NN + 63) / 64;
    pool_max<<<poolGrid, HC, 0, stream>>>(abuf, batch, am, den, num);
    pool_sums<<<poolGrid, HC, 0, stream>>>(abuf, h2b, batch, am, den, num);

    // ---- head MLP ----
    mlp_lin1<<<BB, HC, 0, stream>>>(num, den, Wo1, bo1, ybuf);
    bn_relu<<<1, HC, 0, stream>>>(ybuf, gamma, beta);
    mlp_lin2<<<dim3(8, BB), 256, 0, stream>>>(ybuf, Wo2, bo2, out);
}